// Round 3
// baseline (363.479 us; speedup 1.0000x reference)
//
#include <hip/hip_runtime.h>
#include <stdint.h>

// Problem dims (fixed)
#define LL   1024
#define BB   8
#define EE   512
#define HH   8
#define HDD  64
#define NEXP 8
#define TT   8192   // L*B tokens

typedef unsigned short u16t;
typedef __bf16 bf16x8 __attribute__((ext_vector_type(8)));
typedef u16t   u16x8  __attribute__((ext_vector_type(8)));
typedef u16t   u16x4  __attribute__((ext_vector_type(4)));
typedef float  f32x4  __attribute__((ext_vector_type(4)));

__device__ __forceinline__ u16t f2bf(float f) {
  union { float f; unsigned int u; } a; a.f = f;
  unsigned int r = a.u + 0x7fffu + ((a.u >> 16) & 1u);
  return (u16t)(r >> 16);
}
__device__ __forceinline__ float bf2f(u16t s) {
  union { unsigned int u; float f; } a; a.u = ((unsigned int)s) << 16; return a.f;
}

__device__ __forceinline__ f32x4 mfma16(bf16x8 a, bf16x8 b, f32x4 c) {
  return __builtin_amdgcn_mfma_f32_16x16x32_bf16(a, b, c, 0, 0, 0);
}

// async global->LDS, 16B per lane; LDS dest is wave-uniform base + lane*16
#define GLDS16(gp, lp) \
  __builtin_amdgcn_global_load_lds( \
      (const __attribute__((address_space(1))) unsigned int*)(const void*)(gp), \
      (__attribute__((address_space(3))) unsigned int*)(void*)(lp), 16, 0, 0)

// ---------------- f32 -> bf16 convert (vectorized) ----------------
__global__ __launch_bounds__(256) void cvtk(const float* __restrict__ s,
                                            u16t* __restrict__ d, int n) {
  int i = (blockIdx.x * 256 + threadIdx.x) * 4;
  if (i < n) {
    float4 v = *(const float4*)&s[i];
    u16x4 o = { f2bf(v.x), f2bf(v.y), f2bf(v.z), f2bf(v.w) };
    *(u16x4*)&d[i] = o;
  }
}

// concat bq|bk|bv (f32) into one 1536-vector
__global__ __launch_bounds__(256) void copy3(const float* __restrict__ a,
                                             const float* __restrict__ b,
                                             const float* __restrict__ c,
                                             float* __restrict__ d) {
  int i = blockIdx.x * 256 + threadIdx.x;
  if (i < 512) { d[i] = a[i]; d[512 + i] = b[i]; d[1024 + i] = c[i]; }
}

// ---------------- generic bf16 GEMM: C = A @ W^T + bias ----------------
// A: M x K (lda), W: N x K row-major, C: M x N (ldc)
// ACT: 0 none, 1 leaky(0.01). OUTBF: bf16 or f32 output.
template<int ACT, int OUTBF>
__global__ __launch_bounds__(256) void gemm_bt(
    const u16t* __restrict__ A, int lda,
    const u16t* __restrict__ W,
    const float* __restrict__ bias,
    void* __restrict__ Cp, int ldc, int K)
{
  __shared__ alignas(16) u16t As[128 * 32];
  __shared__ alignas(16) u16t Ws[128 * 32];
  const int tid  = threadIdx.x;
  const int lane = tid & 63, wave = tid >> 6;
  const int r15  = lane & 15, rhi = lane >> 4;
  const int wr   = wave >> 1, wc  = wave & 1;
  const int m0 = blockIdx.x * 128, n0 = blockIdx.y * 128;
  const int arow = tid >> 2, acol = (tid & 3) * 8;

  const f32x4 fz = {0.f, 0.f, 0.f, 0.f};
  f32x4 acc[4][4];
#pragma unroll
  for (int i = 0; i < 4; i++)
#pragma unroll
    for (int j = 0; j < 4; j++) acc[i][j] = fz;

  const u16t* Ap0 = A + (size_t)(m0 + arow) * lda + acol;
  const u16t* Ap1 = A + (size_t)(m0 + arow + 64) * lda + acol;
  const u16t* Wp0 = W + (size_t)(n0 + arow) * K + acol;
  const u16t* Wp1 = W + (size_t)(n0 + arow + 64) * K + acol;
  u16t* As0 = &As[tid * 8];       u16t* As1 = &As[(tid + 256) * 8];
  u16t* Ws0 = &Ws[tid * 8];       u16t* Ws1 = &Ws[(tid + 256) * 8];

  for (int kt = 0; kt < K; kt += 32) {
    __syncthreads();
    GLDS16(Ap0 + kt, As0);
    GLDS16(Ap1 + kt, As1);
    GLDS16(Wp0 + kt, Ws0);
    GLDS16(Wp1 + kt, Ws1);
    asm volatile("s_waitcnt vmcnt(0)" ::: "memory");
    __syncthreads();
    bf16x8 af[4], bfv[4];
#pragma unroll
    for (int mi = 0; mi < 4; mi++)
      af[mi] = *(const bf16x8*)&As[(wr * 64 + mi * 16 + r15) * 32 + rhi * 8];
#pragma unroll
    for (int ni = 0; ni < 4; ni++)
      bfv[ni] = *(const bf16x8*)&Ws[(wc * 64 + ni * 16 + r15) * 32 + rhi * 8];
#pragma unroll
    for (int mi = 0; mi < 4; mi++)
#pragma unroll
      for (int ni = 0; ni < 4; ni++)
        acc[mi][ni] = mfma16(af[mi], bfv[ni], acc[mi][ni]);
  }

#pragma unroll
  for (int mi = 0; mi < 4; mi++) {
#pragma unroll
    for (int ni = 0; ni < 4; ni++) {
      const int col = n0 + wc * 64 + ni * 16 + r15;
      const float bv = bias[col];
#pragma unroll
      for (int r = 0; r < 4; r++) {
        const int row = m0 + wr * 64 + mi * 16 + rhi * 4 + r;
        float v = acc[mi][ni][r] + bv;
        if (ACT == 1) v = v >= 0.f ? v : 0.01f * v;
        if (OUTBF) ((u16t*)Cp)[(size_t)row * ldc + col] = f2bf(v);
        else       ((float*)Cp)[(size_t)row * ldc + col] = v;
      }
    }
  }
}

// ---------------- MoE: loop all 8 experts, weighted-combine top-2 ----------------
__global__ __launch_bounds__(256) void moe_gemm(
    const u16t* __restrict__ A,        // x1 bf16, T x 512
    const u16t* __restrict__ Wall,     // 8 x 512 x 512 bf16
    const float* __restrict__ ball,    // 8 x 512
    const float* __restrict__ wt,      // T x 8
    u16t* __restrict__ Out)            // T x 512 bf16
{
  __shared__ alignas(16) u16t As[128 * 32];
  __shared__ alignas(16) u16t Ws[128 * 32];
  __shared__ float wls[128 * 8];
  const int tid  = threadIdx.x;
  const int lane = tid & 63, wave = tid >> 6;
  const int r15  = lane & 15, rhi = lane >> 4;
  const int wr   = wave >> 1, wc  = wave & 1;
  const int m0 = blockIdx.x * 128, n0 = blockIdx.y * 128;
  const int arow = tid >> 2, acol = (tid & 3) * 8;

  for (int i = tid; i < 1024; i += 256) wls[i] = wt[(size_t)m0 * 8 + i];

  const f32x4 fz = {0.f, 0.f, 0.f, 0.f};
  f32x4 oacc[4][4];
#pragma unroll
  for (int i = 0; i < 4; i++)
#pragma unroll
    for (int j = 0; j < 4; j++) oacc[i][j] = fz;

  const u16t* Ap0 = A + (size_t)(m0 + arow) * EE + acol;
  const u16t* Ap1 = Ap0 + (size_t)64 * EE;
  u16t* As0 = &As[tid * 8];  u16t* As1 = &As[(tid + 256) * 8];
  u16t* Ws0 = &Ws[tid * 8];  u16t* Ws1 = &Ws[(tid + 256) * 8];

  for (int e = 0; e < NEXP; e++) {
    const u16t* W = Wall + (size_t)e * EE * EE;
    const u16t* Wp0 = W + (size_t)(n0 + arow) * EE + acol;
    const u16t* Wp1 = Wp0 + (size_t)64 * EE;
    f32x4 acc[4][4];
#pragma unroll
    for (int i = 0; i < 4; i++)
#pragma unroll
      for (int j = 0; j < 4; j++) acc[i][j] = fz;

    for (int kt = 0; kt < EE; kt += 32) {
      __syncthreads();
      GLDS16(Ap0 + kt, As0);
      GLDS16(Ap1 + kt, As1);
      GLDS16(Wp0 + kt, Ws0);
      GLDS16(Wp1 + kt, Ws1);
      asm volatile("s_waitcnt vmcnt(0)" ::: "memory");
      __syncthreads();
      bf16x8 af[4], bfv[4];
#pragma unroll
      for (int mi = 0; mi < 4; mi++)
        af[mi] = *(const bf16x8*)&As[(wr * 64 + mi * 16 + r15) * 32 + rhi * 8];
#pragma unroll
      for (int ni = 0; ni < 4; ni++)
        bfv[ni] = *(const bf16x8*)&Ws[(wc * 64 + ni * 16 + r15) * 32 + rhi * 8];
#pragma unroll
      for (int mi = 0; mi < 4; mi++)
#pragma unroll
        for (int ni = 0; ni < 4; ni++)
          acc[mi][ni] = mfma16(af[mi], bfv[ni], acc[mi][ni]);
    }
#pragma unroll
    for (int mi = 0; mi < 4; mi++) {
#pragma unroll
      for (int ni = 0; ni < 4; ni++) {
        const int col = n0 + wc * 64 + ni * 16 + r15;
        const float bv = ball[e * EE + col];
#pragma unroll
        for (int r = 0; r < 4; r++) {
          const int rl = wr * 64 + mi * 16 + rhi * 4 + r;
          float z = acc[mi][ni][r] + bv;
          z = z >= 0.f ? z : 0.01f * z;
          oacc[mi][ni][r] += wls[rl * 8 + e] * z;
        }
      }
    }
  }
#pragma unroll
  for (int mi = 0; mi < 4; mi++)
#pragma unroll
    for (int ni = 0; ni < 4; ni++) {
      const int col = n0 + wc * 64 + ni * 16 + r15;
#pragma unroll
      for (int r = 0; r < 4; r++) {
        const int row = m0 + wr * 64 + mi * 16 + rhi * 4 + r;
        Out[(size_t)row * EE + col] = f2bf(oacc[mi][ni][r]);
      }
    }
}

// ---------------- flash attention (bf16, HD=64, no mask) ----------------
// grid: (B*H, L/64). Block 256 = 4 waves; wave owns 16 q-rows.
__global__ __launch_bounds__(256) void attn_kernel(
    const u16t* __restrict__ q, const u16t* __restrict__ k,
    const u16t* __restrict__ v, u16t* __restrict__ ao)
{
  const int bh = blockIdx.x;
  const int b = bh >> 3, h = bh & 7;
  const int qt = blockIdx.y;
  const int tid  = threadIdx.x;
  const int lane = tid & 63, wave = tid >> 6;
  const int r15  = lane & 15, rhi = lane >> 4;
  __shared__ alignas(16) u16t Ks[64 * 64];      // [kv][d]
  __shared__ alignas(16) u16t Vt[64 * 64];      // [d][kv]
  __shared__ alignas(16) u16t Ps[4][16 * 64];   // per-wave P tile

  const int qrowA = qt * 64 + wave * 16 + r15;           // A-frag row
  const size_t qoff = ((size_t)qrowA * BB + b) * EE + h * HDD;
  bf16x8 qf0 = *(const bf16x8*)&q[qoff + rhi * 8];
  bf16x8 qf1 = *(const bf16x8*)&q[qoff + 32 + rhi * 8];

  const f32x4 fz = {0.f, 0.f, 0.f, 0.f};
  float mrun[4], lrun[4];
  f32x4 oa[4];
#pragma unroll
  for (int r = 0; r < 4; r++) { mrun[r] = -1e30f; lrun[r] = 0.f; }
#pragma unroll
  for (int d = 0; d < 4; d++) oa[d] = fz;

  const int srow = tid >> 2, scol = (tid & 3) * 8;

  for (int kv0 = 0; kv0 < LL; kv0 += 64) {
    __syncthreads();
    {
      // stage full 64x64 tile: each thread loads 16 elems of K and of V
      const size_t koff = ((size_t)(kv0 + srow) * BB + b) * EE + h * HDD + scol;
      *(u16x8*)&Ks[srow * 64 + scol]      = *(const u16x8*)&k[koff];
      *(u16x8*)&Ks[srow * 64 + scol + 32] = *(const u16x8*)&k[koff + 32];
      u16x8 vv0 = *(const u16x8*)&v[koff];
      u16x8 vv1 = *(const u16x8*)&v[koff + 32];
#pragma unroll
      for (int j = 0; j < 8; j++) {
        Vt[(scol + j) * 64 + srow]      = vv0[j];
        Vt[(scol + 32 + j) * 64 + srow] = vv1[j];
      }
    }
    __syncthreads();

    f32x4 s[4];
#pragma unroll
    for (int nt = 0; nt < 4; nt++) {
      s[nt] = fz;
      bf16x8 kb0 = *(const bf16x8*)&Ks[(nt * 16 + r15) * 64 + rhi * 8];
      bf16x8 kb1 = *(const bf16x8*)&Ks[(nt * 16 + r15) * 64 + 32 + rhi * 8];
      s[nt] = mfma16(qf0, kb0, s[nt]);
      s[nt] = mfma16(qf1, kb1, s[nt]);
    }
#pragma unroll
    for (int nt = 0; nt < 4; nt++)
#pragma unroll
      for (int r = 0; r < 4; r++) s[nt][r] *= 0.125f;

    float mx[4];
#pragma unroll
    for (int r = 0; r < 4; r++)
      mx[r] = fmaxf(fmaxf(s[0][r], s[1][r]), fmaxf(s[2][r], s[3][r]));
#pragma unroll
    for (int off = 1; off < 16; off <<= 1)
#pragma unroll
      for (int r = 0; r < 4; r++) mx[r] = fmaxf(mx[r], __shfl_xor(mx[r], off));

    float corr[4], rs[4];
#pragma unroll
    for (int r = 0; r < 4; r++) {
      float mn = fmaxf(mrun[r], mx[r]);
      corr[r] = __expf(mrun[r] - mn);
      mrun[r] = mn;
    }
#pragma unroll
    for (int nt = 0; nt < 4; nt++)
#pragma unroll
      for (int r = 0; r < 4; r++) s[nt][r] = __expf(s[nt][r] - mrun[r]);
#pragma unroll
    for (int r = 0; r < 4; r++) rs[r] = s[0][r] + s[1][r] + s[2][r] + s[3][r];
#pragma unroll
    for (int off = 1; off < 16; off <<= 1)
#pragma unroll
      for (int r = 0; r < 4; r++) rs[r] += __shfl_xor(rs[r], off);
#pragma unroll
    for (int r = 0; r < 4; r++) lrun[r] = lrun[r] * corr[r] + rs[r];
#pragma unroll
    for (int d = 0; d < 4; d++)
#pragma unroll
      for (int r = 0; r < 4; r++) oa[d][r] *= corr[r];

    // P (C-layout) -> LDS -> A-layout for PV
#pragma unroll
    for (int nt = 0; nt < 4; nt++)
#pragma unroll
      for (int r = 0; r < 4; r++)
        Ps[wave][(rhi * 4 + r) * 64 + nt * 16 + r15] = f2bf(s[nt][r]);
    __syncthreads();

    bf16x8 pf0 = *(const bf16x8*)&Ps[wave][r15 * 64 + rhi * 8];
    bf16x8 pf1 = *(const bf16x8*)&Ps[wave][r15 * 64 + 32 + rhi * 8];
#pragma unroll
    for (int d = 0; d < 4; d++) {
      bf16x8 vb0 = *(const bf16x8*)&Vt[(d * 16 + r15) * 64 + rhi * 8];
      bf16x8 vb1 = *(const bf16x8*)&Vt[(d * 16 + r15) * 64 + 32 + rhi * 8];
      oa[d] = mfma16(pf0, vb0, oa[d]);
      oa[d] = mfma16(pf1, vb1, oa[d]);
    }
  }

#pragma unroll
  for (int d = 0; d < 4; d++)
#pragma unroll
    for (int r = 0; r < 4; r++) {
      const int qr = qt * 64 + wave * 16 + rhi * 4 + r;
      float o = oa[d][r] / lrun[r];
      ao[((size_t)qr * BB + b) * EE + h * HDD + d * 16 + r15] = f2bf(o);
    }
}

// ---------------- LayerNorm kernels (f32 math) ----------------
__device__ __forceinline__ float wave_sum(float v) {
#pragma unroll
  for (int off = 1; off < 64; off <<= 1) v += __shfl_xor(v, off);
  return v;
}

__global__ __launch_bounds__(256) void ln1_kernel(
    const float* __restrict__ x, const float* __restrict__ aop,
    const float* __restrict__ g, const float* __restrict__ be,
    float* __restrict__ x1, u16t* __restrict__ x1b)
{
  const int t = blockIdx.x, tid = threadIdx.x;
  const size_t base = (size_t)t * EE;
  float v0 = x[base + tid] + aop[base + tid];
  float v1 = x[base + 256 + tid] + aop[base + 256 + tid];
  __shared__ float red[8];
  float s = wave_sum(v0 + v1);
  if ((tid & 63) == 0) red[tid >> 6] = s;
  __syncthreads();
  const float mean = (red[0] + red[1] + red[2] + red[3]) * (1.f / EE);
  const float d0 = v0 - mean, d1 = v1 - mean;
  float vs = wave_sum(d0 * d0 + d1 * d1);
  if ((tid & 63) == 0) red[4 + (tid >> 6)] = vs;
  __syncthreads();
  const float inv = rsqrtf((red[4] + red[5] + red[6] + red[7]) * (1.f / EE) + 1e-5f);
  const float o0 = d0 * inv * g[tid] + be[tid];
  const float o1 = d1 * inv * g[256 + tid] + be[256 + tid];
  x1[base + tid] = o0; x1[base + 256 + tid] = o1;
  x1b[base + tid] = f2bf(o0); x1b[base + 256 + tid] = f2bf(o1);
}

// f32 OUTPUT: reference output dtype is float32
__global__ __launch_bounds__(256) void ln2_kernel(
    const float* __restrict__ x1, const u16t* __restrict__ moe,
    const u16t* __restrict__ sh,
    const float* __restrict__ g, const float* __restrict__ be,
    float* __restrict__ out)
{
  const int t = blockIdx.x, tid = threadIdx.x;
  const size_t base = (size_t)t * EE;
  float v0 = x1[base + tid] + bf2f(moe[base + tid]) + bf2f(sh[base + tid]);
  float v1 = x1[base + 256 + tid] + bf2f(moe[base + 256 + tid]) + bf2f(sh[base + 256 + tid]);
  __shared__ float red[8];
  float s = wave_sum(v0 + v1);
  if ((tid & 63) == 0) red[tid >> 6] = s;
  __syncthreads();
  const float mean = (red[0] + red[1] + red[2] + red[3]) * (1.f / EE);
  const float d0 = v0 - mean, d1 = v1 - mean;
  float vs = wave_sum(d0 * d0 + d1 * d1);
  if ((tid & 63) == 0) red[4 + (tid >> 6)] = vs;
  __syncthreads();
  const float inv = rsqrtf((red[4] + red[5] + red[6] + red[7]) * (1.f / EE) + 1e-5f);
  out[base + tid] = d0 * inv * g[tid] + be[tid];
  out[base + 256 + tid] = d1 * inv * g[256 + tid] + be[256 + tid];
}

// ---------------- gate: softmax over 8, top-2, weights + loss partials ----------------
__global__ __launch_bounds__(256) void gate_kernel(
    const float* __restrict__ x1, const float* __restrict__ gw,
    const float* __restrict__ gb,
    float* __restrict__ wt, float* __restrict__ partials)
{
  const int wave = threadIdx.x >> 6, lane = threadIdx.x & 63;
  const int t = blockIdx.x * 4 + wave;
  float xv[8];
#pragma unroll
  for (int j = 0; j < 8; j++) xv[j] = x1[(size_t)t * EE + lane * 8 + j];
  float pe[8];
  float mx = -1e30f;
#pragma unroll
  for (int e = 0; e < 8; e++) {
    float s = 0.f;
#pragma unroll
    for (int j = 0; j < 8; j++) s += xv[j] * gw[e * EE + lane * 8 + j];
#pragma unroll
    for (int off = 1; off < 64; off <<= 1) s += __shfl_xor(s, off);
    pe[e] = s + gb[e];
    mx = fmaxf(mx, pe[e]);
  }
  float se = 0.f;
#pragma unroll
  for (int e = 0; e < 8; e++) { pe[e] = __expf(pe[e] - mx); se += pe[e]; }
  const float invs = 1.f / se;
#pragma unroll
  for (int e = 0; e < 8; e++) pe[e] *= invs;
  // top-2 (first occurrence wins ties, matching lax.top_k)
  float v1 = -1.f; int i1 = 0;
#pragma unroll
  for (int e = 0; e < 8; e++) if (pe[e] > v1) { v1 = pe[e]; i1 = e; }
  float v2 = -1.f; int i2 = -1;
#pragma unroll
  for (int e = 0; e < 8; e++) if (e != i1 && pe[e] > v2) { v2 = pe[e]; i2 = e; }
  const float denom = 1.f / (v1 + v2);
  if (lane < 8)
    wt[(size_t)t * 8 + lane] = (lane == i1) ? v1 * denom : (lane == i2) ? v2 * denom : 0.f;

  __shared__ float fb[4][8], pb[4][8];
  if (lane < 8) {
    fb[wave][lane] = (lane == i1 || lane == i2) ? 1.f : 0.f;
    pb[wave][lane] = pe[lane];
  }
  __syncthreads();
  if (threadIdx.x < 8) {
    const int e = threadIdx.x;
    partials[(size_t)blockIdx.x * 16 + e]     = fb[0][e] + fb[1][e] + fb[2][e] + fb[3][e];
    partials[(size_t)blockIdx.x * 16 + 8 + e] = pb[0][e] + pb[1][e] + pb[2][e] + pb[3][e];
  }
}

// f32 OUTPUT for the loss scalar
__global__ __launch_bounds__(256) void gate_reduce(
    const float* __restrict__ partials, float* __restrict__ loss_out)
{
  __shared__ float acc[16][16];
  __shared__ float fin[16];
  const int c = threadIdx.x & 15, grp = threadIdx.x >> 4;
  float s = 0.f;
  for (int i = grp; i < 2048; i += 16) s += partials[(size_t)i * 16 + c];
  acc[grp][c] = s;
  __syncthreads();
  if (threadIdx.x < 16) {
    float t2 = 0.f;
    for (int g2 = 0; g2 < 16; g2++) t2 += acc[g2][threadIdx.x];
    fin[threadIdx.x] = t2;
  }
  __syncthreads();
  if (threadIdx.x == 0) {
    float loss = 0.f;
    for (int e = 0; e < 8; e++)
      loss += (fin[e] * (1.f / TT)) * (fin[8 + e] * (1.f / TT));
    loss_out[0] = loss * 8.f;
  }
}

// ---------------- host-side launcher ----------------
extern "C" void kernel_launch(void* const* d_in, const int* in_sizes, int n_in,
                              void* d_out, int out_size, void* d_ws, size_t ws_size,
                              hipStream_t stream) {
  const float* x    = (const float*)d_in[0];
  const float* wq   = (const float*)d_in[1];
  const float* bq   = (const float*)d_in[2];
  const float* wk   = (const float*)d_in[3];
  const float* bk   = (const float*)d_in[4];
  const float* wv   = (const float*)d_in[5];
  const float* bv   = (const float*)d_in[6];
  const float* in_w = (const float*)d_in[7];
  const float* in_b = (const float*)d_in[8];
  const float* out_w= (const float*)d_in[9];
  const float* out_b= (const float*)d_in[10];
  const float* ln1g = (const float*)d_in[11];
  const float* ln1b = (const float*)d_in[12];
  const float* ln2g = (const float*)d_in[13];
  const float* ln2b = (const float*)d_in[14];
  const float* shw  = (const float*)d_in[15];
  const float* shb  = (const float*)d_in[16];
  const float* gw   = (const float*)d_in[17];
  const float* gb   = (const float*)d_in[18];
  const float* expw = (const float*)d_in[19];
  const float* expb = (const float*)d_in[20];

  char* ws = (char*)d_ws;
  // --- static region [0, 17.2 MB) ---
  u16t* xb    = (u16t*)(ws + 0);          // 8 MB   (dead after stage-1)
  u16t* w3    = (u16t*)(ws + 8388608);    // 1.5 MB (dead after stage-1)
  u16t* inwb  = (u16t*)(ws + 9961472);    // 1.5 MB
  u16t* outwb = (u16t*)(ws + 11534336);   // 0.5 MB
  u16t* shwb  = (u16t*)(ws + 12058624);   // 0.5 MB
  u16t* expwb = (u16t*)(ws + 12582912);   // 4 MB
  float* b3   = (float*)(ws + 16777216);  // 6 KB
  float* wtbuf = (float*)(ws + 16783360); // 256 KB
  float* parts = (float*)(ws + 17045504); // 128 KB
  // --- overlay pool (peak 59.1 MB total) ---
  char* P0 = ws + 17176576;               // 24 MB: q0kv -> aob(8)+aop(16) -> x1b(8)+moeb(8)
  char* P1 = ws + 42342400;               // 8 MB:  kb -> x1 (lower half)
  char* P2 = ws + 50731008;               // 8 MB:  vb -> x1 (upper half)

  u16t* q0kv = (u16t*)P0;                       // stage1 -> stage2
  u16t* qb   = (u16t*)(ws + 0);                 // reuses xb (dead)
  u16t* kb   = (u16t*)P1;
  u16t* vb   = (u16t*)P2;
  u16t* aob  = (u16t*)P0;                       // attn out (q0kv dead)
  float* aop = (float*)(P0 + 8388608);          // out-proj f32 (within dead q0kv)
  float* x1  = (float*)P1;                      // 16 MB spans P1+P2 (kb,vb dead)
  u16t* x1b  = (u16t*)P0;                       // aob dead after out-proj
  u16t* shrd = (u16t*)(ws + 0);                 // qb dead after attn
  u16t* moeb = (u16t*)(P0 + 8388608);           // aop dead after ln1
  float* outp = (float*)d_out;                  // f32 output (reference dtype)

  dim3 blk(256);
  // bf16 converts
  cvtk<<<4096, blk, 0, stream>>>(x, xb, TT * EE);
  cvtk<<<256,  blk, 0, stream>>>(wq, w3, EE * EE);
  cvtk<<<256,  blk, 0, stream>>>(wk, w3 + EE * EE, EE * EE);
  cvtk<<<256,  blk, 0, stream>>>(wv, w3 + 2 * EE * EE, EE * EE);
  cvtk<<<768,  blk, 0, stream>>>(in_w, inwb, 3 * EE * EE);
  cvtk<<<256,  blk, 0, stream>>>(out_w, outwb, EE * EE);
  cvtk<<<256,  blk, 0, stream>>>(shw, shwb, EE * EE);
  cvtk<<<2048, blk, 0, stream>>>(expw, expwb, NEXP * EE * EE);
  copy3<<<2,   blk, 0, stream>>>(bq, bk, bv, b3);

  // stage-1 QKV projection (batched, N=1536)
  gemm_bt<0,1><<<dim3(64, 12), blk, 0, stream>>>(xb, EE, w3, b3, q0kv, 1536, EE);
  // stage-2 (MHA in_proj)
  gemm_bt<0,1><<<dim3(64, 4), blk, 0, stream>>>(q0kv,        1536, inwb,               in_b,        qb, EE, EE);
  gemm_bt<0,1><<<dim3(64, 4), blk, 0, stream>>>(q0kv + 512,  1536, inwb + EE * EE,     in_b + 512,  kb, EE, EE);
  gemm_bt<0,1><<<dim3(64, 4), blk, 0, stream>>>(q0kv + 1024, 1536, inwb + 2 * EE * EE, in_b + 1024, vb, EE, EE);
  // attention
  attn_kernel<<<dim3(64, 16), blk, 0, stream>>>(qb, kb, vb, aob);
  // out projection (f32 out)
  gemm_bt<0,0><<<dim3(64, 4), blk, 0, stream>>>(aob, EE, outwb, out_b, aop, EE, EE);
  // LN1
  ln1_kernel<<<8192, blk, 0, stream>>>(x, aop, ln1g, ln1b, x1, x1b);
  // gate + loss
  gate_kernel<<<2048, blk, 0, stream>>>(x1, gw, gb, wtbuf, parts);
  gate_reduce<<<1, blk, 0, stream>>>(parts, outp + (size_t)TT * EE);
  // shared expert (leaky)
  gemm_bt<1,1><<<dim3(64, 4), blk, 0, stream>>>(x1b, EE, shwb, shb, shrd, EE, EE);
  // MoE
  moe_gemm<<<dim3(64, 4), blk, 0, stream>>>(x1b, expwb, expb, wtbuf, moeb);
  // LN2 -> output (f32)
  ln2_kernel<<<8192, blk, 0, stream>>>(x1, moeb, shrd, ln2g, ln2b, outp);
}

// Round 4
// 346.523 us; speedup vs baseline: 1.0489x; 1.0489x over previous
//
#include <hip/hip_runtime.h>
#include <stdint.h>

// Problem dims (fixed)
#define LL   1024
#define BB   8
#define EE   512
#define HH   8
#define HDD  64
#define NEXP 8
#define TT   8192   // L*B tokens

typedef unsigned short u16t;
typedef __bf16 bf16x8 __attribute__((ext_vector_type(8)));
typedef u16t   u16x8  __attribute__((ext_vector_type(8)));
typedef u16t   u16x4  __attribute__((ext_vector_type(4)));
typedef float  f32x4  __attribute__((ext_vector_type(4)));

__device__ __forceinline__ u16t f2bf(float f) {
  union { float f; unsigned int u; } a; a.f = f;
  unsigned int r = a.u + 0x7fffu + ((a.u >> 16) & 1u);
  return (u16t)(r >> 16);
}
__device__ __forceinline__ float bf2f(u16t s) {
  union { unsigned int u; float f; } a; a.u = ((unsigned int)s) << 16; return a.f;
}

__device__ __forceinline__ f32x4 mfma16(bf16x8 a, bf16x8 b, f32x4 c) {
  return __builtin_amdgcn_mfma_f32_16x16x32_bf16(a, b, c, 0, 0, 0);
}

// async global->LDS, 16B per lane; LDS dest is wave-uniform base + lane*16
#define GLDS16(gp, lp) \
  __builtin_amdgcn_global_load_lds( \
      (const __attribute__((address_space(1))) unsigned int*)(const void*)(gp), \
      (__attribute__((address_space(3))) unsigned int*)(void*)(lp), 16, 0, 0)

// XOR bank swizzle for [*][64] bf16 tiles (128B row stride = 32 banks):
// u16 index ^= (row&7)<<3  (== byte ^= (row&7)<<4). Keeps 16B alignment.
#define SWZ(row, idx) ((idx) ^ (((row) & 7) << 3))

// ---------------- f32 -> bf16 convert (vectorized) ----------------
__global__ __launch_bounds__(256) void cvtk(const float* __restrict__ s,
                                            u16t* __restrict__ d, int n) {
  int i = (blockIdx.x * 256 + threadIdx.x) * 4;
  if (i < n) {
    float4 v = *(const float4*)&s[i];
    u16x4 o = { f2bf(v.x), f2bf(v.y), f2bf(v.z), f2bf(v.w) };
    *(u16x4*)&d[i] = o;
  }
}

// concat bq|bk|bv (f32) into one 1536-vector
__global__ __launch_bounds__(256) void copy3(const float* __restrict__ a,
                                             const float* __restrict__ b,
                                             const float* __restrict__ c,
                                             float* __restrict__ d) {
  int i = blockIdx.x * 256 + threadIdx.x;
  if (i < 512) { d[i] = a[i]; d[512 + i] = b[i]; d[1024 + i] = c[i]; }
}

// ---------------- generic bf16 GEMM: C = A @ W^T + bias ----------------
// A: M x K (lda), W: N x K row-major, C: M x N (ldc)
// ACT: 0 none, 1 leaky(0.01). OUTBF: bf16 or f32 output.
template<int ACT, int OUTBF>
__global__ __launch_bounds__(256) void gemm_bt(
    const u16t* __restrict__ A, int lda,
    const u16t* __restrict__ W,
    const float* __restrict__ bias,
    void* __restrict__ Cp, int ldc, int K)
{
  __shared__ alignas(16) u16t As[128 * 32];
  __shared__ alignas(16) u16t Ws[128 * 32];
  const int tid  = threadIdx.x;
  const int lane = tid & 63, wave = tid >> 6;
  const int r15  = lane & 15, rhi = lane >> 4;
  const int wr   = wave >> 1, wc  = wave & 1;
  const int m0 = blockIdx.x * 128, n0 = blockIdx.y * 128;
  const int arow = tid >> 2, acol = (tid & 3) * 8;

  const f32x4 fz = {0.f, 0.f, 0.f, 0.f};
  f32x4 acc[4][4];
#pragma unroll
  for (int i = 0; i < 4; i++)
#pragma unroll
    for (int j = 0; j < 4; j++) acc[i][j] = fz;

  const u16t* Ap0 = A + (size_t)(m0 + arow) * lda + acol;
  const u16t* Ap1 = A + (size_t)(m0 + arow + 64) * lda + acol;
  const u16t* Wp0 = W + (size_t)(n0 + arow) * K + acol;
  const u16t* Wp1 = W + (size_t)(n0 + arow + 64) * K + acol;
  u16t* As0 = &As[tid * 8];       u16t* As1 = &As[(tid + 256) * 8];
  u16t* Ws0 = &Ws[tid * 8];       u16t* Ws1 = &Ws[(tid + 256) * 8];

  for (int kt = 0; kt < K; kt += 32) {
    __syncthreads();
    GLDS16(Ap0 + kt, As0);
    GLDS16(Ap1 + kt, As1);
    GLDS16(Wp0 + kt, Ws0);
    GLDS16(Wp1 + kt, Ws1);
    asm volatile("s_waitcnt vmcnt(0)" ::: "memory");
    __syncthreads();
    bf16x8 af[4], bfv[4];
#pragma unroll
    for (int mi = 0; mi < 4; mi++)
      af[mi] = *(const bf16x8*)&As[(wr * 64 + mi * 16 + r15) * 32 + rhi * 8];
#pragma unroll
    for (int ni = 0; ni < 4; ni++)
      bfv[ni] = *(const bf16x8*)&Ws[(wc * 64 + ni * 16 + r15) * 32 + rhi * 8];
#pragma unroll
    for (int mi = 0; mi < 4; mi++)
#pragma unroll
      for (int ni = 0; ni < 4; ni++)
        acc[mi][ni] = mfma16(af[mi], bfv[ni], acc[mi][ni]);
  }

#pragma unroll
  for (int mi = 0; mi < 4; mi++) {
#pragma unroll
    for (int ni = 0; ni < 4; ni++) {
      const int col = n0 + wc * 64 + ni * 16 + r15;
      const float bv = bias[col];
#pragma unroll
      for (int r = 0; r < 4; r++) {
        const int row = m0 + wr * 64 + mi * 16 + rhi * 4 + r;
        float v = acc[mi][ni][r] + bv;
        if (ACT == 1) v = v >= 0.f ? v : 0.01f * v;
        if (OUTBF) ((u16t*)Cp)[(size_t)row * ldc + col] = f2bf(v);
        else       ((float*)Cp)[(size_t)row * ldc + col] = v;
      }
    }
  }
}

// ---------------- MoE: loop all 8 experts, weighted-combine top-2 ----------------
__global__ __launch_bounds__(256) void moe_gemm(
    const u16t* __restrict__ A,        // x1 bf16, T x 512
    const u16t* __restrict__ Wall,     // 8 x 512 x 512 bf16
    const float* __restrict__ ball,    // 8 x 512
    const float* __restrict__ wt,      // T x 8
    u16t* __restrict__ Out)            // T x 512 bf16
{
  __shared__ alignas(16) u16t As[128 * 32];
  __shared__ alignas(16) u16t Ws[128 * 32];
  __shared__ float wls[128 * 8];
  const int tid  = threadIdx.x;
  const int lane = tid & 63, wave = tid >> 6;
  const int r15  = lane & 15, rhi = lane >> 4;
  const int wr   = wave >> 1, wc  = wave & 1;
  const int m0 = blockIdx.x * 128, n0 = blockIdx.y * 128;
  const int arow = tid >> 2, acol = (tid & 3) * 8;

  for (int i = tid; i < 1024; i += 256) wls[i] = wt[(size_t)m0 * 8 + i];

  const f32x4 fz = {0.f, 0.f, 0.f, 0.f};
  f32x4 oacc[4][4];
#pragma unroll
  for (int i = 0; i < 4; i++)
#pragma unroll
    for (int j = 0; j < 4; j++) oacc[i][j] = fz;

  const u16t* Ap0 = A + (size_t)(m0 + arow) * EE + acol;
  const u16t* Ap1 = Ap0 + (size_t)64 * EE;
  u16t* As0 = &As[tid * 8];  u16t* As1 = &As[(tid + 256) * 8];
  u16t* Ws0 = &Ws[tid * 8];  u16t* Ws1 = &Ws[(tid + 256) * 8];

  for (int e = 0; e < NEXP; e++) {
    const u16t* W = Wall + (size_t)e * EE * EE;
    const u16t* Wp0 = W + (size_t)(n0 + arow) * EE + acol;
    const u16t* Wp1 = Wp0 + (size_t)64 * EE;
    f32x4 acc[4][4];
#pragma unroll
    for (int i = 0; i < 4; i++)
#pragma unroll
      for (int j = 0; j < 4; j++) acc[i][j] = fz;

    for (int kt = 0; kt < EE; kt += 32) {
      __syncthreads();
      GLDS16(Ap0 + kt, As0);
      GLDS16(Ap1 + kt, As1);
      GLDS16(Wp0 + kt, Ws0);
      GLDS16(Wp1 + kt, Ws1);
      asm volatile("s_waitcnt vmcnt(0)" ::: "memory");
      __syncthreads();
      bf16x8 af[4], bfv[4];
#pragma unroll
      for (int mi = 0; mi < 4; mi++)
        af[mi] = *(const bf16x8*)&As[(wr * 64 + mi * 16 + r15) * 32 + rhi * 8];
#pragma unroll
      for (int ni = 0; ni < 4; ni++)
        bfv[ni] = *(const bf16x8*)&Ws[(wc * 64 + ni * 16 + r15) * 32 + rhi * 8];
#pragma unroll
      for (int mi = 0; mi < 4; mi++)
#pragma unroll
        for (int ni = 0; ni < 4; ni++)
          acc[mi][ni] = mfma16(af[mi], bfv[ni], acc[mi][ni]);
    }
#pragma unroll
    for (int mi = 0; mi < 4; mi++) {
#pragma unroll
      for (int ni = 0; ni < 4; ni++) {
        const int col = n0 + wc * 64 + ni * 16 + r15;
        const float bv = ball[e * EE + col];
#pragma unroll
        for (int r = 0; r < 4; r++) {
          const int rl = wr * 64 + mi * 16 + rhi * 4 + r;
          float z = acc[mi][ni][r] + bv;
          z = z >= 0.f ? z : 0.01f * z;
          oacc[mi][ni][r] += wls[rl * 8 + e] * z;
        }
      }
    }
  }
#pragma unroll
  for (int mi = 0; mi < 4; mi++)
#pragma unroll
    for (int ni = 0; ni < 4; ni++) {
      const int col = n0 + wc * 64 + ni * 16 + r15;
#pragma unroll
      for (int r = 0; r < 4; r++) {
        const int row = m0 + wr * 64 + mi * 16 + rhi * 4 + r;
        Out[(size_t)row * EE + col] = f2bf(oacc[mi][ni][r]);
      }
    }
}

// ---------------- flash attention (bf16, HD=64, no mask) ----------------
// grid: (B*H, L/64). Block 256 = 4 waves; wave owns 16 q-rows.
// All LDS tiles XOR-swizzled (SWZ) to kill 16-way bank conflicts on b128 reads.
__global__ __launch_bounds__(256) void attn_kernel(
    const u16t* __restrict__ q, const u16t* __restrict__ k,
    const u16t* __restrict__ v, u16t* __restrict__ ao)
{
  const int bh = blockIdx.x;
  const int b = bh >> 3, h = bh & 7;
  const int qt = blockIdx.y;
  const int tid  = threadIdx.x;
  const int lane = tid & 63, wave = tid >> 6;
  const int r15  = lane & 15, rhi = lane >> 4;
  __shared__ alignas(16) u16t Ks[64 * 64];      // [kv][d]  (swizzled)
  __shared__ alignas(16) u16t Vt[64 * 64];      // [d][kv]  (swizzled)
  __shared__ alignas(16) u16t Ps[4][16 * 64];   // per-wave P tile (swizzled)

  const int qrowA = qt * 64 + wave * 16 + r15;           // A-frag row
  const size_t qoff = ((size_t)qrowA * BB + b) * EE + h * HDD;
  bf16x8 qf0 = *(const bf16x8*)&q[qoff + rhi * 8];
  bf16x8 qf1 = *(const bf16x8*)&q[qoff + 32 + rhi * 8];

  const f32x4 fz = {0.f, 0.f, 0.f, 0.f};
  float mrun[4], lrun[4];
  f32x4 oa[4];
#pragma unroll
  for (int r = 0; r < 4; r++) { mrun[r] = -1e30f; lrun[r] = 0.f; }
#pragma unroll
  for (int d = 0; d < 4; d++) oa[d] = fz;

  const int srow = tid >> 2, scol = (tid & 3) * 8;

  for (int kv0 = 0; kv0 < LL; kv0 += 64) {
    __syncthreads();
    {
      // stage full 64x64 tile: each thread loads 16 elems of K and of V
      const size_t koff = ((size_t)(kv0 + srow) * BB + b) * EE + h * HDD + scol;
      *(u16x8*)&Ks[SWZ(srow, srow * 64 + scol)]      = *(const u16x8*)&k[koff];
      *(u16x8*)&Ks[SWZ(srow, srow * 64 + scol + 32)] = *(const u16x8*)&k[koff + 32];
      u16x8 vv0 = *(const u16x8*)&v[koff];
      u16x8 vv1 = *(const u16x8*)&v[koff + 32];
#pragma unroll
      for (int j = 0; j < 8; j++) {
        const int rA = scol + j, rB = scol + 32 + j;
        Vt[SWZ(rA, rA * 64 + srow)] = vv0[j];
        Vt[SWZ(rB, rB * 64 + srow)] = vv1[j];
      }
    }
    __syncthreads();

    f32x4 s[4];
#pragma unroll
    for (int nt = 0; nt < 4; nt++) {
      s[nt] = fz;
      const int kr = nt * 16 + r15;
      bf16x8 kb0 = *(const bf16x8*)&Ks[SWZ(kr, kr * 64 + rhi * 8)];
      bf16x8 kb1 = *(const bf16x8*)&Ks[SWZ(kr, kr * 64 + 32 + rhi * 8)];
      s[nt] = mfma16(qf0, kb0, s[nt]);
      s[nt] = mfma16(qf1, kb1, s[nt]);
    }
#pragma unroll
    for (int nt = 0; nt < 4; nt++)
#pragma unroll
      for (int r = 0; r < 4; r++) s[nt][r] *= 0.125f;

    float mx[4];
#pragma unroll
    for (int r = 0; r < 4; r++)
      mx[r] = fmaxf(fmaxf(s[0][r], s[1][r]), fmaxf(s[2][r], s[3][r]));
#pragma unroll
    for (int off = 1; off < 16; off <<= 1)
#pragma unroll
      for (int r = 0; r < 4; r++) mx[r] = fmaxf(mx[r], __shfl_xor(mx[r], off));

    float corr[4], rs[4];
#pragma unroll
    for (int r = 0; r < 4; r++) {
      float mn = fmaxf(mrun[r], mx[r]);
      corr[r] = __expf(mrun[r] - mn);
      mrun[r] = mn;
    }
#pragma unroll
    for (int nt = 0; nt < 4; nt++)
#pragma unroll
      for (int r = 0; r < 4; r++) s[nt][r] = __expf(s[nt][r] - mrun[r]);
#pragma unroll
    for (int r = 0; r < 4; r++) rs[r] = s[0][r] + s[1][r] + s[2][r] + s[3][r];
#pragma unroll
    for (int off = 1; off < 16; off <<= 1)
#pragma unroll
      for (int r = 0; r < 4; r++) rs[r] += __shfl_xor(rs[r], off);
#pragma unroll
    for (int r = 0; r < 4; r++) lrun[r] = lrun[r] * corr[r] + rs[r];
#pragma unroll
    for (int d = 0; d < 4; d++)
#pragma unroll
      for (int r = 0; r < 4; r++) oa[d][r] *= corr[r];

    // P (C-layout) -> LDS -> A-layout for PV
#pragma unroll
    for (int nt = 0; nt < 4; nt++)
#pragma unroll
      for (int r = 0; r < 4; r++) {
        const int pr = rhi * 4 + r;
        Ps[wave][SWZ(pr, pr * 64 + nt * 16 + r15)] = f2bf(s[nt][r]);
      }
    __syncthreads();

    bf16x8 pf0 = *(const bf16x8*)&Ps[wave][SWZ(r15, r15 * 64 + rhi * 8)];
    bf16x8 pf1 = *(const bf16x8*)&Ps[wave][SWZ(r15, r15 * 64 + 32 + rhi * 8)];
#pragma unroll
    for (int d = 0; d < 4; d++) {
      const int vr = d * 16 + r15;
      bf16x8 vb0 = *(const bf16x8*)&Vt[SWZ(vr, vr * 64 + rhi * 8)];
      bf16x8 vb1 = *(const bf16x8*)&Vt[SWZ(vr, vr * 64 + 32 + rhi * 8)];
      oa[d] = mfma16(pf0, vb0, oa[d]);
      oa[d] = mfma16(pf1, vb1, oa[d]);
    }
  }

#pragma unroll
  for (int d = 0; d < 4; d++)
#pragma unroll
    for (int r = 0; r < 4; r++) {
      const int qr = qt * 64 + wave * 16 + rhi * 4 + r;
      float o = oa[d][r] / lrun[r];
      ao[((size_t)qr * BB + b) * EE + h * HDD + d * 16 + r15] = f2bf(o);
    }
}

// ---------------- LayerNorm kernels (f32 math) ----------------
__device__ __forceinline__ float wave_sum(float v) {
#pragma unroll
  for (int off = 1; off < 64; off <<= 1) v += __shfl_xor(v, off);
  return v;
}

__global__ __launch_bounds__(256) void ln1_kernel(
    const float* __restrict__ x, const float* __restrict__ aop,
    const float* __restrict__ g, const float* __restrict__ be,
    float* __restrict__ x1, u16t* __restrict__ x1b)
{
  const int t = blockIdx.x, tid = threadIdx.x;
  const size_t base = (size_t)t * EE;
  float v0 = x[base + tid] + aop[base + tid];
  float v1 = x[base + 256 + tid] + aop[base + 256 + tid];
  __shared__ float red[8];
  float s = wave_sum(v0 + v1);
  if ((tid & 63) == 0) red[tid >> 6] = s;
  __syncthreads();
  const float mean = (red[0] + red[1] + red[2] + red[3]) * (1.f / EE);
  const float d0 = v0 - mean, d1 = v1 - mean;
  float vs = wave_sum(d0 * d0 + d1 * d1);
  if ((tid & 63) == 0) red[4 + (tid >> 6)] = vs;
  __syncthreads();
  const float inv = rsqrtf((red[4] + red[5] + red[6] + red[7]) * (1.f / EE) + 1e-5f);
  const float o0 = d0 * inv * g[tid] + be[tid];
  const float o1 = d1 * inv * g[256 + tid] + be[256 + tid];
  x1[base + tid] = o0; x1[base + 256 + tid] = o1;
  x1b[base + tid] = f2bf(o0); x1b[base + 256 + tid] = f2bf(o1);
}

// f32 OUTPUT: reference output dtype is float32
__global__ __launch_bounds__(256) void ln2_kernel(
    const float* __restrict__ x1, const u16t* __restrict__ moe,
    const u16t* __restrict__ sh,
    const float* __restrict__ g, const float* __restrict__ be,
    float* __restrict__ out)
{
  const int t = blockIdx.x, tid = threadIdx.x;
  const size_t base = (size_t)t * EE;
  float v0 = x1[base + tid] + bf2f(moe[base + tid]) + bf2f(sh[base + tid]);
  float v1 = x1[base + 256 + tid] + bf2f(moe[base + 256 + tid]) + bf2f(sh[base + 256 + tid]);
  __shared__ float red[8];
  float s = wave_sum(v0 + v1);
  if ((tid & 63) == 0) red[tid >> 6] = s;
  __syncthreads();
  const float mean = (red[0] + red[1] + red[2] + red[3]) * (1.f / EE);
  const float d0 = v0 - mean, d1 = v1 - mean;
  float vs = wave_sum(d0 * d0 + d1 * d1);
  if ((tid & 63) == 0) red[4 + (tid >> 6)] = vs;
  __syncthreads();
  const float inv = rsqrtf((red[4] + red[5] + red[6] + red[7]) * (1.f / EE) + 1e-5f);
  out[base + tid] = d0 * inv * g[tid] + be[tid];
  out[base + 256 + tid] = d1 * inv * g[256 + tid] + be[256 + tid];
}

// ---------------- gate: softmax over 8, top-2, weights + loss partials ----------------
__global__ __launch_bounds__(256) void gate_kernel(
    const float* __restrict__ x1, const float* __restrict__ gw,
    const float* __restrict__ gb,
    float* __restrict__ wt, float* __restrict__ partials)
{
  const int wave = threadIdx.x >> 6, lane = threadIdx.x & 63;
  const int t = blockIdx.x * 4 + wave;
  float xv[8];
#pragma unroll
  for (int j = 0; j < 8; j++) xv[j] = x1[(size_t)t * EE + lane * 8 + j];
  float pe[8];
  float mx = -1e30f;
#pragma unroll
  for (int e = 0; e < 8; e++) {
    float s = 0.f;
#pragma unroll
    for (int j = 0; j < 8; j++) s += xv[j] * gw[e * EE + lane * 8 + j];
#pragma unroll
    for (int off = 1; off < 64; off <<= 1) s += __shfl_xor(s, off);
    pe[e] = s + gb[e];
    mx = fmaxf(mx, pe[e]);
  }
  float se = 0.f;
#pragma unroll
  for (int e = 0; e < 8; e++) { pe[e] = __expf(pe[e] - mx); se += pe[e]; }
  const float invs = 1.f / se;
#pragma unroll
  for (int e = 0; e < 8; e++) pe[e] *= invs;
  // top-2 (first occurrence wins ties, matching lax.top_k)
  float v1 = -1.f; int i1 = 0;
#pragma unroll
  for (int e = 0; e < 8; e++) if (pe[e] > v1) { v1 = pe[e]; i1 = e; }
  float v2 = -1.f; int i2 = -1;
#pragma unroll
  for (int e = 0; e < 8; e++) if (e != i1 && pe[e] > v2) { v2 = pe[e]; i2 = e; }
  const float denom = 1.f / (v1 + v2);
  if (lane < 8)
    wt[(size_t)t * 8 + lane] = (lane == i1) ? v1 * denom : (lane == i2) ? v2 * denom : 0.f;

  __shared__ float fb[4][8], pb[4][8];
  if (lane < 8) {
    fb[wave][lane] = (lane == i1 || lane == i2) ? 1.f : 0.f;
    pb[wave][lane] = pe[lane];
  }
  __syncthreads();
  if (threadIdx.x < 8) {
    const int e = threadIdx.x;
    partials[(size_t)blockIdx.x * 16 + e]     = fb[0][e] + fb[1][e] + fb[2][e] + fb[3][e];
    partials[(size_t)blockIdx.x * 16 + 8 + e] = pb[0][e] + pb[1][e] + pb[2][e] + pb[3][e];
  }
}

// f32 OUTPUT for the loss scalar
__global__ __launch_bounds__(256) void gate_reduce(
    const float* __restrict__ partials, float* __restrict__ loss_out)
{
  __shared__ float acc[16][16];
  __shared__ float fin[16];
  const int c = threadIdx.x & 15, grp = threadIdx.x >> 4;
  float s = 0.f;
  for (int i = grp; i < 2048; i += 16) s += partials[(size_t)i * 16 + c];
  acc[grp][c] = s;
  __syncthreads();
  if (threadIdx.x < 16) {
    float t2 = 0.f;
    for (int g2 = 0; g2 < 16; g2++) t2 += acc[g2][threadIdx.x];
    fin[threadIdx.x] = t2;
  }
  __syncthreads();
  if (threadIdx.x == 0) {
    float loss = 0.f;
    for (int e = 0; e < 8; e++)
      loss += (fin[e] * (1.f / TT)) * (fin[8 + e] * (1.f / TT));
    loss_out[0] = loss * 8.f;
  }
}

// ---------------- host-side launcher ----------------
extern "C" void kernel_launch(void* const* d_in, const int* in_sizes, int n_in,
                              void* d_out, int out_size, void* d_ws, size_t ws_size,
                              hipStream_t stream) {
  const float* x    = (const float*)d_in[0];
  const float* wq   = (const float*)d_in[1];
  const float* bq   = (const float*)d_in[2];
  const float* wk   = (const float*)d_in[3];
  const float* bk   = (const float*)d_in[4];
  const float* wv   = (const float*)d_in[5];
  const float* bv   = (const float*)d_in[6];
  const float* in_w = (const float*)d_in[7];
  const float* in_b = (const float*)d_in[8];
  const float* out_w= (const float*)d_in[9];
  const float* out_b= (const float*)d_in[10];
  const float* ln1g = (const float*)d_in[11];
  const float* ln1b = (const float*)d_in[12];
  const float* ln2g = (const float*)d_in[13];
  const float* ln2b = (const float*)d_in[14];
  const float* shw  = (const float*)d_in[15];
  const float* shb  = (const float*)d_in[16];
  const float* gw   = (const float*)d_in[17];
  const float* gb   = (const float*)d_in[18];
  const float* expw = (const float*)d_in[19];
  const float* expb = (const float*)d_in[20];

  char* ws = (char*)d_ws;
  // --- static region [0, 17.2 MB) ---
  u16t* xb    = (u16t*)(ws + 0);          // 8 MB   (dead after stage-1)
  u16t* w3    = (u16t*)(ws + 8388608);    // 1.5 MB (dead after stage-1)
  u16t* inwb  = (u16t*)(ws + 9961472);    // 1.5 MB
  u16t* outwb = (u16t*)(ws + 11534336);   // 0.5 MB
  u16t* shwb  = (u16t*)(ws + 12058624);   // 0.5 MB
  u16t* expwb = (u16t*)(ws + 12582912);   // 4 MB
  float* b3   = (float*)(ws + 16777216);  // 6 KB
  float* wtbuf = (float*)(ws + 16783360); // 256 KB
  float* parts = (float*)(ws + 17045504); // 128 KB
  // --- overlay pool (peak 59.1 MB total) ---
  char* P0 = ws + 17176576;               // 24 MB: q0kv -> aob(8)+aop(16) -> x1b(8)+moeb(8)
  char* P1 = ws + 42342400;               // 8 MB:  kb -> x1 (lower half)
  char* P2 = ws + 50731008;               // 8 MB:  vb -> x1 (upper half)

  u16t* q0kv = (u16t*)P0;                       // stage1 -> stage2
  u16t* qb   = (u16t*)(ws + 0);                 // reuses xb (dead)
  u16t* kb   = (u16t*)P1;
  u16t* vb   = (u16t*)P2;
  u16t* aob  = (u16t*)P0;                       // attn out (q0kv dead)
  float* aop = (float*)(P0 + 8388608);          // out-proj f32 (within dead q0kv)
  float* x1  = (float*)P1;                      // 16 MB spans P1+P2 (kb,vb dead)
  u16t* x1b  = (u16t*)P0;                       // aob dead after out-proj
  u16t* shrd = (u16t*)(ws + 0);                 // qb dead after attn
  u16t* moeb = (u16t*)(P0 + 8388608);           // aop dead after ln1
  float* outp = (float*)d_out;                  // f32 output (reference dtype)

  dim3 blk(256);
  // bf16 converts
  cvtk<<<4096, blk, 0, stream>>>(x, xb, TT * EE);
  cvtk<<<256,  blk, 0, stream>>>(wq, w3, EE * EE);
  cvtk<<<256,  blk, 0, stream>>>(wk, w3 + EE * EE, EE * EE);
  cvtk<<<256,  blk, 0, stream>>>(wv, w3 + 2 * EE * EE, EE * EE);
  cvtk<<<768,  blk, 0, stream>>>(in_w, inwb, 3 * EE * EE);
  cvtk<<<256,  blk, 0, stream>>>(out_w, outwb, EE * EE);
  cvtk<<<256,  blk, 0, stream>>>(shw, shwb, EE * EE);
  cvtk<<<2048, blk, 0, stream>>>(expw, expwb, NEXP * EE * EE);
  copy3<<<2,   blk, 0, stream>>>(bq, bk, bv, b3);

  // stage-1 QKV projection (batched, N=1536)
  gemm_bt<0,1><<<dim3(64, 12), blk, 0, stream>>>(xb, EE, w3, b3, q0kv, 1536, EE);
  // stage-2 (MHA in_proj)
  gemm_bt<0,1><<<dim3(64, 4), blk, 0, stream>>>(q0kv,        1536, inwb,               in_b,        qb, EE, EE);
  gemm_bt<0,1><<<dim3(64, 4), blk, 0, stream>>>(q0kv + 512,  1536, inwb + EE * EE,     in_b + 512,  kb, EE, EE);
  gemm_bt<0,1><<<dim3(64, 4), blk, 0, stream>>>(q0kv + 1024, 1536, inwb + 2 * EE * EE, in_b + 1024, vb, EE, EE);
  // attention
  attn_kernel<<<dim3(64, 16), blk, 0, stream>>>(qb, kb, vb, aob);
  // out projection (f32 out)
  gemm_bt<0,0><<<dim3(64, 4), blk, 0, stream>>>(aob, EE, outwb, out_b, aop, EE, EE);
  // LN1
  ln1_kernel<<<8192, blk, 0, stream>>>(x, aop, ln1g, ln1b, x1, x1b);
  // gate + loss
  gate_kernel<<<2048, blk, 0, stream>>>(x1, gw, gb, wtbuf, parts);
  gate_reduce<<<1, blk, 0, stream>>>(parts, outp + (size_t)TT * EE);
  // shared expert (leaky)
  gemm_bt<1,1><<<dim3(64, 4), blk, 0, stream>>>(x1b, EE, shwb, shb, shrd, EE, EE);
  // MoE
  moe_gemm<<<dim3(64, 4), blk, 0, stream>>>(x1b, expwb, expb, wtbuf, moeb);
  // LN2 -> output (f32)
  ln2_kernel<<<8192, blk, 0, stream>>>(x1, moeb, shrd, ln2g, ln2b, outp);
}

// Round 5
// 291.742 us; speedup vs baseline: 1.2459x; 1.1878x over previous
//
#include <hip/hip_runtime.h>
#include <stdint.h>

// Problem dims (fixed)
#define LL   1024
#define BB   8
#define EE   512
#define HH   8
#define HDD  64
#define NEXP 8
#define TT   8192   // L*B tokens

typedef unsigned short u16t;
typedef __bf16 bf16x8 __attribute__((ext_vector_type(8)));
typedef u16t   u16x8  __attribute__((ext_vector_type(8)));
typedef u16t   u16x4  __attribute__((ext_vector_type(4)));
typedef float  f32x4  __attribute__((ext_vector_type(4)));

__device__ __forceinline__ u16t f2bf(float f) {
  union { float f; unsigned int u; } a; a.f = f;
  unsigned int r = a.u + 0x7fffu + ((a.u >> 16) & 1u);
  return (u16t)(r >> 16);
}
__device__ __forceinline__ float bf2f(u16t s) {
  union { unsigned int u; float f; } a; a.u = ((unsigned int)s) << 16; return a.f;
}

__device__ __forceinline__ f32x4 mfma16(bf16x8 a, bf16x8 b, f32x4 c) {
  return __builtin_amdgcn_mfma_f32_16x16x32_bf16(a, b, c, 0, 0, 0);
}

// async global->LDS, 16B per lane; LDS dest linear in tid, global src may be per-lane
#define GLDS16(gp, lp) \
  __builtin_amdgcn_global_load_lds( \
      (const __attribute__((address_space(1))) unsigned int*)(const void*)(gp), \
      (__attribute__((address_space(3))) unsigned int*)(void*)(lp), 16, 0, 0)

// XOR bank swizzle for [*][64] bf16 tiles (128B row stride): u16 idx ^= (row&7)<<3
#define SWZ(row, idx) ((idx) ^ (((row) & 7) << 3))

// ---------------- f32 -> bf16 convert (vectorized) ----------------
__global__ __launch_bounds__(256) void cvtk(const float* __restrict__ s,
                                            u16t* __restrict__ d, int n) {
  int i = (blockIdx.x * 256 + threadIdx.x) * 4;
  if (i < n) {
    float4 v = *(const float4*)&s[i];
    u16x4 o = { f2bf(v.x), f2bf(v.y), f2bf(v.z), f2bf(v.w) };
    *(u16x4*)&d[i] = o;
  }
}

// ---------------- transpose-convert: out[n][j] = bf16(in[j][n]), 512x512, z=3 ----------------
__global__ __launch_bounds__(256) void cvt_t(const float* __restrict__ w0,
                                             const float* __restrict__ w1,
                                             const float* __restrict__ w2,
                                             u16t* __restrict__ out) {
  const float* src = blockIdx.z == 0 ? w0 : blockIdx.z == 1 ? w1 : w2;
  u16t* dst = out + (size_t)blockIdx.z * 262144;
  __shared__ float tile[64][65];
  const int r = threadIdx.x >> 4;          // 0..15
  const int c = (threadIdx.x & 15) * 4;    // 0..60
  const int r0 = blockIdx.y * 64, c0 = blockIdx.x * 64;
#pragma unroll
  for (int i = 0; i < 4; i++) {
    float4 v = *(const float4*)&src[(size_t)(r0 + r + i * 16) * 512 + c0 + c];
    tile[r + i * 16][c] = v.x; tile[r + i * 16][c + 1] = v.y;
    tile[r + i * 16][c + 2] = v.z; tile[r + i * 16][c + 3] = v.w;
  }
  __syncthreads();
#pragma unroll
  for (int i = 0; i < 4; i++) {
    const int orow = c0 + r + i * 16;
    u16x4 o = { f2bf(tile[c][r + i * 16]), f2bf(tile[c + 1][r + i * 16]),
                f2bf(tile[c + 2][r + i * 16]), f2bf(tile[c + 3][r + i * 16]) };
    *(u16x4*)&dst[(size_t)orow * 512 + r0 + c] = o;
  }
}

// ---------------- composed-weight GEMM: C(z) = A(z) @ W(z)^T (no bias), 512^3, bf16 out ----------------
__global__ __launch_bounds__(256) void compose_k(const u16t* __restrict__ Aall,
                                                 const u16t* __restrict__ Wall,
                                                 u16t* __restrict__ Call) {
  const u16t* A = Aall + (size_t)blockIdx.z * 262144;
  const u16t* W = Wall + (size_t)blockIdx.z * 262144;
  u16t* C = Call + (size_t)blockIdx.z * 262144;
  __shared__ alignas(16) u16t As[128 * 32];
  __shared__ alignas(16) u16t Ws[128 * 32];
  const int tid = threadIdx.x;
  const int lane = tid & 63, wave = tid >> 6;
  const int r15 = lane & 15, rhi = lane >> 4;
  const int wr = wave >> 1, wc = wave & 1;
  const int m0 = blockIdx.x * 128, n0 = blockIdx.y * 128;
  const int arow = tid >> 2, acol = (tid & 3) * 8;
  const f32x4 fz = {0.f, 0.f, 0.f, 0.f};
  f32x4 acc[4][4];
#pragma unroll
  for (int i = 0; i < 4; i++)
#pragma unroll
    for (int j = 0; j < 4; j++) acc[i][j] = fz;
  const u16t* Ap0 = A + (size_t)(m0 + arow) * 512 + acol;
  const u16t* Ap1 = Ap0 + (size_t)64 * 512;
  const u16t* Wp0 = W + (size_t)(n0 + arow) * 512 + acol;
  const u16t* Wp1 = Wp0 + (size_t)64 * 512;
  u16t* As0 = &As[tid * 8]; u16t* As1 = &As[(tid + 256) * 8];
  u16t* Ws0 = &Ws[tid * 8]; u16t* Ws1 = &Ws[(tid + 256) * 8];
  for (int kt = 0; kt < 512; kt += 32) {
    __syncthreads();
    GLDS16(Ap0 + kt, As0);
    GLDS16(Ap1 + kt, As1);
    GLDS16(Wp0 + kt, Ws0);
    GLDS16(Wp1 + kt, Ws1);
    asm volatile("s_waitcnt vmcnt(0)" ::: "memory");
    __syncthreads();
    bf16x8 af[4], bfv[4];
#pragma unroll
    for (int mi = 0; mi < 4; mi++)
      af[mi] = *(const bf16x8*)&As[(wr * 64 + mi * 16 + r15) * 32 + rhi * 8];
#pragma unroll
    for (int ni = 0; ni < 4; ni++)
      bfv[ni] = *(const bf16x8*)&Ws[(wc * 64 + ni * 16 + r15) * 32 + rhi * 8];
#pragma unroll
    for (int mi = 0; mi < 4; mi++)
#pragma unroll
      for (int ni = 0; ni < 4; ni++)
        acc[mi][ni] = mfma16(af[mi], bfv[ni], acc[mi][ni]);
  }
#pragma unroll
  for (int mi = 0; mi < 4; mi++)
#pragma unroll
    for (int ni = 0; ni < 4; ni++) {
      const int col = n0 + wc * 64 + ni * 16 + r15;
#pragma unroll
      for (int r = 0; r < 4; r++) {
        const int row = m0 + wr * 64 + mi * 16 + rhi * 4 + r;
        C[(size_t)row * 512 + col] = f2bf(acc[mi][ni][r]);
      }
    }
}

// ---------------- composed bias: b2[seg*512+m] = in_w_seg[m,:] . bvec_seg + in_b[seg*512+m] ----------------
__global__ __launch_bounds__(256) void bias_mv(const float* __restrict__ in_w,
                                               const float* __restrict__ in_b,
                                               const float* __restrict__ b0,
                                               const float* __restrict__ b1,
                                               const float* __restrict__ b2v,
                                               float* __restrict__ out) {
  const int bi = blockIdx.x;                 // 24 blocks
  const int seg = bi >> 3, m0 = (bi & 7) * 64;
  const float* bvec = seg == 0 ? b0 : seg == 1 ? b1 : b2v;
  const int m = m0 + (threadIdx.x >> 2), q = threadIdx.x & 3;
  const float* row = in_w + (size_t)(seg * 512 + m) * 512 + q * 128;
  const float* bv = bvec + q * 128;
  float s = 0.f;
  for (int j = 0; j < 128; j++) s += row[j] * bv[j];
  s += __shfl_xor(s, 1); s += __shfl_xor(s, 2);
  if (q == 0) out[seg * 512 + m] = s + in_b[seg * 512 + m];
}

// ---------------- generic bf16 GEMM: C = A @ W^T + bias ----------------
template<int ACT, int OUTBF>
__global__ __launch_bounds__(256) void gemm_bt(
    const u16t* __restrict__ A, int lda,
    const u16t* __restrict__ W,
    const float* __restrict__ bias,
    void* __restrict__ Cp, int ldc, int K)
{
  __shared__ alignas(16) u16t As[128 * 32];
  __shared__ alignas(16) u16t Ws[128 * 32];
  const int tid  = threadIdx.x;
  const int lane = tid & 63, wave = tid >> 6;
  const int r15  = lane & 15, rhi = lane >> 4;
  const int wr   = wave >> 1, wc  = wave & 1;
  const int m0 = blockIdx.x * 128, n0 = blockIdx.y * 128;
  const int arow = tid >> 2, acol = (tid & 3) * 8;

  const f32x4 fz = {0.f, 0.f, 0.f, 0.f};
  f32x4 acc[4][4];
#pragma unroll
  for (int i = 0; i < 4; i++)
#pragma unroll
    for (int j = 0; j < 4; j++) acc[i][j] = fz;

  const u16t* Ap0 = A + (size_t)(m0 + arow) * lda + acol;
  const u16t* Ap1 = A + (size_t)(m0 + arow + 64) * lda + acol;
  const u16t* Wp0 = W + (size_t)(n0 + arow) * K + acol;
  const u16t* Wp1 = W + (size_t)(n0 + arow + 64) * K + acol;
  u16t* As0 = &As[tid * 8];       u16t* As1 = &As[(tid + 256) * 8];
  u16t* Ws0 = &Ws[tid * 8];       u16t* Ws1 = &Ws[(tid + 256) * 8];

  for (int kt = 0; kt < K; kt += 32) {
    __syncthreads();
    GLDS16(Ap0 + kt, As0);
    GLDS16(Ap1 + kt, As1);
    GLDS16(Wp0 + kt, Ws0);
    GLDS16(Wp1 + kt, Ws1);
    asm volatile("s_waitcnt vmcnt(0)" ::: "memory");
    __syncthreads();
    bf16x8 af[4], bfv[4];
#pragma unroll
    for (int mi = 0; mi < 4; mi++)
      af[mi] = *(const bf16x8*)&As[(wr * 64 + mi * 16 + r15) * 32 + rhi * 8];
#pragma unroll
    for (int ni = 0; ni < 4; ni++)
      bfv[ni] = *(const bf16x8*)&Ws[(wc * 64 + ni * 16 + r15) * 32 + rhi * 8];
#pragma unroll
    for (int mi = 0; mi < 4; mi++)
#pragma unroll
      for (int ni = 0; ni < 4; ni++)
        acc[mi][ni] = mfma16(af[mi], bfv[ni], acc[mi][ni]);
  }

#pragma unroll
  for (int mi = 0; mi < 4; mi++) {
#pragma unroll
    for (int ni = 0; ni < 4; ni++) {
      const int col = n0 + wc * 64 + ni * 16 + r15;
      const float bv = bias[col];
#pragma unroll
      for (int r = 0; r < 4; r++) {
        const int row = m0 + wr * 64 + mi * 16 + rhi * 4 + r;
        float v = acc[mi][ni][r] + bv;
        if (ACT == 1) v = v >= 0.f ? v : 0.01f * v;
        if (OUTBF) ((u16t*)Cp)[(size_t)row * ldc + col] = f2bf(v);
        else       ((float*)Cp)[(size_t)row * ldc + col] = v;
      }
    }
  }
}

// ---------------- sparse MoE: per-expert compacted token tiles ----------------
// grid (NEXP*64, 4); block computes rows [m0,m0+128) of expert e's token list.
// Writes weighted leaky output to out_slots[list_entry] (= 2*token+pos).
__global__ __launch_bounds__(256) void moe_sparse(
    const u16t* __restrict__ x1b, const u16t* __restrict__ Wall,
    const float* __restrict__ ball, const int* __restrict__ counts,
    const int* __restrict__ list, const float* __restrict__ wlist,
    u16t* __restrict__ out_slots)
{
  const int e = blockIdx.x >> 6, mt = blockIdx.x & 63;
  const int cnt = counts[e];
  const int m0 = mt * 128;
  if (m0 >= cnt) return;
  const int n0 = blockIdx.y * 128;
  __shared__ alignas(16) u16t As[128 * 32];
  __shared__ alignas(16) u16t Ws[128 * 32];
  __shared__ int tks[128];
  __shared__ float wws[128];
  const int tid  = threadIdx.x;
  const int lane = tid & 63, wave = tid >> 6;
  const int r15  = lane & 15, rhi = lane >> 4;
  const int wr   = wave >> 1, wc  = wave & 1;
  const int arow = tid >> 2, acol = (tid & 3) * 8;

  if (tid < 128) {
    int idx = m0 + tid; if (idx >= cnt) idx = cnt - 1;
    tks[tid] = list[e * 8192 + idx];
    wws[tid] = wlist[e * 8192 + idx];
  }
  __syncthreads();
  const int tokA = tks[arow] >> 1, tokB = tks[arow + 64] >> 1;

  const f32x4 fz = {0.f, 0.f, 0.f, 0.f};
  f32x4 acc[4][4];
#pragma unroll
  for (int i = 0; i < 4; i++)
#pragma unroll
    for (int j = 0; j < 4; j++) acc[i][j] = fz;

  const u16t* Ap0 = x1b + (size_t)tokA * 512 + acol;
  const u16t* Ap1 = x1b + (size_t)tokB * 512 + acol;
  const u16t* W = Wall + (size_t)e * 262144;
  const u16t* Wp0 = W + (size_t)(n0 + arow) * 512 + acol;
  const u16t* Wp1 = Wp0 + (size_t)64 * 512;
  u16t* As0 = &As[tid * 8];  u16t* As1 = &As[(tid + 256) * 8];
  u16t* Ws0 = &Ws[tid * 8];  u16t* Ws1 = &Ws[(tid + 256) * 8];

  for (int kt = 0; kt < 512; kt += 32) {
    __syncthreads();
    GLDS16(Ap0 + kt, As0);
    GLDS16(Ap1 + kt, As1);
    GLDS16(Wp0 + kt, Ws0);
    GLDS16(Wp1 + kt, Ws1);
    asm volatile("s_waitcnt vmcnt(0)" ::: "memory");
    __syncthreads();
    bf16x8 af[4], bfv[4];
#pragma unroll
    for (int mi = 0; mi < 4; mi++)
      af[mi] = *(const bf16x8*)&As[(wr * 64 + mi * 16 + r15) * 32 + rhi * 8];
#pragma unroll
    for (int ni = 0; ni < 4; ni++)
      bfv[ni] = *(const bf16x8*)&Ws[(wc * 64 + ni * 16 + r15) * 32 + rhi * 8];
#pragma unroll
    for (int mi = 0; mi < 4; mi++)
#pragma unroll
      for (int ni = 0; ni < 4; ni++)
        acc[mi][ni] = mfma16(af[mi], bfv[ni], acc[mi][ni]);
  }

#pragma unroll
  for (int mi = 0; mi < 4; mi++)
#pragma unroll
    for (int ni = 0; ni < 4; ni++) {
      const int col = n0 + wc * 64 + ni * 16 + r15;
      const float bv = ball[e * 512 + col];
#pragma unroll
      for (int r = 0; r < 4; r++) {
        const int rl = wr * 64 + mi * 16 + rhi * 4 + r;
        if (m0 + rl < cnt) {
          float z = acc[mi][ni][r] + bv;
          z = z >= 0.f ? z : 0.01f * z;
          out_slots[(size_t)tks[rl] * 512 + col] = f2bf(wws[rl] * z);
        }
      }
    }
}

// ---------------- flash attention (bf16, HD=64), qkv packed row-stride 1536 ----------------
__global__ __launch_bounds__(256) void attn_kernel(
    const u16t* __restrict__ qkv, u16t* __restrict__ ao)
{
  const int bh = blockIdx.x;
  const int b = bh >> 3, h = bh & 7;
  const int qt = blockIdx.y;
  const int tid  = threadIdx.x;
  const int lane = tid & 63, wave = tid >> 6;
  const int r15  = lane & 15, rhi = lane >> 4;
  __shared__ alignas(16) u16t Ks[64 * 64];      // [kv][d]  (swizzled)
  __shared__ alignas(16) u16t Vt[64 * 64];      // [d][kv]  (swizzled)
  __shared__ alignas(16) u16t Ps[4][16 * 64];   // per-wave P tile (swizzled)

  const int qrowA = qt * 64 + wave * 16 + r15;
  const size_t qoff = ((size_t)qrowA * BB + b) * 1536 + h * HDD;
  bf16x8 qf0 = *(const bf16x8*)&qkv[qoff + rhi * 8];
  bf16x8 qf1 = *(const bf16x8*)&qkv[qoff + 32 + rhi * 8];

  const f32x4 fz = {0.f, 0.f, 0.f, 0.f};
  float mrun[4], lrun[4];
  f32x4 oa[4];
#pragma unroll
  for (int r = 0; r < 4; r++) { mrun[r] = -1e30f; lrun[r] = 0.f; }
#pragma unroll
  for (int d = 0; d < 4; d++) oa[d] = fz;

  const int srow = tid >> 2, scol = (tid & 3) * 8;

  for (int kv0 = 0; kv0 < LL; kv0 += 64) {
    __syncthreads();
    {
      const size_t base = ((size_t)(kv0 + srow) * BB + b) * 1536 + h * HDD + scol;
      *(u16x8*)&Ks[SWZ(srow, srow * 64 + scol)]      = *(const u16x8*)&qkv[base + 512];
      *(u16x8*)&Ks[SWZ(srow, srow * 64 + scol + 32)] = *(const u16x8*)&qkv[base + 512 + 32];
      u16x8 vv0 = *(const u16x8*)&qkv[base + 1024];
      u16x8 vv1 = *(const u16x8*)&qkv[base + 1024 + 32];
#pragma unroll
      for (int j = 0; j < 8; j++) {
        const int rA = scol + j, rB = scol + 32 + j;
        Vt[SWZ(rA, rA * 64 + srow)] = vv0[j];
        Vt[SWZ(rB, rB * 64 + srow)] = vv1[j];
      }
    }
    __syncthreads();

    f32x4 s[4];
#pragma unroll
    for (int nt = 0; nt < 4; nt++) {
      s[nt] = fz;
      const int kr = nt * 16 + r15;
      bf16x8 kb0 = *(const bf16x8*)&Ks[SWZ(kr, kr * 64 + rhi * 8)];
      bf16x8 kb1 = *(const bf16x8*)&Ks[SWZ(kr, kr * 64 + 32 + rhi * 8)];
      s[nt] = mfma16(qf0, kb0, s[nt]);
      s[nt] = mfma16(qf1, kb1, s[nt]);
    }
#pragma unroll
    for (int nt = 0; nt < 4; nt++)
#pragma unroll
      for (int r = 0; r < 4; r++) s[nt][r] *= 0.125f;

    float mx[4];
#pragma unroll
    for (int r = 0; r < 4; r++)
      mx[r] = fmaxf(fmaxf(s[0][r], s[1][r]), fmaxf(s[2][r], s[3][r]));
#pragma unroll
    for (int off = 1; off < 16; off <<= 1)
#pragma unroll
      for (int r = 0; r < 4; r++) mx[r] = fmaxf(mx[r], __shfl_xor(mx[r], off));

    float corr[4], rs[4];
#pragma unroll
    for (int r = 0; r < 4; r++) {
      float mn = fmaxf(mrun[r], mx[r]);
      corr[r] = __expf(mrun[r] - mn);
      mrun[r] = mn;
    }
#pragma unroll
    for (int nt = 0; nt < 4; nt++)
#pragma unroll
      for (int r = 0; r < 4; r++) s[nt][r] = __expf(s[nt][r] - mrun[r]);
#pragma unroll
    for (int r = 0; r < 4; r++) rs[r] = s[0][r] + s[1][r] + s[2][r] + s[3][r];
#pragma unroll
    for (int off = 1; off < 16; off <<= 1)
#pragma unroll
      for (int r = 0; r < 4; r++) rs[r] += __shfl_xor(rs[r], off);
#pragma unroll
    for (int r = 0; r < 4; r++) lrun[r] = lrun[r] * corr[r] + rs[r];
#pragma unroll
    for (int d = 0; d < 4; d++)
#pragma unroll
      for (int r = 0; r < 4; r++) oa[d][r] *= corr[r];

#pragma unroll
    for (int nt = 0; nt < 4; nt++)
#pragma unroll
      for (int r = 0; r < 4; r++) {
        const int pr = rhi * 4 + r;
        Ps[wave][SWZ(pr, pr * 64 + nt * 16 + r15)] = f2bf(s[nt][r]);
      }
    __syncthreads();

    bf16x8 pf0 = *(const bf16x8*)&Ps[wave][SWZ(r15, r15 * 64 + rhi * 8)];
    bf16x8 pf1 = *(const bf16x8*)&Ps[wave][SWZ(r15, r15 * 64 + 32 + rhi * 8)];
#pragma unroll
    for (int d = 0; d < 4; d++) {
      const int vr = d * 16 + r15;
      bf16x8 vb0 = *(const bf16x8*)&Vt[SWZ(vr, vr * 64 + rhi * 8)];
      bf16x8 vb1 = *(const bf16x8*)&Vt[SWZ(vr, vr * 64 + 32 + rhi * 8)];
      oa[d] = mfma16(pf0, vb0, oa[d]);
      oa[d] = mfma16(pf1, vb1, oa[d]);
    }
  }

#pragma unroll
  for (int d = 0; d < 4; d++)
#pragma unroll
    for (int r = 0; r < 4; r++) {
      const int qr = qt * 64 + wave * 16 + rhi * 4 + r;
      float o = oa[d][r] / lrun[r];
      ao[((size_t)qr * BB + b) * EE + h * HDD + d * 16 + r15] = f2bf(o);
    }
}

// ---------------- wave-per-token LayerNorms ----------------
__device__ __forceinline__ float wave_sum(float v) {
#pragma unroll
  for (int off = 1; off < 64; off <<= 1) v += __shfl_xor(v, off);
  return v;
}

__global__ __launch_bounds__(256) void ln1_kernel(
    const float* __restrict__ x, const float* __restrict__ aop,
    const float* __restrict__ g, const float* __restrict__ be,
    float* __restrict__ x1, u16t* __restrict__ x1b)
{
  const int wave = threadIdx.x >> 6, lane = threadIdx.x & 63;
  const int t = blockIdx.x * 4 + wave;
  const size_t base = (size_t)t * EE + lane * 8;
  float4 a0 = *(const float4*)&x[base],   a1 = *(const float4*)&x[base + 4];
  float4 p0 = *(const float4*)&aop[base], p1 = *(const float4*)&aop[base + 4];
  float v[8] = { a0.x + p0.x, a0.y + p0.y, a0.z + p0.z, a0.w + p0.w,
                 a1.x + p1.x, a1.y + p1.y, a1.z + p1.z, a1.w + p1.w };
  float s = 0.f;
#pragma unroll
  for (int i = 0; i < 8; i++) s += v[i];
  const float mean = wave_sum(s) * (1.f / EE);
  float vs = 0.f;
#pragma unroll
  for (int i = 0; i < 8; i++) { v[i] -= mean; vs += v[i] * v[i]; }
  const float inv = rsqrtf(wave_sum(vs) * (1.f / EE) + 1e-5f);
  float4 g0 = *(const float4*)&g[lane * 8],  g1 = *(const float4*)&g[lane * 8 + 4];
  float4 b0 = *(const float4*)&be[lane * 8], b1 = *(const float4*)&be[lane * 8 + 4];
  float o[8] = { v[0]*inv*g0.x + b0.x, v[1]*inv*g0.y + b0.y, v[2]*inv*g0.z + b0.z, v[3]*inv*g0.w + b0.w,
                 v[4]*inv*g1.x + b1.x, v[5]*inv*g1.y + b1.y, v[6]*inv*g1.z + b1.z, v[7]*inv*g1.w + b1.w };
  *(float4*)&x1[base]     = make_float4(o[0], o[1], o[2], o[3]);
  *(float4*)&x1[base + 4] = make_float4(o[4], o[5], o[6], o[7]);
  u16x8 ob = { f2bf(o[0]), f2bf(o[1]), f2bf(o[2]), f2bf(o[3]),
               f2bf(o[4]), f2bf(o[5]), f2bf(o[6]), f2bf(o[7]) };
  *(u16x8*)&x1b[base] = ob;
}

__global__ __launch_bounds__(256) void ln2_kernel(
    const float* __restrict__ x1, const u16t* __restrict__ slots,
    const u16t* __restrict__ sh,
    const float* __restrict__ g, const float* __restrict__ be,
    float* __restrict__ out)
{
  const int wave = threadIdx.x >> 6, lane = threadIdx.x & 63;
  const int t = blockIdx.x * 4 + wave;
  const size_t base = (size_t)t * EE + lane * 8;
  float4 a0 = *(const float4*)&x1[base], a1 = *(const float4*)&x1[base + 4];
  u16x8 m0 = *(const u16x8*)&slots[(size_t)(2 * t) * EE + lane * 8];
  u16x8 m1 = *(const u16x8*)&slots[(size_t)(2 * t + 1) * EE + lane * 8];
  u16x8 sv = *(const u16x8*)&sh[base];
  float v[8] = { a0.x, a0.y, a0.z, a0.w, a1.x, a1.y, a1.z, a1.w };
#pragma unroll
  for (int i = 0; i < 8; i++) v[i] += bf2f(m0[i]) + bf2f(m1[i]) + bf2f(sv[i]);
  float s = 0.f;
#pragma unroll
  for (int i = 0; i < 8; i++) s += v[i];
  const float mean = wave_sum(s) * (1.f / EE);
  float vs = 0.f;
#pragma unroll
  for (int i = 0; i < 8; i++) { v[i] -= mean; vs += v[i] * v[i]; }
  const float inv = rsqrtf(wave_sum(vs) * (1.f / EE) + 1e-5f);
  float4 g0 = *(const float4*)&g[lane * 8],  g1 = *(const float4*)&g[lane * 8 + 4];
  float4 b0 = *(const float4*)&be[lane * 8], b1 = *(const float4*)&be[lane * 8 + 4];
  *(float4*)&out[base] = make_float4(v[0]*inv*g0.x + b0.x, v[1]*inv*g0.y + b0.y,
                                     v[2]*inv*g0.z + b0.z, v[3]*inv*g0.w + b0.w);
  *(float4*)&out[base + 4] = make_float4(v[4]*inv*g1.x + b1.x, v[5]*inv*g1.y + b1.y,
                                         v[6]*inv*g1.z + b1.z, v[7]*inv*g1.w + b1.w);
}

// ---------------- gate: softmax over 8, top-2, per-token pack + loss partials ----------------
__global__ __launch_bounds__(256) void gate_kernel(
    const float* __restrict__ x1, const float* __restrict__ gw,
    const float* __restrict__ gb,
    int* __restrict__ tok_pack, float2* __restrict__ tok_w,
    float* __restrict__ partials)
{
  const int wave = threadIdx.x >> 6, lane = threadIdx.x & 63;
  const int t = blockIdx.x * 4 + wave;
  float4 xa = *(const float4*)&x1[(size_t)t * EE + lane * 8];
  float4 xb2 = *(const float4*)&x1[(size_t)t * EE + lane * 8 + 4];
  float pe[8];
  float mx = -1e30f;
#pragma unroll
  for (int e = 0; e < 8; e++) {
    float4 ga = *(const float4*)&gw[e * EE + lane * 8];
    float4 gB = *(const float4*)&gw[e * EE + lane * 8 + 4];
    float s = xa.x*ga.x + xa.y*ga.y + xa.z*ga.z + xa.w*ga.w
            + xb2.x*gB.x + xb2.y*gB.y + xb2.z*gB.z + xb2.w*gB.w;
#pragma unroll
    for (int off = 1; off < 64; off <<= 1) s += __shfl_xor(s, off);
    pe[e] = s + gb[e];
    mx = fmaxf(mx, pe[e]);
  }
  float se = 0.f;
#pragma unroll
  for (int e = 0; e < 8; e++) { pe[e] = __expf(pe[e] - mx); se += pe[e]; }
  const float invs = 1.f / se;
#pragma unroll
  for (int e = 0; e < 8; e++) pe[e] *= invs;
  float v1 = -1.f; int i1 = 0;
#pragma unroll
  for (int e = 0; e < 8; e++) if (pe[e] > v1) { v1 = pe[e]; i1 = e; }
  float v2 = -1.f; int i2 = -1;
#pragma unroll
  for (int e = 0; e < 8; e++) if (e != i1 && pe[e] > v2) { v2 = pe[e]; i2 = e; }
  const float denom = 1.f / (v1 + v2);
  if (lane == 0) {
    tok_pack[t] = i1 | (i2 << 8);
    float2 w; w.x = v1 * denom; w.y = v2 * denom;
    tok_w[t] = w;
  }
  __shared__ float fb[4][8], pb[4][8];
  if (lane < 8) {
    fb[wave][lane] = (lane == i1 || lane == i2) ? 1.f : 0.f;
    pb[wave][lane] = pe[lane];
  }
  __syncthreads();
  if (threadIdx.x < 8) {
    const int e = threadIdx.x;
    partials[(size_t)blockIdx.x * 16 + e]     = fb[0][e] + fb[1][e] + fb[2][e] + fb[3][e];
    partials[(size_t)blockIdx.x * 16 + 8 + e] = pb[0][e] + pb[1][e] + pb[2][e] + pb[3][e];
  }
}

// ---------------- deterministic list build: 1 block per expert, ballot-scan ----------------
__global__ __launch_bounds__(256) void build_lists(
    const int* __restrict__ tok_pack, const float2* __restrict__ tok_w,
    int* __restrict__ counts, int* __restrict__ list, float* __restrict__ wlist)
{
  const int e = blockIdx.x;
  const int tid = threadIdx.x;
  const int lane = tid & 63, wave = tid >> 6;
  __shared__ int wtot[4];
  __shared__ int runb;
  if (tid == 0) runb = 0;
  __syncthreads();
  for (int c = 0; c < 32; c++) {
    const int t = c * 256 + tid;
    const int pk = tok_pack[t];
    const int i1 = pk & 255, i2 = (pk >> 8) & 255;
    const bool s1 = (i1 == e);
    const bool flag = s1 || (i2 == e);
    const unsigned long long mask = __ballot(flag);
    if (lane == 63) wtot[wave] = __popcll(mask);
    __syncthreads();
    int wbase = 0;
#pragma unroll
    for (int w2 = 0; w2 < 4; w2++) if (w2 < wave) wbase += wtot[w2];
    const int btot = wtot[0] + wtot[1] + wtot[2] + wtot[3];
    if (flag) {
      const int pre = __popcll(mask & ((1ull << lane) - 1ull));
      const int pos = runb + wbase + pre;
      list[e * 8192 + pos] = 2 * t + (s1 ? 0 : 1);
      float2 w = tok_w[t];
      wlist[e * 8192 + pos] = s1 ? w.x : w.y;
    }
    __syncthreads();
    if (tid == 0) runb += btot;
    __syncthreads();
  }
  if (tid == 0) counts[e] = runb;
}

__global__ __launch_bounds__(256) void gate_reduce(
    const float* __restrict__ partials, float* __restrict__ loss_out)
{
  __shared__ float acc[16][16];
  __shared__ float fin[16];
  const int c = threadIdx.x & 15, grp = threadIdx.x >> 4;
  float s = 0.f;
  for (int i = grp; i < 2048; i += 16) s += partials[(size_t)i * 16 + c];
  acc[grp][c] = s;
  __syncthreads();
  if (threadIdx.x < 16) {
    float t2 = 0.f;
    for (int g2 = 0; g2 < 16; g2++) t2 += acc[g2][threadIdx.x];
    fin[threadIdx.x] = t2;
  }
  __syncthreads();
  if (threadIdx.x == 0) {
    float loss = 0.f;
    for (int e = 0; e < 8; e++)
      loss += (fin[e] * (1.f / TT)) * (fin[8 + e] * (1.f / TT));
    loss_out[0] = loss * 8.f;
  }
}

// ---------------- host-side launcher ----------------
extern "C" void kernel_launch(void* const* d_in, const int* in_sizes, int n_in,
                              void* d_out, int out_size, void* d_ws, size_t ws_size,
                              hipStream_t stream) {
  const float* x    = (const float*)d_in[0];
  const float* wq   = (const float*)d_in[1];
  const float* bq   = (const float*)d_in[2];
  const float* wk   = (const float*)d_in[3];
  const float* bk   = (const float*)d_in[4];
  const float* wv   = (const float*)d_in[5];
  const float* bv   = (const float*)d_in[6];
  const float* in_w = (const float*)d_in[7];
  const float* in_b = (const float*)d_in[8];
  const float* out_w= (const float*)d_in[9];
  const float* out_b= (const float*)d_in[10];
  const float* ln1g = (const float*)d_in[11];
  const float* ln1b = (const float*)d_in[12];
  const float* ln2g = (const float*)d_in[13];
  const float* ln2b = (const float*)d_in[14];
  const float* shw  = (const float*)d_in[15];
  const float* shb  = (const float*)d_in[16];
  const float* gw   = (const float*)d_in[17];
  const float* gb   = (const float*)d_in[18];
  const float* expw = (const float*)d_in[19];
  const float* expb = (const float*)d_in[20];

  char* ws = (char*)d_ws;
  // --- static region ---
  u16t* xb     = (u16t*)(ws + 0);          // 8 MB
  u16t* inwb   = (u16t*)(ws + 8388608);    // 1.5 MB bf16(in_w)
  u16t* w3t    = (u16t*)(ws + 9961472);    // 1.5 MB bf16(wq^T|wk^T|wv^T)
  u16t* w2big  = (u16t*)(ws + 11534336);   // 1.5 MB composed [1536][512]
  u16t* outwb  = (u16t*)(ws + 13107200);   // 0.5 MB
  u16t* shwb   = (u16t*)(ws + 13631488);   // 0.5 MB
  u16t* expwb  = (u16t*)(ws + 14155776);   // 4 MB
  float* b2    = (float*)(ws + 18350080);  // 6 KB composed bias
  int*  tok_pack = (int*)(ws + 18356224);  // 32 KB
  float2* tok_w  = (float2*)(ws + 18388992); // 64 KB
  int*  counts = (int*)(ws + 18454528);    // 128 B
  int*  list   = (int*)(ws + 18454656);    // 256 KB
  float* wlist = (float*)(ws + 18716800);  // 256 KB
  float* parts = (float*)(ws + 18978944);  // 128 KB
  // --- overlay pool (peak ~61 MB) ---
  const size_t S = 19110016;
  u16t* qkvb   = (u16t*)(ws + S);                 // 24 MB: stage1 -> attn
  float* aop   = (float*)(ws + S);                // 16 MB: outproj -> ln1 (qkvb dead)
  u16t* x1b    = (u16t*)(ws + S + 16777216);      // 8 MB: ln1 -> shared/moe
  u16t* oslots = (u16t*)(ws + S);                 // 16 MB: moe -> ln2 (aop dead)
  float* x1    = (float*)(ws + S + 25165824);     // 16 MB: ln1 -> ln2
  u16t* aob    = (u16t*)(ws + 0);                 // 8 MB: attn -> outproj (xb dead)
  u16t* shrd   = (u16t*)(ws + 0);                 // 8 MB: shared -> ln2 (aob dead)
  float* outp  = (float*)d_out;

  dim3 blk(256);
  // converts
  cvtk<<<4096, blk, 0, stream>>>(x, xb, TT * EE);
  cvtk<<<768,  blk, 0, stream>>>(in_w, inwb, 3 * EE * EE);
  cvtk<<<256,  blk, 0, stream>>>(out_w, outwb, EE * EE);
  cvtk<<<256,  blk, 0, stream>>>(shw, shwb, EE * EE);
  cvtk<<<2048, blk, 0, stream>>>(expw, expwb, NEXP * EE * EE);
  cvt_t<<<dim3(8, 8, 3), blk, 0, stream>>>(wq, wk, wv, w3t);
  // weight/bias composition: W2 = in_w_seg @ w_seg, b2 = in_w_seg @ b_seg + in_b_seg
  compose_k<<<dim3(4, 4, 3), blk, 0, stream>>>(inwb, w3t, w2big);
  bias_mv<<<24, blk, 0, stream>>>(in_w, in_b, bq, bk, bv, b2);
  // fused QKV projection: x @ W2^T + b2 -> q|k|v packed (ldc 1536)
  gemm_bt<0,1><<<dim3(64, 12), blk, 0, stream>>>(xb, EE, w2big, b2, qkvb, 1536, EE);
  // attention
  attn_kernel<<<dim3(64, 16), blk, 0, stream>>>(qkvb, aob);
  // out projection (f32 out)
  gemm_bt<0,0><<<dim3(64, 4), blk, 0, stream>>>(aob, EE, outwb, out_b, aop, EE, EE);
  // LN1
  ln1_kernel<<<2048, blk, 0, stream>>>(x, aop, ln1g, ln1b, x1, x1b);
  // gate + deterministic list build + loss
  gate_kernel<<<2048, blk, 0, stream>>>(x1, gw, gb, tok_pack, tok_w, parts);
  build_lists<<<8, blk, 0, stream>>>(tok_pack, tok_w, counts, list, wlist);
  gate_reduce<<<1, blk, 0, stream>>>(parts, outp + (size_t)TT * EE);
  // shared expert (leaky)
  gemm_bt<1,1><<<dim3(64, 4), blk, 0, stream>>>(x1b, EE, shwb, shb, shrd, EE, EE);
  // sparse MoE
  moe_sparse<<<dim3(512, 4), blk, 0, stream>>>(x1b, expwb, expb, counts, list, wlist, oslots);
  // LN2 -> output (f32)
  ln2_kernel<<<2048, blk, 0, stream>>>(x1, oslots, shrd, ln2g, ln2b, outp);
}

// Round 6
// 263.564 us; speedup vs baseline: 1.3791x; 1.1069x over previous
//
#include <hip/hip_runtime.h>
#include <stdint.h>

// Problem dims (fixed)
#define LL   1024
#define BB   8
#define EE   512
#define HH   8
#define HDD  64
#define NEXP 8
#define TT   8192   // L*B tokens

typedef unsigned short u16t;
typedef __bf16 bf16x8 __attribute__((ext_vector_type(8)));
typedef u16t   u16x8  __attribute__((ext_vector_type(8)));
typedef u16t   u16x4  __attribute__((ext_vector_type(4)));
typedef float  f32x4  __attribute__((ext_vector_type(4)));

__device__ __forceinline__ u16t f2bf(float f) {
  union { float f; unsigned int u; } a; a.f = f;
  unsigned int r = a.u + 0x7fffu + ((a.u >> 16) & 1u);
  return (u16t)(r >> 16);
}
__device__ __forceinline__ float bf2f(u16t s) {
  union { unsigned int u; float f; } a; a.u = ((unsigned int)s) << 16; return a.f;
}

__device__ __forceinline__ f32x4 mfma16(bf16x8 a, bf16x8 b, f32x4 c) {
  return __builtin_amdgcn_mfma_f32_16x16x32_bf16(a, b, c, 0, 0, 0);
}

// async global->LDS, 16B per lane; LDS dest linear in tid, global src may be per-lane
#define GLDS16(gp, lp) \
  __builtin_amdgcn_global_load_lds( \
      (const __attribute__((address_space(1))) unsigned int*)(const void*)(gp), \
      (__attribute__((address_space(3))) unsigned int*)(void*)(lp), 16, 0, 0)

// ---------------- f32 -> bf16 convert (vectorized) ----------------
__global__ __launch_bounds__(256) void cvtk(const float* __restrict__ s,
                                            u16t* __restrict__ d, int n) {
  int i = (blockIdx.x * 256 + threadIdx.x) * 4;
  if (i < n) {
    float4 v = *(const float4*)&s[i];
    u16x4 o = { f2bf(v.x), f2bf(v.y), f2bf(v.z), f2bf(v.w) };
    *(u16x4*)&d[i] = o;
  }
}

// ---------------- transpose-convert: out[n][j] = bf16(in[j][n]), 512x512, z=3 ----------------
__global__ __launch_bounds__(256) void cvt_t(const float* __restrict__ w0,
                                             const float* __restrict__ w1,
                                             const float* __restrict__ w2,
                                             u16t* __restrict__ out) {
  const float* src = blockIdx.z == 0 ? w0 : blockIdx.z == 1 ? w1 : w2;
  u16t* dst = out + (size_t)blockIdx.z * 262144;
  __shared__ float tile[64][65];
  const int r = threadIdx.x >> 4;          // 0..15
  const int c = (threadIdx.x & 15) * 4;    // 0..60
  const int r0 = blockIdx.y * 64, c0 = blockIdx.x * 64;
#pragma unroll
  for (int i = 0; i < 4; i++) {
    float4 v = *(const float4*)&src[(size_t)(r0 + r + i * 16) * 512 + c0 + c];
    tile[r + i * 16][c] = v.x; tile[r + i * 16][c + 1] = v.y;
    tile[r + i * 16][c + 2] = v.z; tile[r + i * 16][c + 3] = v.w;
  }
  __syncthreads();
#pragma unroll
  for (int i = 0; i < 4; i++) {
    const int orow = c0 + r + i * 16;
    u16x4 o = { f2bf(tile[c][r + i * 16]), f2bf(tile[c + 1][r + i * 16]),
                f2bf(tile[c + 2][r + i * 16]), f2bf(tile[c + 3][r + i * 16]) };
    *(u16x4*)&dst[(size_t)orow * 512 + r0 + c] = o;
  }
}

// ---------------- composed-weight GEMM: C(z) = A(z) @ W(z)^T (no bias), 512^3, bf16 out ----------------
__global__ __launch_bounds__(256) void compose_k(const u16t* __restrict__ Aall,
                                                 const u16t* __restrict__ Wall,
                                                 u16t* __restrict__ Call) {
  const u16t* A = Aall + (size_t)blockIdx.z * 262144;
  const u16t* W = Wall + (size_t)blockIdx.z * 262144;
  u16t* C = Call + (size_t)blockIdx.z * 262144;
  __shared__ alignas(16) u16t As[128 * 32];
  __shared__ alignas(16) u16t Ws[128 * 32];
  const int tid = threadIdx.x;
  const int lane = tid & 63, wave = tid >> 6;
  const int r15 = lane & 15, rhi = lane >> 4;
  const int wr = wave >> 1, wc = wave & 1;
  const int m0 = blockIdx.x * 128, n0 = blockIdx.y * 128;
  const int arow = tid >> 2, acol = (tid & 3) * 8;
  const f32x4 fz = {0.f, 0.f, 0.f, 0.f};
  f32x4 acc[4][4];
#pragma unroll
  for (int i = 0; i < 4; i++)
#pragma unroll
    for (int j = 0; j < 4; j++) acc[i][j] = fz;
  const u16t* Ap0 = A + (size_t)(m0 + arow) * 512 + acol;
  const u16t* Ap1 = Ap0 + (size_t)64 * 512;
  const u16t* Wp0 = W + (size_t)(n0 + arow) * 512 + acol;
  const u16t* Wp1 = Wp0 + (size_t)64 * 512;
  u16t* As0 = &As[tid * 8]; u16t* As1 = &As[(tid + 256) * 8];
  u16t* Ws0 = &Ws[tid * 8]; u16t* Ws1 = &Ws[(tid + 256) * 8];
  for (int kt = 0; kt < 512; kt += 32) {
    __syncthreads();
    GLDS16(Ap0 + kt, As0);
    GLDS16(Ap1 + kt, As1);
    GLDS16(Wp0 + kt, Ws0);
    GLDS16(Wp1 + kt, Ws1);
    asm volatile("s_waitcnt vmcnt(0)" ::: "memory");
    __syncthreads();
    bf16x8 af[4], bfv[4];
#pragma unroll
    for (int mi = 0; mi < 4; mi++)
      af[mi] = *(const bf16x8*)&As[(wr * 64 + mi * 16 + r15) * 32 + rhi * 8];
#pragma unroll
    for (int ni = 0; ni < 4; ni++)
      bfv[ni] = *(const bf16x8*)&Ws[(wc * 64 + ni * 16 + r15) * 32 + rhi * 8];
#pragma unroll
    for (int mi = 0; mi < 4; mi++)
#pragma unroll
      for (int ni = 0; ni < 4; ni++)
        acc[mi][ni] = mfma16(af[mi], bfv[ni], acc[mi][ni]);
  }
#pragma unroll
  for (int mi = 0; mi < 4; mi++)
#pragma unroll
    for (int ni = 0; ni < 4; ni++) {
      const int col = n0 + wc * 64 + ni * 16 + r15;
#pragma unroll
      for (int r = 0; r < 4; r++) {
        const int row = m0 + wr * 64 + mi * 16 + rhi * 4 + r;
        C[(size_t)row * 512 + col] = f2bf(acc[mi][ni][r]);
      }
    }
}

// ---------------- composed bias: b2[seg*512+m] = in_w_seg[m,:] . bvec_seg + in_b[seg*512+m] ----------------
__global__ __launch_bounds__(256) void bias_mv(const float* __restrict__ in_w,
                                               const float* __restrict__ in_b,
                                               const float* __restrict__ b0,
                                               const float* __restrict__ b1,
                                               const float* __restrict__ b2v,
                                               float* __restrict__ out) {
  const int bi = blockIdx.x;                 // 24 blocks
  const int seg = bi >> 3, m0 = (bi & 7) * 64;
  const float* bvec = seg == 0 ? b0 : seg == 1 ? b1 : b2v;
  const int m = m0 + (threadIdx.x >> 2), q = threadIdx.x & 3;
  const float* row = in_w + (size_t)(seg * 512 + m) * 512 + q * 128;
  const float* bv = bvec + q * 128;
  float s = 0.f;
  for (int j = 0; j < 128; j++) s += row[j] * bv[j];
  s += __shfl_xor(s, 1); s += __shfl_xor(s, 2);
  if (q == 0) out[seg * 512 + m] = s + in_b[seg * 512 + m];
}

// ---------------- generic bf16 GEMM: C = A @ W^T + bias ----------------
template<int ACT, int OUTBF>
__global__ __launch_bounds__(256) void gemm_bt(
    const u16t* __restrict__ A, int lda,
    const u16t* __restrict__ W,
    const float* __restrict__ bias,
    void* __restrict__ Cp, int ldc, int K)
{
  __shared__ alignas(16) u16t As[128 * 32];
  __shared__ alignas(16) u16t Ws[128 * 32];
  const int tid  = threadIdx.x;
  const int lane = tid & 63, wave = tid >> 6;
  const int r15  = lane & 15, rhi = lane >> 4;
  const int wr   = wave >> 1, wc  = wave & 1;
  const int m0 = blockIdx.x * 128, n0 = blockIdx.y * 128;
  const int arow = tid >> 2, acol = (tid & 3) * 8;

  const f32x4 fz = {0.f, 0.f, 0.f, 0.f};
  f32x4 acc[4][4];
#pragma unroll
  for (int i = 0; i < 4; i++)
#pragma unroll
    for (int j = 0; j < 4; j++) acc[i][j] = fz;

  const u16t* Ap0 = A + (size_t)(m0 + arow) * lda + acol;
  const u16t* Ap1 = A + (size_t)(m0 + arow + 64) * lda + acol;
  const u16t* Wp0 = W + (size_t)(n0 + arow) * K + acol;
  const u16t* Wp1 = W + (size_t)(n0 + arow + 64) * K + acol;
  u16t* As0 = &As[tid * 8];       u16t* As1 = &As[(tid + 256) * 8];
  u16t* Ws0 = &Ws[tid * 8];       u16t* Ws1 = &Ws[(tid + 256) * 8];

  for (int kt = 0; kt < K; kt += 32) {
    __syncthreads();
    GLDS16(Ap0 + kt, As0);
    GLDS16(Ap1 + kt, As1);
    GLDS16(Wp0 + kt, Ws0);
    GLDS16(Wp1 + kt, Ws1);
    asm volatile("s_waitcnt vmcnt(0)" ::: "memory");
    __syncthreads();
    bf16x8 af[4], bfv[4];
#pragma unroll
    for (int mi = 0; mi < 4; mi++)
      af[mi] = *(const bf16x8*)&As[(wr * 64 + mi * 16 + r15) * 32 + rhi * 8];
#pragma unroll
    for (int ni = 0; ni < 4; ni++)
      bfv[ni] = *(const bf16x8*)&Ws[(wc * 64 + ni * 16 + r15) * 32 + rhi * 8];
#pragma unroll
    for (int mi = 0; mi < 4; mi++)
#pragma unroll
      for (int ni = 0; ni < 4; ni++)
        acc[mi][ni] = mfma16(af[mi], bfv[ni], acc[mi][ni]);
  }

#pragma unroll
  for (int mi = 0; mi < 4; mi++) {
#pragma unroll
    for (int ni = 0; ni < 4; ni++) {
      const int col = n0 + wc * 64 + ni * 16 + r15;
      const float bv = bias[col];
#pragma unroll
      for (int r = 0; r < 4; r++) {
        const int row = m0 + wr * 64 + mi * 16 + rhi * 4 + r;
        float v = acc[mi][ni][r] + bv;
        if (ACT == 1) v = v >= 0.f ? v : 0.01f * v;
        if (OUTBF) ((u16t*)Cp)[(size_t)row * ldc + col] = f2bf(v);
        else       ((float*)Cp)[(size_t)row * ldc + col] = v;
      }
    }
  }
}

// ---------------- sparse MoE: per-expert compacted token tiles ----------------
__global__ __launch_bounds__(256) void moe_sparse(
    const u16t* __restrict__ x1b, const u16t* __restrict__ Wall,
    const float* __restrict__ ball, const int* __restrict__ counts,
    const int* __restrict__ list, const float* __restrict__ wlist,
    u16t* __restrict__ out_slots)
{
  const int e = blockIdx.x >> 6, mt = blockIdx.x & 63;
  const int cnt = counts[e];
  const int m0 = mt * 128;
  if (m0 >= cnt) return;
  const int n0 = blockIdx.y * 128;
  __shared__ alignas(16) u16t As[128 * 32];
  __shared__ alignas(16) u16t Ws[128 * 32];
  __shared__ int tks[128];
  __shared__ float wws[128];
  const int tid  = threadIdx.x;
  const int lane = tid & 63, wave = tid >> 6;
  const int r15  = lane & 15, rhi = lane >> 4;
  const int wr   = wave >> 1, wc  = wave & 1;
  const int arow = tid >> 2, acol = (tid & 3) * 8;

  if (tid < 128) {
    int idx = m0 + tid; if (idx >= cnt) idx = cnt - 1;
    tks[tid] = list[e * 8192 + idx];
    wws[tid] = wlist[e * 8192 + idx];
  }
  __syncthreads();
  const int tokA = tks[arow] >> 1, tokB = tks[arow + 64] >> 1;

  const f32x4 fz = {0.f, 0.f, 0.f, 0.f};
  f32x4 acc[4][4];
#pragma unroll
  for (int i = 0; i < 4; i++)
#pragma unroll
    for (int j = 0; j < 4; j++) acc[i][j] = fz;

  const u16t* Ap0 = x1b + (size_t)tokA * 512 + acol;
  const u16t* Ap1 = x1b + (size_t)tokB * 512 + acol;
  const u16t* W = Wall + (size_t)e * 262144;
  const u16t* Wp0 = W + (size_t)(n0 + arow) * 512 + acol;
  const u16t* Wp1 = Wp0 + (size_t)64 * 512;
  u16t* As0 = &As[tid * 8];  u16t* As1 = &As[(tid + 256) * 8];
  u16t* Ws0 = &Ws[tid * 8];  u16t* Ws1 = &Ws[(tid + 256) * 8];

  for (int kt = 0; kt < 512; kt += 32) {
    __syncthreads();
    GLDS16(Ap0 + kt, As0);
    GLDS16(Ap1 + kt, As1);
    GLDS16(Wp0 + kt, Ws0);
    GLDS16(Wp1 + kt, Ws1);
    asm volatile("s_waitcnt vmcnt(0)" ::: "memory");
    __syncthreads();
    bf16x8 af[4], bfv[4];
#pragma unroll
    for (int mi = 0; mi < 4; mi++)
      af[mi] = *(const bf16x8*)&As[(wr * 64 + mi * 16 + r15) * 32 + rhi * 8];
#pragma unroll
    for (int ni = 0; ni < 4; ni++)
      bfv[ni] = *(const bf16x8*)&Ws[(wc * 64 + ni * 16 + r15) * 32 + rhi * 8];
#pragma unroll
    for (int mi = 0; mi < 4; mi++)
#pragma unroll
      for (int ni = 0; ni < 4; ni++)
        acc[mi][ni] = mfma16(af[mi], bfv[ni], acc[mi][ni]);
  }

#pragma unroll
  for (int mi = 0; mi < 4; mi++)
#pragma unroll
    for (int ni = 0; ni < 4; ni++) {
      const int col = n0 + wc * 64 + ni * 16 + r15;
      const float bv = ball[e * 512 + col];
#pragma unroll
      for (int r = 0; r < 4; r++) {
        const int rl = wr * 64 + mi * 16 + rhi * 4 + r;
        if (m0 + rl < cnt) {
          float z = acc[mi][ni][r] + bv;
          z = z >= 0.f ? z : 0.01f * z;
          out_slots[(size_t)tks[rl] * 512 + col] = f2bf(wws[rl] * z);
        }
      }
    }
}

// ---------------- flash attention v2: swapped QK^T, lane-local P, no-max softmax ----------------
// grid (B*H, L/64), block 256 = 4 waves; wave owns 16 q-rows (q = lane&15).
// KVBLK=128, padded LDS (conflict-free), T14 prefetch.
__global__ __launch_bounds__(256) void attn_kernel(
    const u16t* __restrict__ qkv, u16t* __restrict__ ao)
{
  const int bh = blockIdx.x;
  const int b = bh >> 3, h = bh & 7;
  const int qt = blockIdx.y;
  const int tid  = threadIdx.x;
  const int lane = tid & 63, wave = tid >> 6;
  const int r15  = lane & 15, rhi = lane >> 4;

  __shared__ alignas(16) u16t Ks[128 * 72];   // [kv][72] padded
  __shared__ alignas(16) u16t Vt[64 * 136];   // [d][136] padded (transposed V)

  // Q as B-operand: lane holds Q[q = r15][d = rhi*8 + j (+32)]
  const int qrow = qt * 64 + wave * 16 + r15;
  const size_t qoff = ((size_t)qrow * BB + b) * 1536 + h * HDD;
  const bf16x8 qf0 = *(const bf16x8*)&qkv[qoff + rhi * 8];
  const bf16x8 qf1 = *(const bf16x8*)&qkv[qoff + 32 + rhi * 8];

  const f32x4 fz = {0.f, 0.f, 0.f, 0.f};
  f32x4 oa[4] = {fz, fz, fz, fz};
  float psum = 0.f;

  // staging roles
  const int krow = tid >> 1, khalf = tid & 1;   // K: one row, one 32-col half
  const int vd0 = wave * 16;                    // V: wave owns 16 d-cols; lane owns kv pair

  // prefetch tile 0
  u16x8 kA0, kA1, kA2, kA3, vA0, vA1, vA2, vA3;
  {
    const size_t kb = ((size_t)krow * BB + b) * 1536 + h * HDD + 512 + khalf * 32;
    kA0 = *(const u16x8*)&qkv[kb];      kA1 = *(const u16x8*)&qkv[kb + 8];
    kA2 = *(const u16x8*)&qkv[kb + 16]; kA3 = *(const u16x8*)&qkv[kb + 24];
    const size_t v0 = ((size_t)(2 * lane) * BB + b) * 1536 + h * HDD + 1024 + vd0;
    const size_t v1 = v0 + (size_t)BB * 1536;
    vA0 = *(const u16x8*)&qkv[v0]; vA1 = *(const u16x8*)&qkv[v0 + 8];
    vA2 = *(const u16x8*)&qkv[v1]; vA3 = *(const u16x8*)&qkv[v1 + 8];
  }

  for (int t = 0; t < 8; t++) {
    __syncthreads();   // prev tile's readers done
    {
      u16t* kd = &Ks[krow * 72 + khalf * 32];
      *(u16x8*)&kd[0]  = kA0; *(u16x8*)&kd[8]  = kA1;
      *(u16x8*)&kd[16] = kA2; *(u16x8*)&kd[24] = kA3;
    }
#pragma unroll
    for (int j = 0; j < 8; j++) {
      unsigned int w = (unsigned int)vA0[j] | ((unsigned int)vA2[j] << 16);
      *(unsigned int*)&Vt[(vd0 + j) * 136 + 2 * lane] = w;
    }
#pragma unroll
    for (int j = 0; j < 8; j++) {
      unsigned int w = (unsigned int)vA1[j] | ((unsigned int)vA3[j] << 16);
      *(unsigned int*)&Vt[(vd0 + 8 + j) * 136 + 2 * lane] = w;
    }
    if (t < 7) {  // prefetch next tile (latency hides under compute)
      const int kv0n = (t + 1) * 128;
      const size_t kb = ((size_t)(kv0n + krow) * BB + b) * 1536 + h * HDD + 512 + khalf * 32;
      kA0 = *(const u16x8*)&qkv[kb];      kA1 = *(const u16x8*)&qkv[kb + 8];
      kA2 = *(const u16x8*)&qkv[kb + 16]; kA3 = *(const u16x8*)&qkv[kb + 24];
      const size_t v0 = ((size_t)(kv0n + 2 * lane) * BB + b) * 1536 + h * HDD + 1024 + vd0;
      const size_t v1 = v0 + (size_t)BB * 1536;
      vA0 = *(const u16x8*)&qkv[v0]; vA1 = *(const u16x8*)&qkv[v0 + 8];
      vA2 = *(const u16x8*)&qkv[v1]; vA3 = *(const u16x8*)&qkv[v1 + 8];
    }
    __syncthreads();   // LDS tile ready

    // S^T = K · Q^T : lane holds S[q = r15][kv = nt*16 + rhi*4 + r]
    f32x4 s[8];
#pragma unroll
    for (int nt = 0; nt < 8; nt++) {
      const u16t* kr = &Ks[(nt * 16 + r15) * 72];
      bf16x8 k0 = *(const bf16x8*)&kr[rhi * 8];
      bf16x8 k1 = *(const bf16x8*)&kr[32 + rhi * 8];
      f32x4 acc = fz;
      acc = mfma16(k0, qf0, acc);
      acc = mfma16(k1, qf1, acc);
      s[nt] = acc;
    }

    // P = exp(s/8) = exp2(s * log2e/8); accumulate raw sum; pack to bf16 pairs
    unsigned int P2[8][2];
#pragma unroll
    for (int nt = 0; nt < 8; nt++) {
#pragma unroll
      for (int r = 0; r < 4; r++) {
        s[nt][r] = exp2f(s[nt][r] * 0.18033688011112042f);
        psum += s[nt][r];
      }
      asm("v_cvt_pk_bf16_f32 %0, %1, %2" : "=v"(P2[nt][0]) : "v"(s[nt][0]), "v"(s[nt][1]));
      asm("v_cvt_pk_bf16_f32 %0, %1, %2" : "=v"(P2[nt][1]) : "v"(s[nt][2]), "v"(s[nt][3]));
    }

    // PV with lane-local P: k-slot (hi*8+jj) holds kv = 32c + (jj<4?0:16) + hi*4 + (jj&3);
    // V A-frag reads match that order (two 8B reads per chunk per d-block).
#pragma unroll
    for (int c = 0; c < 4; c++) {
      union { unsigned int w[4]; bf16x8 v; } pf;
      pf.w[0] = P2[2 * c][0];     pf.w[1] = P2[2 * c][1];
      pf.w[2] = P2[2 * c + 1][0]; pf.w[3] = P2[2 * c + 1][1];
#pragma unroll
      for (int dd = 0; dd < 4; dd++) {
        const u16t* vr = &Vt[(dd * 16 + r15) * 136 + c * 32 + rhi * 4];
        union { u16x4 h[2]; bf16x8 v; } vb;
        vb.h[0] = *(const u16x4*)&vr[0];
        vb.h[1] = *(const u16x4*)&vr[16];
        oa[dd] = mfma16(vb.v, pf.v, oa[dd]);
      }
    }
  }

  // final: lsum(q) = psum reduced over the 4 rhi lanes holding q's kv partitions
  float ls = psum;
  ls += __shfl_xor(ls, 16);
  ls += __shfl_xor(ls, 32);
  const float inv = 1.f / ls;
  const size_t obase = ((size_t)qrow * BB + b) * EE + h * HDD;
#pragma unroll
  for (int dd = 0; dd < 4; dd++) {
    u16x4 o = { f2bf(oa[dd][0] * inv), f2bf(oa[dd][1] * inv),
                f2bf(oa[dd][2] * inv), f2bf(oa[dd][3] * inv) };
    *(u16x4*)&ao[obase + dd * 16 + rhi * 4] = o;
  }
}

// ---------------- wave-per-token LayerNorms ----------------
__device__ __forceinline__ float wave_sum(float v) {
#pragma unroll
  for (int off = 1; off < 64; off <<= 1) v += __shfl_xor(v, off);
  return v;
}

__global__ __launch_bounds__(256) void ln1_kernel(
    const float* __restrict__ x, const float* __restrict__ aop,
    const float* __restrict__ g, const float* __restrict__ be,
    float* __restrict__ x1, u16t* __restrict__ x1b)
{
  const int wave = threadIdx.x >> 6, lane = threadIdx.x & 63;
  const int t = blockIdx.x * 4 + wave;
  const size_t base = (size_t)t * EE + lane * 8;
  float4 a0 = *(const float4*)&x[base],   a1 = *(const float4*)&x[base + 4];
  float4 p0 = *(const float4*)&aop[base], p1 = *(const float4*)&aop[base + 4];
  float v[8] = { a0.x + p0.x, a0.y + p0.y, a0.z + p0.z, a0.w + p0.w,
                 a1.x + p1.x, a1.y + p1.y, a1.z + p1.z, a1.w + p1.w };
  float s = 0.f;
#pragma unroll
  for (int i = 0; i < 8; i++) s += v[i];
  const float mean = wave_sum(s) * (1.f / EE);
  float vs = 0.f;
#pragma unroll
  for (int i = 0; i < 8; i++) { v[i] -= mean; vs += v[i] * v[i]; }
  const float inv = rsqrtf(wave_sum(vs) * (1.f / EE) + 1e-5f);
  float4 g0 = *(const float4*)&g[lane * 8],  g1 = *(const float4*)&g[lane * 8 + 4];
  float4 b0 = *(const float4*)&be[lane * 8], b1 = *(const float4*)&be[lane * 8 + 4];
  float o[8] = { v[0]*inv*g0.x + b0.x, v[1]*inv*g0.y + b0.y, v[2]*inv*g0.z + b0.z, v[3]*inv*g0.w + b0.w,
                 v[4]*inv*g1.x + b1.x, v[5]*inv*g1.y + b1.y, v[6]*inv*g1.z + b1.z, v[7]*inv*g1.w + b1.w };
  *(float4*)&x1[base]     = make_float4(o[0], o[1], o[2], o[3]);
  *(float4*)&x1[base + 4] = make_float4(o[4], o[5], o[6], o[7]);
  u16x8 ob = { f2bf(o[0]), f2bf(o[1]), f2bf(o[2]), f2bf(o[3]),
               f2bf(o[4]), f2bf(o[5]), f2bf(o[6]), f2bf(o[7]) };
  *(u16x8*)&x1b[base] = ob;
}

__global__ __launch_bounds__(256) void ln2_kernel(
    const float* __restrict__ x1, const u16t* __restrict__ slots,
    const u16t* __restrict__ sh,
    const float* __restrict__ g, const float* __restrict__ be,
    float* __restrict__ out)
{
  const int wave = threadIdx.x >> 6, lane = threadIdx.x & 63;
  const int t = blockIdx.x * 4 + wave;
  const size_t base = (size_t)t * EE + lane * 8;
  float4 a0 = *(const float4*)&x1[base], a1 = *(const float4*)&x1[base + 4];
  u16x8 m0 = *(const u16x8*)&slots[(size_t)(2 * t) * EE + lane * 8];
  u16x8 m1 = *(const u16x8*)&slots[(size_t)(2 * t + 1) * EE + lane * 8];
  u16x8 sv = *(const u16x8*)&sh[base];
  float v[8] = { a0.x, a0.y, a0.z, a0.w, a1.x, a1.y, a1.z, a1.w };
#pragma unroll
  for (int i = 0; i < 8; i++) v[i] += bf2f(m0[i]) + bf2f(m1[i]) + bf2f(sv[i]);
  float s = 0.f;
#pragma unroll
  for (int i = 0; i < 8; i++) s += v[i];
  const float mean = wave_sum(s) * (1.f / EE);
  float vs = 0.f;
#pragma unroll
  for (int i = 0; i < 8; i++) { v[i] -= mean; vs += v[i] * v[i]; }
  const float inv = rsqrtf(wave_sum(vs) * (1.f / EE) + 1e-5f);
  float4 g0 = *(const float4*)&g[lane * 8],  g1 = *(const float4*)&g[lane * 8 + 4];
  float4 b0 = *(const float4*)&be[lane * 8], b1 = *(const float4*)&be[lane * 8 + 4];
  *(float4*)&out[base] = make_float4(v[0]*inv*g0.x + b0.x, v[1]*inv*g0.y + b0.y,
                                     v[2]*inv*g0.z + b0.z, v[3]*inv*g0.w + b0.w);
  *(float4*)&out[base + 4] = make_float4(v[4]*inv*g1.x + b1.x, v[5]*inv*g1.y + b1.y,
                                         v[6]*inv*g1.z + b1.z, v[7]*inv*g1.w + b1.w);
}

// ---------------- gate: softmax over 8, top-2, per-token pack + loss partials ----------------
__global__ __launch_bounds__(256) void gate_kernel(
    const float* __restrict__ x1, const float* __restrict__ gw,
    const float* __restrict__ gb,
    int* __restrict__ tok_pack, float2* __restrict__ tok_w,
    float* __restrict__ partials)
{
  const int wave = threadIdx.x >> 6, lane = threadIdx.x & 63;
  const int t = blockIdx.x * 4 + wave;
  float4 xa = *(const float4*)&x1[(size_t)t * EE + lane * 8];
  float4 xb2 = *(const float4*)&x1[(size_t)t * EE + lane * 8 + 4];
  float pe[8];
  float mx = -1e30f;
#pragma unroll
  for (int e = 0; e < 8; e++) {
    float4 ga = *(const float4*)&gw[e * EE + lane * 8];
    float4 gB = *(const float4*)&gw[e * EE + lane * 8 + 4];
    float s = xa.x*ga.x + xa.y*ga.y + xa.z*ga.z + xa.w*ga.w
            + xb2.x*gB.x + xb2.y*gB.y + xb2.z*gB.z + xb2.w*gB.w;
#pragma unroll
    for (int off = 1; off < 64; off <<= 1) s += __shfl_xor(s, off);
    pe[e] = s + gb[e];
    mx = fmaxf(mx, pe[e]);
  }
  float se = 0.f;
#pragma unroll
  for (int e = 0; e < 8; e++) { pe[e] = __expf(pe[e] - mx); se += pe[e]; }
  const float invs = 1.f / se;
#pragma unroll
  for (int e = 0; e < 8; e++) pe[e] *= invs;
  float v1 = -1.f; int i1 = 0;
#pragma unroll
  for (int e = 0; e < 8; e++) if (pe[e] > v1) { v1 = pe[e]; i1 = e; }
  float v2 = -1.f; int i2 = -1;
#pragma unroll
  for (int e = 0; e < 8; e++) if (e != i1 && pe[e] > v2) { v2 = pe[e]; i2 = e; }
  const float denom = 1.f / (v1 + v2);
  if (lane == 0) {
    tok_pack[t] = i1 | (i2 << 8);
    float2 w; w.x = v1 * denom; w.y = v2 * denom;
    tok_w[t] = w;
  }
  __shared__ float fb[4][8], pb[4][8];
  if (lane < 8) {
    fb[wave][lane] = (lane == i1 || lane == i2) ? 1.f : 0.f;
    pb[wave][lane] = pe[lane];
  }
  __syncthreads();
  if (threadIdx.x < 8) {
    const int e = threadIdx.x;
    partials[(size_t)blockIdx.x * 16 + e]     = fb[0][e] + fb[1][e] + fb[2][e] + fb[3][e];
    partials[(size_t)blockIdx.x * 16 + 8 + e] = pb[0][e] + pb[1][e] + pb[2][e] + pb[3][e];
  }
}

// ---------------- deterministic list build: 1 block per expert, ballot-scan ----------------
__global__ __launch_bounds__(256) void build_lists(
    const int* __restrict__ tok_pack, const float2* __restrict__ tok_w,
    int* __restrict__ counts, int* __restrict__ list, float* __restrict__ wlist)
{
  const int e = blockIdx.x;
  const int tid = threadIdx.x;
  const int lane = tid & 63, wave = tid >> 6;
  __shared__ int wtot[4];
  __shared__ int runb;
  if (tid == 0) runb = 0;
  __syncthreads();
  for (int c = 0; c < 32; c++) {
    const int t = c * 256 + tid;
    const int pk = tok_pack[t];
    const int i1 = pk & 255, i2 = (pk >> 8) & 255;
    const bool s1 = (i1 == e);
    const bool flag = s1 || (i2 == e);
    const unsigned long long mask = __ballot(flag);
    if (lane == 63) wtot[wave] = __popcll(mask);
    __syncthreads();
    int wbase = 0;
#pragma unroll
    for (int w2 = 0; w2 < 4; w2++) if (w2 < wave) wbase += wtot[w2];
    const int btot = wtot[0] + wtot[1] + wtot[2] + wtot[3];
    if (flag) {
      const int pre = __popcll(mask & ((1ull << lane) - 1ull));
      const int pos = runb + wbase + pre;
      list[e * 8192 + pos] = 2 * t + (s1 ? 0 : 1);
      float2 w = tok_w[t];
      wlist[e * 8192 + pos] = s1 ? w.x : w.y;
    }
    __syncthreads();
    if (tid == 0) runb += btot;
    __syncthreads();
  }
  if (tid == 0) counts[e] = runb;
}

__global__ __launch_bounds__(256) void gate_reduce(
    const float* __restrict__ partials, float* __restrict__ loss_out)
{
  __shared__ float acc[16][16];
  __shared__ float fin[16];
  const int c = threadIdx.x & 15, grp = threadIdx.x >> 4;
  float s = 0.f;
  for (int i = grp; i < 2048; i += 16) s += partials[(size_t)i * 16 + c];
  acc[grp][c] = s;
  __syncthreads();
  if (threadIdx.x < 16) {
    float t2 = 0.f;
    for (int g2 = 0; g2 < 16; g2++) t2 += acc[g2][threadIdx.x];
    fin[threadIdx.x] = t2;
  }
  __syncthreads();
  if (threadIdx.x == 0) {
    float loss = 0.f;
    for (int e = 0; e < 8; e++)
      loss += (fin[e] * (1.f / TT)) * (fin[8 + e] * (1.f / TT));
    loss_out[0] = loss * 8.f;
  }
}

// ---------------- host-side launcher ----------------
extern "C" void kernel_launch(void* const* d_in, const int* in_sizes, int n_in,
                              void* d_out, int out_size, void* d_ws, size_t ws_size,
                              hipStream_t stream) {
  const float* x    = (const float*)d_in[0];
  const float* wq   = (const float*)d_in[1];
  const float* bq   = (const float*)d_in[2];
  const float* wk   = (const float*)d_in[3];
  const float* bk   = (const float*)d_in[4];
  const float* wv   = (const float*)d_in[5];
  const float* bv   = (const float*)d_in[6];
  const float* in_w = (const float*)d_in[7];
  const float* in_b = (const float*)d_in[8];
  const float* out_w= (const float*)d_in[9];
  const float* out_b= (const float*)d_in[10];
  const float* ln1g = (const float*)d_in[11];
  const float* ln1b = (const float*)d_in[12];
  const float* ln2g = (const float*)d_in[13];
  const float* ln2b = (const float*)d_in[14];
  const float* shw  = (const float*)d_in[15];
  const float* shb  = (const float*)d_in[16];
  const float* gw   = (const float*)d_in[17];
  const float* gb   = (const float*)d_in[18];
  const float* expw = (const float*)d_in[19];
  const float* expb = (const float*)d_in[20];

  char* ws = (char*)d_ws;
  // --- static region ---
  u16t* xb     = (u16t*)(ws + 0);          // 8 MB
  u16t* inwb   = (u16t*)(ws + 8388608);    // 1.5 MB bf16(in_w)
  u16t* w3t    = (u16t*)(ws + 9961472);    // 1.5 MB bf16(wq^T|wk^T|wv^T)
  u16t* w2big  = (u16t*)(ws + 11534336);   // 1.5 MB composed [1536][512]
  u16t* outwb  = (u16t*)(ws + 13107200);   // 0.5 MB
  u16t* shwb   = (u16t*)(ws + 13631488);   // 0.5 MB
  u16t* expwb  = (u16t*)(ws + 14155776);   // 4 MB
  float* b2    = (float*)(ws + 18350080);  // 6 KB composed bias
  int*  tok_pack = (int*)(ws + 18356224);  // 32 KB
  float2* tok_w  = (float2*)(ws + 18388992); // 64 KB
  int*  counts = (int*)(ws + 18454528);    // 128 B
  int*  list   = (int*)(ws + 18454656);    // 256 KB
  float* wlist = (float*)(ws + 18716800);  // 256 KB
  float* parts = (float*)(ws + 18978944);  // 128 KB
  // --- overlay pool (peak ~61 MB) ---
  const size_t S = 19110016;
  u16t* qkvb   = (u16t*)(ws + S);                 // 24 MB: stage1 -> attn
  float* aop   = (float*)(ws + S);                // 16 MB: outproj -> ln1 (qkvb dead)
  u16t* x1b    = (u16t*)(ws + S + 16777216);      // 8 MB: ln1 -> shared/moe
  u16t* oslots = (u16t*)(ws + S);                 // 16 MB: moe -> ln2 (aop dead)
  float* x1    = (float*)(ws + S + 25165824);     // 16 MB: ln1 -> ln2
  u16t* aob    = (u16t*)(ws + 0);                 // 8 MB: attn -> outproj (xb dead)
  u16t* shrd   = (u16t*)(ws + 0);                 // 8 MB: shared -> ln2 (aob dead)
  float* outp  = (float*)d_out;

  dim3 blk(256);
  // converts
  cvtk<<<4096, blk, 0, stream>>>(x, xb, TT * EE);
  cvtk<<<768,  blk, 0, stream>>>(in_w, inwb, 3 * EE * EE);
  cvtk<<<256,  blk, 0, stream>>>(out_w, outwb, EE * EE);
  cvtk<<<256,  blk, 0, stream>>>(shw, shwb, EE * EE);
  cvtk<<<2048, blk, 0, stream>>>(expw, expwb, NEXP * EE * EE);
  cvt_t<<<dim3(8, 8, 3), blk, 0, stream>>>(wq, wk, wv, w3t);
  // weight/bias composition: W2 = in_w_seg @ w_seg, b2 = in_w_seg @ b_seg + in_b_seg
  compose_k<<<dim3(4, 4, 3), blk, 0, stream>>>(inwb, w3t, w2big);
  bias_mv<<<24, blk, 0, stream>>>(in_w, in_b, bq, bk, bv, b2);
  // fused QKV projection: x @ W2^T + b2 -> q|k|v packed (ldc 1536)
  gemm_bt<0,1><<<dim3(64, 12), blk, 0, stream>>>(xb, EE, w2big, b2, qkvb, 1536, EE);
  // attention
  attn_kernel<<<dim3(64, 16), blk, 0, stream>>>(qkvb, aob);
  // out projection (f32 out)
  gemm_bt<0,0><<<dim3(64, 4), blk, 0, stream>>>(aob, EE, outwb, out_b, aop, EE, EE);
  // LN1
  ln1_kernel<<<2048, blk, 0, stream>>>(x, aop, ln1g, ln1b, x1, x1b);
  // gate + deterministic list build + loss
  gate_kernel<<<2048, blk, 0, stream>>>(x1, gw, gb, tok_pack, tok_w, parts);
  build_lists<<<8, blk, 0, stream>>>(tok_pack, tok_w, counts, list, wlist);
  gate_reduce<<<1, blk, 0, stream>>>(parts, outp + (size_t)TT * EE);
  // shared expert (leaky)
  gemm_bt<1,1><<<dim3(64, 4), blk, 0, stream>>>(x1b, EE, shwb, shb, shrd, EE, EE);
  // sparse MoE
  moe_sparse<<<dim3(512, 4), blk, 0, stream>>>(x1b, expwb, expb, counts, list, wlist, oslots);
  // LN2 -> output (f32)
  ln2_kernel<<<2048, blk, 0, stream>>>(x1, oslots, shrd, ln2g, ln2b, outp);
}

// Round 7
// 233.589 us; speedup vs baseline: 1.5561x; 1.1283x over previous
//
#include <hip/hip_runtime.h>
#include <stdint.h>

// Problem dims (fixed)
#define LL   1024
#define BB   8
#define EE   512
#define HH   8
#define HDD  64
#define NEXP 8
#define TT   8192   // L*B tokens

typedef unsigned short u16t;
typedef __bf16 bf16x8 __attribute__((ext_vector_type(8)));
typedef u16t   u16x8  __attribute__((ext_vector_type(8)));
typedef u16t   u16x4  __attribute__((ext_vector_type(4)));
typedef float  f32x4  __attribute__((ext_vector_type(4)));

__device__ __forceinline__ u16t f2bf(float f) {
  union { float f; unsigned int u; } a; a.f = f;
  unsigned int r = a.u + 0x7fffu + ((a.u >> 16) & 1u);
  return (u16t)(r >> 16);
}
__device__ __forceinline__ float bf2f(u16t s) {
  union { unsigned int u; float f; } a; a.u = ((unsigned int)s) << 16; return a.f;
}

__device__ __forceinline__ f32x4 mfma16(bf16x8 a, bf16x8 b, f32x4 c) {
  return __builtin_amdgcn_mfma_f32_16x16x32_bf16(a, b, c, 0, 0, 0);
}

// async global->LDS, 16B per lane; LDS dest linear in tid, global src may be per-lane
#define GLDS16(gp, lp) \
  __builtin_amdgcn_global_load_lds( \
      (const __attribute__((address_space(1))) unsigned int*)(const void*)(gp), \
      (__attribute__((address_space(3))) unsigned int*)(void*)(lp), 16, 0, 0)

// ---------------- f32 -> bf16 convert (vectorized) ----------------
__global__ __launch_bounds__(256) void cvtk(const float* __restrict__ s,
                                            u16t* __restrict__ d, int n) {
  int i = (blockIdx.x * 256 + threadIdx.x) * 4;
  if (i < n) {
    float4 v = *(const float4*)&s[i];
    u16x4 o = { f2bf(v.x), f2bf(v.y), f2bf(v.z), f2bf(v.w) };
    *(u16x4*)&d[i] = o;
  }
}

// ---------------- transpose-convert: out[n][j] = bf16(in[j][n]), 512x512, z=3 ----------------
__global__ __launch_bounds__(256) void cvt_t(const float* __restrict__ w0,
                                             const float* __restrict__ w1,
                                             const float* __restrict__ w2,
                                             u16t* __restrict__ out) {
  const float* src = blockIdx.z == 0 ? w0 : blockIdx.z == 1 ? w1 : w2;
  u16t* dst = out + (size_t)blockIdx.z * 262144;
  __shared__ float tile[64][65];
  const int r = threadIdx.x >> 4;
  const int c = (threadIdx.x & 15) * 4;
  const int r0 = blockIdx.y * 64, c0 = blockIdx.x * 64;
#pragma unroll
  for (int i = 0; i < 4; i++) {
    float4 v = *(const float4*)&src[(size_t)(r0 + r + i * 16) * 512 + c0 + c];
    tile[r + i * 16][c] = v.x; tile[r + i * 16][c + 1] = v.y;
    tile[r + i * 16][c + 2] = v.z; tile[r + i * 16][c + 3] = v.w;
  }
  __syncthreads();
#pragma unroll
  for (int i = 0; i < 4; i++) {
    const int orow = c0 + r + i * 16;
    u16x4 o = { f2bf(tile[c][r + i * 16]), f2bf(tile[c + 1][r + i * 16]),
                f2bf(tile[c + 2][r + i * 16]), f2bf(tile[c + 3][r + i * 16]) };
    *(u16x4*)&dst[(size_t)orow * 512 + r0 + c] = o;
  }
}

// ---------------- composed-weight GEMM (64x64 tiles): C(z) = A(z) @ W(z)^T, bf16 out ----------------
__global__ __launch_bounds__(256) void compose_k(const u16t* __restrict__ Aall,
                                                 const u16t* __restrict__ Wall,
                                                 u16t* __restrict__ Call) {
  const u16t* A = Aall + (size_t)blockIdx.z * 262144;
  const u16t* W = Wall + (size_t)blockIdx.z * 262144;
  u16t* C = Call + (size_t)blockIdx.z * 262144;
  __shared__ alignas(16) u16t As[64 * 32];
  __shared__ alignas(16) u16t Ws[64 * 32];
  const int tid = threadIdx.x;
  const int lane = tid & 63, wave = tid >> 6;
  const int r15 = lane & 15, rhi = lane >> 4;
  const int wr = wave >> 1, wc = wave & 1;
  const int m0 = blockIdx.x * 64, n0 = blockIdx.y * 64;
  const int arow = tid >> 2, acol = (tid & 3) * 8;
  const f32x4 fz = {0.f, 0.f, 0.f, 0.f};
  f32x4 acc[2][2] = {{fz, fz}, {fz, fz}};
  const u16t* Ap = A + (size_t)(m0 + arow) * 512 + acol;
  const u16t* Wp = W + (size_t)(n0 + arow) * 512 + acol;
  u16t* As0 = &As[tid * 8];
  u16t* Ws0 = &Ws[tid * 8];
  for (int kt = 0; kt < 512; kt += 32) {
    __syncthreads();
    GLDS16(Ap + kt, As0);
    GLDS16(Wp + kt, Ws0);
    asm volatile("s_waitcnt vmcnt(0)" ::: "memory");
    __syncthreads();
    bf16x8 af[2], bfv[2];
#pragma unroll
    for (int mi = 0; mi < 2; mi++)
      af[mi] = *(const bf16x8*)&As[(wr * 32 + mi * 16 + r15) * 32 + rhi * 8];
#pragma unroll
    for (int ni = 0; ni < 2; ni++)
      bfv[ni] = *(const bf16x8*)&Ws[(wc * 32 + ni * 16 + r15) * 32 + rhi * 8];
#pragma unroll
    for (int mi = 0; mi < 2; mi++)
#pragma unroll
      for (int ni = 0; ni < 2; ni++)
        acc[mi][ni] = mfma16(af[mi], bfv[ni], acc[mi][ni]);
  }
#pragma unroll
  for (int mi = 0; mi < 2; mi++)
#pragma unroll
    for (int ni = 0; ni < 2; ni++) {
      const int col = n0 + wc * 32 + ni * 16 + r15;
#pragma unroll
      for (int r = 0; r < 4; r++) {
        const int row = m0 + wr * 32 + mi * 16 + rhi * 4 + r;
        C[(size_t)row * 512 + col] = f2bf(acc[mi][ni][r]);
      }
    }
}

// ---------------- composed bias ----------------
__global__ __launch_bounds__(256) void bias_mv(const float* __restrict__ in_w,
                                               const float* __restrict__ in_b,
                                               const float* __restrict__ b0,
                                               const float* __restrict__ b1,
                                               const float* __restrict__ b2v,
                                               float* __restrict__ out) {
  const int bi = blockIdx.x;                 // 24 blocks
  const int seg = bi >> 3, m0 = (bi & 7) * 64;
  const float* bvec = seg == 0 ? b0 : seg == 1 ? b1 : b2v;
  const int m = m0 + (threadIdx.x >> 2), q = threadIdx.x & 3;
  const float* row = in_w + (size_t)(seg * 512 + m) * 512 + q * 128;
  const float* bv = bvec + q * 128;
  float s = 0.f;
  for (int j = 0; j < 128; j++) s += row[j] * bv[j];
  s += __shfl_xor(s, 1); s += __shfl_xor(s, 2);
  if (q == 0) out[seg * 512 + m] = s + in_b[seg * 512 + m];
}

// ---------------- 128x128-tile GEMM (for stage-1 QKV): C = A @ W^T + bias ----------------
template<int ACT, int OUTBF>
__global__ __launch_bounds__(256) void gemm_bt(
    const u16t* __restrict__ A, int lda,
    const u16t* __restrict__ W,
    const float* __restrict__ bias,
    void* __restrict__ Cp, int ldc, int K)
{
  __shared__ alignas(16) u16t As[128 * 32];
  __shared__ alignas(16) u16t Ws[128 * 32];
  const int tid  = threadIdx.x;
  const int lane = tid & 63, wave = tid >> 6;
  const int r15  = lane & 15, rhi = lane >> 4;
  const int wr   = wave >> 1, wc  = wave & 1;
  const int m0 = blockIdx.x * 128, n0 = blockIdx.y * 128;
  const int arow = tid >> 2, acol = (tid & 3) * 8;

  const f32x4 fz = {0.f, 0.f, 0.f, 0.f};
  f32x4 acc[4][4];
#pragma unroll
  for (int i = 0; i < 4; i++)
#pragma unroll
    for (int j = 0; j < 4; j++) acc[i][j] = fz;

  const u16t* Ap0 = A + (size_t)(m0 + arow) * lda + acol;
  const u16t* Ap1 = A + (size_t)(m0 + arow + 64) * lda + acol;
  const u16t* Wp0 = W + (size_t)(n0 + arow) * K + acol;
  const u16t* Wp1 = W + (size_t)(n0 + arow + 64) * K + acol;
  u16t* As0 = &As[tid * 8];       u16t* As1 = &As[(tid + 256) * 8];
  u16t* Ws0 = &Ws[tid * 8];       u16t* Ws1 = &Ws[(tid + 256) * 8];

  for (int kt = 0; kt < K; kt += 32) {
    __syncthreads();
    GLDS16(Ap0 + kt, As0);
    GLDS16(Ap1 + kt, As1);
    GLDS16(Wp0 + kt, Ws0);
    GLDS16(Wp1 + kt, Ws1);
    asm volatile("s_waitcnt vmcnt(0)" ::: "memory");
    __syncthreads();
    bf16x8 af[4], bfv[4];
#pragma unroll
    for (int mi = 0; mi < 4; mi++)
      af[mi] = *(const bf16x8*)&As[(wr * 64 + mi * 16 + r15) * 32 + rhi * 8];
#pragma unroll
    for (int ni = 0; ni < 4; ni++)
      bfv[ni] = *(const bf16x8*)&Ws[(wc * 64 + ni * 16 + r15) * 32 + rhi * 8];
#pragma unroll
    for (int mi = 0; mi < 4; mi++)
#pragma unroll
      for (int ni = 0; ni < 4; ni++)
        acc[mi][ni] = mfma16(af[mi], bfv[ni], acc[mi][ni]);
  }

#pragma unroll
  for (int mi = 0; mi < 4; mi++) {
#pragma unroll
    for (int ni = 0; ni < 4; ni++) {
      const int col = n0 + wc * 64 + ni * 16 + r15;
      const float bv = bias[col];
#pragma unroll
      for (int r = 0; r < 4; r++) {
        const int row = m0 + wr * 64 + mi * 16 + rhi * 4 + r;
        float v = acc[mi][ni][r] + bv;
        if (ACT == 1) v = v >= 0.f ? v : 0.01f * v;
        if (OUTBF) ((u16t*)Cp)[(size_t)row * ldc + col] = f2bf(v);
        else       ((float*)Cp)[(size_t)row * ldc + col] = v;
      }
    }
  }
}

// ---------------- 64x64-tile GEMM (occupancy-friendly for N=512 GEMMs) ----------------
template<int ACT>
__global__ __launch_bounds__(256) void gemm64(
    const u16t* __restrict__ A, int lda,
    const u16t* __restrict__ W,
    const float* __restrict__ bias,
    u16t* __restrict__ Cp, int ldc, int K)
{
  __shared__ alignas(16) u16t As[64 * 32];
  __shared__ alignas(16) u16t Ws[64 * 32];
  const int tid  = threadIdx.x;
  const int lane = tid & 63, wave = tid >> 6;
  const int r15  = lane & 15, rhi = lane >> 4;
  const int wr   = wave >> 1, wc  = wave & 1;
  const int m0 = blockIdx.x * 64, n0 = blockIdx.y * 64;
  const int arow = tid >> 2, acol = (tid & 3) * 8;

  const f32x4 fz = {0.f, 0.f, 0.f, 0.f};
  f32x4 acc[2][2] = {{fz, fz}, {fz, fz}};

  const u16t* Ap = A + (size_t)(m0 + arow) * lda + acol;
  const u16t* Wp = W + (size_t)(n0 + arow) * K + acol;
  u16t* As0 = &As[tid * 8];
  u16t* Ws0 = &Ws[tid * 8];

  for (int kt = 0; kt < K; kt += 32) {
    __syncthreads();
    GLDS16(Ap + kt, As0);
    GLDS16(Wp + kt, Ws0);
    asm volatile("s_waitcnt vmcnt(0)" ::: "memory");
    __syncthreads();
    bf16x8 af[2], bfv[2];
#pragma unroll
    for (int mi = 0; mi < 2; mi++)
      af[mi] = *(const bf16x8*)&As[(wr * 32 + mi * 16 + r15) * 32 + rhi * 8];
#pragma unroll
    for (int ni = 0; ni < 2; ni++)
      bfv[ni] = *(const bf16x8*)&Ws[(wc * 32 + ni * 16 + r15) * 32 + rhi * 8];
#pragma unroll
    for (int mi = 0; mi < 2; mi++)
#pragma unroll
      for (int ni = 0; ni < 2; ni++)
        acc[mi][ni] = mfma16(af[mi], bfv[ni], acc[mi][ni]);
  }

#pragma unroll
  for (int mi = 0; mi < 2; mi++)
#pragma unroll
    for (int ni = 0; ni < 2; ni++) {
      const int col = n0 + wc * 32 + ni * 16 + r15;
      const float bv = bias[col];
#pragma unroll
      for (int r = 0; r < 4; r++) {
        const int row = m0 + wr * 32 + mi * 16 + rhi * 4 + r;
        float v = acc[mi][ni][r] + bv;
        if (ACT == 1) v = v >= 0.f ? v : 0.01f * v;
        Cp[(size_t)row * ldc + col] = f2bf(v);
      }
    }
}

// ---------------- sparse MoE: 64-token tiles per expert ----------------
__global__ __launch_bounds__(256) void moe_sparse(
    const u16t* __restrict__ x1b, const u16t* __restrict__ Wall,
    const float* __restrict__ ball, const int* __restrict__ counts,
    const int* __restrict__ list, const float* __restrict__ wlist,
    u16t* __restrict__ out_slots)
{
  const int e = blockIdx.x >> 7, mt = blockIdx.x & 127;
  const int cnt = counts[e];
  const int m0 = mt * 64;
  if (m0 >= cnt) return;
  const int n0 = blockIdx.y * 64;
  __shared__ alignas(16) u16t As[64 * 32];
  __shared__ alignas(16) u16t Ws[64 * 32];
  __shared__ int tks[64];
  __shared__ float wws[64];
  const int tid  = threadIdx.x;
  const int lane = tid & 63, wave = tid >> 6;
  const int r15  = lane & 15, rhi = lane >> 4;
  const int wr   = wave >> 1, wc  = wave & 1;
  const int arow = tid >> 2, acol = (tid & 3) * 8;

  if (tid < 64) {
    int idx = m0 + tid; if (idx >= cnt) idx = cnt - 1;
    tks[tid] = list[e * 8192 + idx];
    wws[tid] = wlist[e * 8192 + idx];
  }
  __syncthreads();
  const int tokA = tks[arow] >> 1;

  const f32x4 fz = {0.f, 0.f, 0.f, 0.f};
  f32x4 acc[2][2] = {{fz, fz}, {fz, fz}};

  const u16t* Ap = x1b + (size_t)tokA * 512 + acol;
  const u16t* W = Wall + (size_t)e * 262144;
  const u16t* Wp = W + (size_t)(n0 + arow) * 512 + acol;
  u16t* As0 = &As[tid * 8];
  u16t* Ws0 = &Ws[tid * 8];

  for (int kt = 0; kt < 512; kt += 32) {
    __syncthreads();
    GLDS16(Ap + kt, As0);
    GLDS16(Wp + kt, Ws0);
    asm volatile("s_waitcnt vmcnt(0)" ::: "memory");
    __syncthreads();
    bf16x8 af[2], bfv[2];
#pragma unroll
    for (int mi = 0; mi < 2; mi++)
      af[mi] = *(const bf16x8*)&As[(wr * 32 + mi * 16 + r15) * 32 + rhi * 8];
#pragma unroll
    for (int ni = 0; ni < 2; ni++)
      bfv[ni] = *(const bf16x8*)&Ws[(wc * 32 + ni * 16 + r15) * 32 + rhi * 8];
#pragma unroll
    for (int mi = 0; mi < 2; mi++)
#pragma unroll
      for (int ni = 0; ni < 2; ni++)
        acc[mi][ni] = mfma16(af[mi], bfv[ni], acc[mi][ni]);
  }

#pragma unroll
  for (int mi = 0; mi < 2; mi++)
#pragma unroll
    for (int ni = 0; ni < 2; ni++) {
      const int col = n0 + wc * 32 + ni * 16 + r15;
      const float bv = ball[e * 512 + col];
#pragma unroll
      for (int r = 0; r < 4; r++) {
        const int rl = wr * 32 + mi * 16 + rhi * 4 + r;
        if (m0 + rl < cnt) {
          float z = acc[mi][ni][r] + bv;
          z = z >= 0.f ? z : 0.01f * z;
          out_slots[(size_t)tks[rl] * 512 + col] = f2bf(wws[rl] * z);
        }
      }
    }
}

// ---------------- flash attention v2 (+setprio) ----------------
__global__ __launch_bounds__(256) void attn_kernel(
    const u16t* __restrict__ qkv, u16t* __restrict__ ao)
{
  const int bh = blockIdx.x;
  const int b = bh >> 3, h = bh & 7;
  const int qt = blockIdx.y;
  const int tid  = threadIdx.x;
  const int lane = tid & 63, wave = tid >> 6;
  const int r15  = lane & 15, rhi = lane >> 4;

  __shared__ alignas(16) u16t Ks[128 * 72];
  __shared__ alignas(16) u16t Vt[64 * 136];

  const int qrow = qt * 64 + wave * 16 + r15;
  const size_t qoff = ((size_t)qrow * BB + b) * 1536 + h * HDD;
  const bf16x8 qf0 = *(const bf16x8*)&qkv[qoff + rhi * 8];
  const bf16x8 qf1 = *(const bf16x8*)&qkv[qoff + 32 + rhi * 8];

  const f32x4 fz = {0.f, 0.f, 0.f, 0.f};
  f32x4 oa[4] = {fz, fz, fz, fz};
  float psum = 0.f;

  const int krow = tid >> 1, khalf = tid & 1;
  const int vd0 = wave * 16;

  u16x8 kA0, kA1, kA2, kA3, vA0, vA1, vA2, vA3;
  {
    const size_t kb = ((size_t)krow * BB + b) * 1536 + h * HDD + 512 + khalf * 32;
    kA0 = *(const u16x8*)&qkv[kb];      kA1 = *(const u16x8*)&qkv[kb + 8];
    kA2 = *(const u16x8*)&qkv[kb + 16]; kA3 = *(const u16x8*)&qkv[kb + 24];
    const size_t v0 = ((size_t)(2 * lane) * BB + b) * 1536 + h * HDD + 1024 + vd0;
    const size_t v1 = v0 + (size_t)BB * 1536;
    vA0 = *(const u16x8*)&qkv[v0]; vA1 = *(const u16x8*)&qkv[v0 + 8];
    vA2 = *(const u16x8*)&qkv[v1]; vA3 = *(const u16x8*)&qkv[v1 + 8];
  }

  for (int t = 0; t < 8; t++) {
    __syncthreads();
    {
      u16t* kd = &Ks[krow * 72 + khalf * 32];
      *(u16x8*)&kd[0]  = kA0; *(u16x8*)&kd[8]  = kA1;
      *(u16x8*)&kd[16] = kA2; *(u16x8*)&kd[24] = kA3;
    }
#pragma unroll
    for (int j = 0; j < 8; j++) {
      unsigned int w = (unsigned int)vA0[j] | ((unsigned int)vA2[j] << 16);
      *(unsigned int*)&Vt[(vd0 + j) * 136 + 2 * lane] = w;
    }
#pragma unroll
    for (int j = 0; j < 8; j++) {
      unsigned int w = (unsigned int)vA1[j] | ((unsigned int)vA3[j] << 16);
      *(unsigned int*)&Vt[(vd0 + 8 + j) * 136 + 2 * lane] = w;
    }
    if (t < 7) {
      const int kv0n = (t + 1) * 128;
      const size_t kb = ((size_t)(kv0n + krow) * BB + b) * 1536 + h * HDD + 512 + khalf * 32;
      kA0 = *(const u16x8*)&qkv[kb];      kA1 = *(const u16x8*)&qkv[kb + 8];
      kA2 = *(const u16x8*)&qkv[kb + 16]; kA3 = *(const u16x8*)&qkv[kb + 24];
      const size_t v0 = ((size_t)(kv0n + 2 * lane) * BB + b) * 1536 + h * HDD + 1024 + vd0;
      const size_t v1 = v0 + (size_t)BB * 1536;
      vA0 = *(const u16x8*)&qkv[v0]; vA1 = *(const u16x8*)&qkv[v0 + 8];
      vA2 = *(const u16x8*)&qkv[v1]; vA3 = *(const u16x8*)&qkv[v1 + 8];
    }
    __syncthreads();

    f32x4 s[8];
    __builtin_amdgcn_s_setprio(1);
#pragma unroll
    for (int nt = 0; nt < 8; nt++) {
      const u16t* kr = &Ks[(nt * 16 + r15) * 72];
      bf16x8 k0 = *(const bf16x8*)&kr[rhi * 8];
      bf16x8 k1 = *(const bf16x8*)&kr[32 + rhi * 8];
      f32x4 acc = fz;
      acc = mfma16(k0, qf0, acc);
      acc = mfma16(k1, qf1, acc);
      s[nt] = acc;
    }
    __builtin_amdgcn_s_setprio(0);

    unsigned int P2[8][2];
#pragma unroll
    for (int nt = 0; nt < 8; nt++) {
#pragma unroll
      for (int r = 0; r < 4; r++) {
        s[nt][r] = exp2f(s[nt][r] * 0.18033688011112042f);
        psum += s[nt][r];
      }
      asm("v_cvt_pk_bf16_f32 %0, %1, %2" : "=v"(P2[nt][0]) : "v"(s[nt][0]), "v"(s[nt][1]));
      asm("v_cvt_pk_bf16_f32 %0, %1, %2" : "=v"(P2[nt][1]) : "v"(s[nt][2]), "v"(s[nt][3]));
    }

    __builtin_amdgcn_s_setprio(1);
#pragma unroll
    for (int c = 0; c < 4; c++) {
      union { unsigned int w[4]; bf16x8 v; } pf;
      pf.w[0] = P2[2 * c][0];     pf.w[1] = P2[2 * c][1];
      pf.w[2] = P2[2 * c + 1][0]; pf.w[3] = P2[2 * c + 1][1];
#pragma unroll
      for (int dd = 0; dd < 4; dd++) {
        const u16t* vr = &Vt[(dd * 16 + r15) * 136 + c * 32 + rhi * 4];
        union { u16x4 h[2]; bf16x8 v; } vb;
        vb.h[0] = *(const u16x4*)&vr[0];
        vb.h[1] = *(const u16x4*)&vr[16];
        oa[dd] = mfma16(vb.v, pf.v, oa[dd]);
      }
    }
    __builtin_amdgcn_s_setprio(0);
  }

  float ls = psum;
  ls += __shfl_xor(ls, 16);
  ls += __shfl_xor(ls, 32);
  const float inv = 1.f / ls;
  const size_t obase = ((size_t)qrow * BB + b) * EE + h * HDD;
#pragma unroll
  for (int dd = 0; dd < 4; dd++) {
    u16x4 o = { f2bf(oa[dd][0] * inv), f2bf(oa[dd][1] * inv),
                f2bf(oa[dd][2] * inv), f2bf(oa[dd][3] * inv) };
    *(u16x4*)&ao[obase + dd * 16 + rhi * 4] = o;
  }
}

// ---------------- fused LN1 + gate (wave per token) ----------------
__device__ __forceinline__ float wave_sum(float v) {
#pragma unroll
  for (int off = 1; off < 64; off <<= 1) v += __shfl_xor(v, off);
  return v;
}

__global__ __launch_bounds__(256) void ln1_gate(
    const float* __restrict__ x, const u16t* __restrict__ aopb,
    const float* __restrict__ g, const float* __restrict__ be,
    const float* __restrict__ gw, const float* __restrict__ gb,
    u16t* __restrict__ x1b,
    int* __restrict__ tok_pack, float2* __restrict__ tok_w,
    float* __restrict__ partials)
{
  const int wave = threadIdx.x >> 6, lane = threadIdx.x & 63;
  const int t = blockIdx.x * 4 + wave;
  const size_t base = (size_t)t * EE + lane * 8;
  float4 a0 = *(const float4*)&x[base], a1 = *(const float4*)&x[base + 4];
  u16x8 ap = *(const u16x8*)&aopb[base];
  float v[8] = { a0.x + bf2f(ap[0]), a0.y + bf2f(ap[1]), a0.z + bf2f(ap[2]), a0.w + bf2f(ap[3]),
                 a1.x + bf2f(ap[4]), a1.y + bf2f(ap[5]), a1.z + bf2f(ap[6]), a1.w + bf2f(ap[7]) };
  float s = 0.f;
#pragma unroll
  for (int i = 0; i < 8; i++) s += v[i];
  const float mean = wave_sum(s) * (1.f / EE);
  float vs = 0.f;
#pragma unroll
  for (int i = 0; i < 8; i++) { v[i] -= mean; vs += v[i] * v[i]; }
  const float inv = rsqrtf(wave_sum(vs) * (1.f / EE) + 1e-5f);
  float4 g0 = *(const float4*)&g[lane * 8],  g1 = *(const float4*)&g[lane * 8 + 4];
  float4 b0 = *(const float4*)&be[lane * 8], b1 = *(const float4*)&be[lane * 8 + 4];
  float o[8] = { v[0]*inv*g0.x + b0.x, v[1]*inv*g0.y + b0.y, v[2]*inv*g0.z + b0.z, v[3]*inv*g0.w + b0.w,
                 v[4]*inv*g1.x + b1.x, v[5]*inv*g1.y + b1.y, v[6]*inv*g1.z + b1.z, v[7]*inv*g1.w + b1.w };
  u16x8 ob = { f2bf(o[0]), f2bf(o[1]), f2bf(o[2]), f2bf(o[3]),
               f2bf(o[4]), f2bf(o[5]), f2bf(o[6]), f2bf(o[7]) };
  *(u16x8*)&x1b[base] = ob;

  // gate from f32 normalized row
  float pe[8];
  float mx = -1e30f;
#pragma unroll
  for (int e = 0; e < 8; e++) {
    float4 ga = *(const float4*)&gw[e * EE + lane * 8];
    float4 gB = *(const float4*)&gw[e * EE + lane * 8 + 4];
    float d = o[0]*ga.x + o[1]*ga.y + o[2]*ga.z + o[3]*ga.w
            + o[4]*gB.x + o[5]*gB.y + o[6]*gB.z + o[7]*gB.w;
#pragma unroll
    for (int off = 1; off < 64; off <<= 1) d += __shfl_xor(d, off);
    pe[e] = d + gb[e];
    mx = fmaxf(mx, pe[e]);
  }
  float se = 0.f;
#pragma unroll
  for (int e = 0; e < 8; e++) { pe[e] = __expf(pe[e] - mx); se += pe[e]; }
  const float invs = 1.f / se;
#pragma unroll
  for (int e = 0; e < 8; e++) pe[e] *= invs;
  float v1 = -1.f; int i1 = 0;
#pragma unroll
  for (int e = 0; e < 8; e++) if (pe[e] > v1) { v1 = pe[e]; i1 = e; }
  float v2 = -1.f; int i2 = -1;
#pragma unroll
  for (int e = 0; e < 8; e++) if (e != i1 && pe[e] > v2) { v2 = pe[e]; i2 = e; }
  const float denom = 1.f / (v1 + v2);
  if (lane == 0) {
    tok_pack[t] = i1 | (i2 << 8);
    float2 w; w.x = v1 * denom; w.y = v2 * denom;
    tok_w[t] = w;
  }
  __shared__ float fb[4][8], pb[4][8];
  if (lane < 8) {
    fb[wave][lane] = (lane == i1 || lane == i2) ? 1.f : 0.f;
    pb[wave][lane] = pe[lane];
  }
  __syncthreads();
  if (threadIdx.x < 8) {
    const int e = threadIdx.x;
    partials[(size_t)blockIdx.x * 16 + e]     = fb[0][e] + fb[1][e] + fb[2][e] + fb[3][e];
    partials[(size_t)blockIdx.x * 16 + 8 + e] = pb[0][e] + pb[1][e] + pb[2][e] + pb[3][e];
  }
}

// ---------------- LN2 (bf16 inputs) ----------------
__global__ __launch_bounds__(256) void ln2_kernel(
    const u16t* __restrict__ x1b, const u16t* __restrict__ slots,
    const u16t* __restrict__ sh,
    const float* __restrict__ g, const float* __restrict__ be,
    float* __restrict__ out)
{
  const int wave = threadIdx.x >> 6, lane = threadIdx.x & 63;
  const int t = blockIdx.x * 4 + wave;
  const size_t base = (size_t)t * EE + lane * 8;
  u16x8 xv = *(const u16x8*)&x1b[base];
  u16x8 m0 = *(const u16x8*)&slots[(size_t)(2 * t) * EE + lane * 8];
  u16x8 m1 = *(const u16x8*)&slots[(size_t)(2 * t + 1) * EE + lane * 8];
  u16x8 sv = *(const u16x8*)&sh[base];
  float v[8];
#pragma unroll
  for (int i = 0; i < 8; i++)
    v[i] = bf2f(xv[i]) + bf2f(m0[i]) + bf2f(m1[i]) + bf2f(sv[i]);
  float s = 0.f;
#pragma unroll
  for (int i = 0; i < 8; i++) s += v[i];
  const float mean = wave_sum(s) * (1.f / EE);
  float vs = 0.f;
#pragma unroll
  for (int i = 0; i < 8; i++) { v[i] -= mean; vs += v[i] * v[i]; }
  const float inv = rsqrtf(wave_sum(vs) * (1.f / EE) + 1e-5f);
  float4 g0 = *(const float4*)&g[lane * 8],  g1 = *(const float4*)&g[lane * 8 + 4];
  float4 b0 = *(const float4*)&be[lane * 8], b1 = *(const float4*)&be[lane * 8 + 4];
  *(float4*)&out[base] = make_float4(v[0]*inv*g0.x + b0.x, v[1]*inv*g0.y + b0.y,
                                     v[2]*inv*g0.z + b0.z, v[3]*inv*g0.w + b0.w);
  *(float4*)&out[base + 4] = make_float4(v[4]*inv*g1.x + b1.x, v[5]*inv*g1.y + b1.y,
                                         v[6]*inv*g1.z + b1.z, v[7]*inv*g1.w + b1.w);
}

// ---------------- deterministic list build ----------------
__global__ __launch_bounds__(256) void build_lists(
    const int* __restrict__ tok_pack, const float2* __restrict__ tok_w,
    int* __restrict__ counts, int* __restrict__ list, float* __restrict__ wlist)
{
  const int e = blockIdx.x;
  const int tid = threadIdx.x;
  const int lane = tid & 63, wave = tid >> 6;
  __shared__ int wtot[4];
  __shared__ int runb;
  if (tid == 0) runb = 0;
  __syncthreads();
  for (int c = 0; c < 32; c++) {
    const int t = c * 256 + tid;
    const int pk = tok_pack[t];
    const int i1 = pk & 255, i2 = (pk >> 8) & 255;
    const bool s1 = (i1 == e);
    const bool flag = s1 || (i2 == e);
    const unsigned long long mask = __ballot(flag);
    if (lane == 63) wtot[wave] = __popcll(mask);
    __syncthreads();
    int wbase = 0;
#pragma unroll
    for (int w2 = 0; w2 < 4; w2++) if (w2 < wave) wbase += wtot[w2];
    const int btot = wtot[0] + wtot[1] + wtot[2] + wtot[3];
    if (flag) {
      const int pre = __popcll(mask & ((1ull << lane) - 1ull));
      const int pos = runb + wbase + pre;
      list[e * 8192 + pos] = 2 * t + (s1 ? 0 : 1);
      float2 w = tok_w[t];
      wlist[e * 8192 + pos] = s1 ? w.x : w.y;
    }
    __syncthreads();
    if (tid == 0) runb += btot;
    __syncthreads();
  }
  if (tid == 0) counts[e] = runb;
}

__global__ __launch_bounds__(256) void gate_reduce(
    const float* __restrict__ partials, float* __restrict__ loss_out)
{
  __shared__ float acc[16][16];
  __shared__ float fin[16];
  const int c = threadIdx.x & 15, grp = threadIdx.x >> 4;
  float s = 0.f;
  for (int i = grp; i < 2048; i += 16) s += partials[(size_t)i * 16 + c];
  acc[grp][c] = s;
  __syncthreads();
  if (threadIdx.x < 16) {
    float t2 = 0.f;
    for (int g2 = 0; g2 < 16; g2++) t2 += acc[g2][threadIdx.x];
    fin[threadIdx.x] = t2;
  }
  __syncthreads();
  if (threadIdx.x == 0) {
    float loss = 0.f;
    for (int e = 0; e < 8; e++)
      loss += (fin[e] * (1.f / TT)) * (fin[8 + e] * (1.f / TT));
    loss_out[0] = loss * 8.f;
  }
}

// ---------------- host-side launcher ----------------
extern "C" void kernel_launch(void* const* d_in, const int* in_sizes, int n_in,
                              void* d_out, int out_size, void* d_ws, size_t ws_size,
                              hipStream_t stream) {
  const float* x    = (const float*)d_in[0];
  const float* wq   = (const float*)d_in[1];
  const float* bq   = (const float*)d_in[2];
  const float* wk   = (const float*)d_in[3];
  const float* bk   = (const float*)d_in[4];
  const float* wv   = (const float*)d_in[5];
  const float* bv   = (const float*)d_in[6];
  const float* in_w = (const float*)d_in[7];
  const float* in_b = (const float*)d_in[8];
  const float* out_w= (const float*)d_in[9];
  const float* out_b= (const float*)d_in[10];
  const float* ln1g = (const float*)d_in[11];
  const float* ln1b = (const float*)d_in[12];
  const float* ln2g = (const float*)d_in[13];
  const float* ln2b = (const float*)d_in[14];
  const float* shw  = (const float*)d_in[15];
  const float* shb  = (const float*)d_in[16];
  const float* gw   = (const float*)d_in[17];
  const float* gb   = (const float*)d_in[18];
  const float* expw = (const float*)d_in[19];
  const float* expb = (const float*)d_in[20];

  char* ws = (char*)d_ws;
  // --- static region ---
  u16t* xb     = (u16t*)(ws + 0);          // 8 MB
  u16t* inwb   = (u16t*)(ws + 8388608);    // 1.5 MB
  u16t* w3t    = (u16t*)(ws + 9961472);    // 1.5 MB
  u16t* w2big  = (u16t*)(ws + 11534336);   // 1.5 MB
  u16t* outwb  = (u16t*)(ws + 13107200);   // 0.5 MB
  u16t* shwb   = (u16t*)(ws + 13631488);   // 0.5 MB
  u16t* expwb  = (u16t*)(ws + 14155776);   // 4 MB
  float* b2    = (float*)(ws + 18350080);  // 6 KB
  int*  tok_pack = (int*)(ws + 18356224);  // 32 KB
  float2* tok_w  = (float2*)(ws + 18388992); // 64 KB
  int*  counts = (int*)(ws + 18454528);
  int*  list   = (int*)(ws + 18454656);    // 256 KB
  float* wlist = (float*)(ws + 18716800);  // 256 KB
  float* parts = (float*)(ws + 18978944);  // 128 KB
  // --- overlay pool ---
  const size_t S = 19110016;
  u16t* qkvb   = (u16t*)(ws + S);                 // 24 MB: stage1 -> attn
  u16t* aopb   = (u16t*)(ws + S);                 // 8 MB: outproj -> ln1 (qkvb dead)
  u16t* x1b    = (u16t*)(ws + S + 16777216);      // 8 MB: ln1 -> moe/shared/ln2
  u16t* oslots = (u16t*)(ws + S);                 // 16 MB: moe -> ln2 (aopb dead)
  u16t* aob    = (u16t*)(ws + 0);                 // 8 MB: attn -> outproj (xb dead)
  u16t* shrd   = (u16t*)(ws + 0);                 // 8 MB: shared -> ln2 (aob dead)
  float* outp  = (float*)d_out;

  dim3 blk(256);
  // converts
  cvtk<<<4096, blk, 0, stream>>>(x, xb, TT * EE);
  cvtk<<<768,  blk, 0, stream>>>(in_w, inwb, 3 * EE * EE);
  cvtk<<<256,  blk, 0, stream>>>(out_w, outwb, EE * EE);
  cvtk<<<256,  blk, 0, stream>>>(shw, shwb, EE * EE);
  cvtk<<<2048, blk, 0, stream>>>(expw, expwb, NEXP * EE * EE);
  cvt_t<<<dim3(8, 8, 3), blk, 0, stream>>>(wq, wk, wv, w3t);
  // weight/bias composition
  compose_k<<<dim3(8, 8, 3), blk, 0, stream>>>(inwb, w3t, w2big);
  bias_mv<<<24, blk, 0, stream>>>(in_w, in_b, bq, bk, bv, b2);
  // fused QKV projection -> q|k|v packed (ldc 1536)
  gemm_bt<0,1><<<dim3(64, 12), blk, 0, stream>>>(xb, EE, w2big, b2, qkvb, 1536, EE);
  // attention
  attn_kernel<<<dim3(64, 16), blk, 0, stream>>>(qkvb, aob);
  // out projection (bf16 out, 64x64 tiles)
  gemm64<0><<<dim3(128, 8), blk, 0, stream>>>(aob, EE, outwb, out_b, aopb, EE, EE);
  // fused LN1 + gate
  ln1_gate<<<2048, blk, 0, stream>>>(x, aopb, ln1g, ln1b, gw, gb, x1b, tok_pack, tok_w, parts);
  build_lists<<<8, blk, 0, stream>>>(tok_pack, tok_w, counts, list, wlist);
  gate_reduce<<<1, blk, 0, stream>>>(parts, outp + (size_t)TT * EE);
  // shared expert (leaky, 64x64 tiles)
  gemm64<1><<<dim3(128, 8), blk, 0, stream>>>(x1b, EE, shwb, shb, shrd, EE, EE);
  // sparse MoE (64-token tiles)
  moe_sparse<<<dim3(1024, 8), blk, 0, stream>>>(x1b, expwb, expb, counts, list, wlist, oslots);
  // LN2 -> output (f32)
  ln2_kernel<<<2048, blk, 0, stream>>>(x1b, oslots, shrd, ln2g, ln2b, outp);
}

// Round 8
// 200.524 us; speedup vs baseline: 1.8126x; 1.1649x over previous
//
#include <hip/hip_runtime.h>
#include <stdint.h>

// Problem dims (fixed)
#define LL   1024
#define BB   8
#define EE   512
#define HH   8
#define HDD  64
#define NEXP 8
#define TT   8192   // L*B tokens

typedef unsigned short u16t;
typedef __bf16 bf16x8 __attribute__((ext_vector_type(8)));
typedef u16t   u16x8  __attribute__((ext_vector_type(8)));
typedef u16t   u16x4  __attribute__((ext_vector_type(4)));
typedef float  f32x4  __attribute__((ext_vector_type(4)));

#define LAM 0.18033688011112042f   // log2(e)/8 : folded into Q projection

__device__ __forceinline__ u16t f2bf(float f) {
  union { float f; unsigned int u; } a; a.f = f;
  unsigned int r = a.u + 0x7fffu + ((a.u >> 16) & 1u);
  return (u16t)(r >> 16);
}
__device__ __forceinline__ float bf2f(u16t s) {
  union { unsigned int u; float f; } a; a.u = ((unsigned int)s) << 16; return a.f;
}

__device__ __forceinline__ f32x4 mfma16(bf16x8 a, bf16x8 b, f32x4 c) {
  return __builtin_amdgcn_mfma_f32_16x16x32_bf16(a, b, c, 0, 0, 0);
}

#define GLDS16(gp, lp) \
  __builtin_amdgcn_global_load_lds( \
      (const __attribute__((address_space(1))) unsigned int*)(const void*)(gp), \
      (__attribute__((address_space(3))) unsigned int*)(void*)(lp), 16, 0, 0)

// ---------------- all f32->bf16 converts in ONE dispatch (block-range) ----------------
__global__ __launch_bounds__(256) void cvt_all(
    const float* __restrict__ x, const float* __restrict__ in_w,
    const float* __restrict__ out_w, const float* __restrict__ shw,
    const float* __restrict__ expw,
    u16t* __restrict__ xb, u16t* __restrict__ inwb, u16t* __restrict__ outwb,
    u16t* __restrict__ shwb, u16t* __restrict__ expwb) {
  const int bid = blockIdx.x;
  const float* s; u16t* d; int i;
  if (bid < 4096)      { s = x;     d = xb;    i = bid; }
  else if (bid < 4864) { s = in_w;  d = inwb;  i = bid - 4096; }
  else if (bid < 5120) { s = out_w; d = outwb; i = bid - 4864; }
  else if (bid < 5376) { s = shw;   d = shwb;  i = bid - 5120; }
  else                 { s = expw;  d = expwb; i = bid - 5376; }
  const int idx = (i * 256 + threadIdx.x) * 4;
  float4 v = *(const float4*)&s[idx];
  u16x4 o = { f2bf(v.x), f2bf(v.y), f2bf(v.z), f2bf(v.w) };
  *(u16x4*)&d[idx] = o;
}

// ---------------- transpose-convert: out[n][j] = bf16(in[j][n]), 512x512, z=3 ----------------
__global__ __launch_bounds__(256) void cvt_t(const float* __restrict__ w0,
                                             const float* __restrict__ w1,
                                             const float* __restrict__ w2,
                                             u16t* __restrict__ out) {
  const float* src = blockIdx.z == 0 ? w0 : blockIdx.z == 1 ? w1 : w2;
  u16t* dst = out + (size_t)blockIdx.z * 262144;
  __shared__ float tile[64][65];
  const int r = threadIdx.x >> 4;
  const int c = (threadIdx.x & 15) * 4;
  const int r0 = blockIdx.y * 64, c0 = blockIdx.x * 64;
#pragma unroll
  for (int i = 0; i < 4; i++) {
    float4 v = *(const float4*)&src[(size_t)(r0 + r + i * 16) * 512 + c0 + c];
    tile[r + i * 16][c] = v.x; tile[r + i * 16][c + 1] = v.y;
    tile[r + i * 16][c + 2] = v.z; tile[r + i * 16][c + 3] = v.w;
  }
  __syncthreads();
#pragma unroll
  for (int i = 0; i < 4; i++) {
    const int orow = c0 + r + i * 16;
    u16x4 o = { f2bf(tile[c][r + i * 16]), f2bf(tile[c + 1][r + i * 16]),
                f2bf(tile[c + 2][r + i * 16]), f2bf(tile[c + 3][r + i * 16]) };
    *(u16x4*)&dst[(size_t)orow * 512 + r0 + c] = o;
  }
}

// ---------------- composed-weight GEMM (64x64 tiles); z==0 (Q) scaled by LAM ----------------
__global__ __launch_bounds__(256) void compose_k(const u16t* __restrict__ Aall,
                                                 const u16t* __restrict__ Wall,
                                                 u16t* __restrict__ Call) {
  const u16t* A = Aall + (size_t)blockIdx.z * 262144;
  const u16t* W = Wall + (size_t)blockIdx.z * 262144;
  u16t* C = Call + (size_t)blockIdx.z * 262144;
  const float scale = blockIdx.z == 0 ? LAM : 1.0f;
  __shared__ alignas(16) u16t As[64 * 32];
  __shared__ alignas(16) u16t Ws[64 * 32];
  const int tid = threadIdx.x;
  const int lane = tid & 63, wave = tid >> 6;
  const int r15 = lane & 15, rhi = lane >> 4;
  const int wr = wave >> 1, wc = wave & 1;
  const int m0 = blockIdx.x * 64, n0 = blockIdx.y * 64;
  const int arow = tid >> 2, acol = (tid & 3) * 8;
  const f32x4 fz = {0.f, 0.f, 0.f, 0.f};
  f32x4 acc[2][2] = {{fz, fz}, {fz, fz}};
  const u16t* Ap = A + (size_t)(m0 + arow) * 512 + acol;
  const u16t* Wp = W + (size_t)(n0 + arow) * 512 + acol;
  u16t* As0 = &As[tid * 8];
  u16t* Ws0 = &Ws[tid * 8];
  for (int kt = 0; kt < 512; kt += 32) {
    __syncthreads();
    GLDS16(Ap + kt, As0);
    GLDS16(Wp + kt, Ws0);
    asm volatile("s_waitcnt vmcnt(0)" ::: "memory");
    __syncthreads();
    bf16x8 af[2], bfv[2];
#pragma unroll
    for (int mi = 0; mi < 2; mi++)
      af[mi] = *(const bf16x8*)&As[(wr * 32 + mi * 16 + r15) * 32 + rhi * 8];
#pragma unroll
    for (int ni = 0; ni < 2; ni++)
      bfv[ni] = *(const bf16x8*)&Ws[(wc * 32 + ni * 16 + r15) * 32 + rhi * 8];
#pragma unroll
    for (int mi = 0; mi < 2; mi++)
#pragma unroll
      for (int ni = 0; ni < 2; ni++)
        acc[mi][ni] = mfma16(af[mi], bfv[ni], acc[mi][ni]);
  }
#pragma unroll
  for (int mi = 0; mi < 2; mi++)
#pragma unroll
    for (int ni = 0; ni < 2; ni++) {
      const int col = n0 + wc * 32 + ni * 16 + r15;
#pragma unroll
      for (int r = 0; r < 4; r++) {
        const int row = m0 + wr * 32 + mi * 16 + rhi * 4 + r;
        C[(size_t)row * 512 + col] = f2bf(acc[mi][ni][r] * scale);
      }
    }
}

// ---------------- composed bias (seg 0 scaled by LAM) ----------------
__global__ __launch_bounds__(256) void bias_mv(const float* __restrict__ in_w,
                                               const float* __restrict__ in_b,
                                               const float* __restrict__ b0,
                                               const float* __restrict__ b1,
                                               const float* __restrict__ b2v,
                                               float* __restrict__ out) {
  const int bi = blockIdx.x;                 // 24 blocks
  const int seg = bi >> 3, m0 = (bi & 7) * 64;
  const float* bvec = seg == 0 ? b0 : seg == 1 ? b1 : b2v;
  const int m = m0 + (threadIdx.x >> 2), q = threadIdx.x & 3;
  const float* row = in_w + (size_t)(seg * 512 + m) * 512 + q * 128;
  const float* bv = bvec + q * 128;
  float s = 0.f;
  for (int j = 0; j < 128; j++) s += row[j] * bv[j];
  s += __shfl_xor(s, 1); s += __shfl_xor(s, 2);
  if (q == 0) {
    float r2 = s + in_b[seg * 512 + m];
    out[seg * 512 + m] = seg == 0 ? r2 * LAM : r2;
  }
}

// ---------------- 128x128-tile GEMM (stage-1 QKV): C = A @ W^T + bias ----------------
template<int ACT, int OUTBF>
__global__ __launch_bounds__(256) void gemm_bt(
    const u16t* __restrict__ A, int lda,
    const u16t* __restrict__ W,
    const float* __restrict__ bias,
    void* __restrict__ Cp, int ldc, int K)
{
  __shared__ alignas(16) u16t As[128 * 32];
  __shared__ alignas(16) u16t Ws[128 * 32];
  const int tid  = threadIdx.x;
  const int lane = tid & 63, wave = tid >> 6;
  const int r15  = lane & 15, rhi = lane >> 4;
  const int wr   = wave >> 1, wc  = wave & 1;
  const int m0 = blockIdx.x * 128, n0 = blockIdx.y * 128;
  const int arow = tid >> 2, acol = (tid & 3) * 8;

  const f32x4 fz = {0.f, 0.f, 0.f, 0.f};
  f32x4 acc[4][4];
#pragma unroll
  for (int i = 0; i < 4; i++)
#pragma unroll
    for (int j = 0; j < 4; j++) acc[i][j] = fz;

  const u16t* Ap0 = A + (size_t)(m0 + arow) * lda + acol;
  const u16t* Ap1 = A + (size_t)(m0 + arow + 64) * lda + acol;
  const u16t* Wp0 = W + (size_t)(n0 + arow) * K + acol;
  const u16t* Wp1 = W + (size_t)(n0 + arow + 64) * K + acol;
  u16t* As0 = &As[tid * 8];       u16t* As1 = &As[(tid + 256) * 8];
  u16t* Ws0 = &Ws[tid * 8];       u16t* Ws1 = &Ws[(tid + 256) * 8];

  for (int kt = 0; kt < K; kt += 32) {
    __syncthreads();
    GLDS16(Ap0 + kt, As0);
    GLDS16(Ap1 + kt, As1);
    GLDS16(Wp0 + kt, Ws0);
    GLDS16(Wp1 + kt, Ws1);
    asm volatile("s_waitcnt vmcnt(0)" ::: "memory");
    __syncthreads();
    bf16x8 af[4], bfv[4];
#pragma unroll
    for (int mi = 0; mi < 4; mi++)
      af[mi] = *(const bf16x8*)&As[(wr * 64 + mi * 16 + r15) * 32 + rhi * 8];
#pragma unroll
    for (int ni = 0; ni < 4; ni++)
      bfv[ni] = *(const bf16x8*)&Ws[(wc * 64 + ni * 16 + r15) * 32 + rhi * 8];
#pragma unroll
    for (int mi = 0; mi < 4; mi++)
#pragma unroll
      for (int ni = 0; ni < 4; ni++)
        acc[mi][ni] = mfma16(af[mi], bfv[ni], acc[mi][ni]);
  }

#pragma unroll
  for (int mi = 0; mi < 4; mi++) {
#pragma unroll
    for (int ni = 0; ni < 4; ni++) {
      const int col = n0 + wc * 64 + ni * 16 + r15;
      const float bv = bias[col];
#pragma unroll
      for (int r = 0; r < 4; r++) {
        const int row = m0 + wr * 64 + mi * 16 + rhi * 4 + r;
        float v = acc[mi][ni][r] + bv;
        if (ACT == 1) v = v >= 0.f ? v : 0.01f * v;
        if (OUTBF) ((u16t*)Cp)[(size_t)row * ldc + col] = f2bf(v);
        else       ((float*)Cp)[(size_t)row * ldc + col] = v;
      }
    }
  }
}

// ---------------- 64x64-tile GEMM (out-proj) ----------------
template<int ACT>
__global__ __launch_bounds__(256) void gemm64(
    const u16t* __restrict__ A, int lda,
    const u16t* __restrict__ W,
    const float* __restrict__ bias,
    u16t* __restrict__ Cp, int ldc, int K)
{
  __shared__ alignas(16) u16t As[64 * 32];
  __shared__ alignas(16) u16t Ws[64 * 32];
  const int tid  = threadIdx.x;
  const int lane = tid & 63, wave = tid >> 6;
  const int r15  = lane & 15, rhi = lane >> 4;
  const int wr   = wave >> 1, wc  = wave & 1;
  const int m0 = blockIdx.x * 64, n0 = blockIdx.y * 64;
  const int arow = tid >> 2, acol = (tid & 3) * 8;

  const f32x4 fz = {0.f, 0.f, 0.f, 0.f};
  f32x4 acc[2][2] = {{fz, fz}, {fz, fz}};

  const u16t* Ap = A + (size_t)(m0 + arow) * lda + acol;
  const u16t* Wp = W + (size_t)(n0 + arow) * K + acol;
  u16t* As0 = &As[tid * 8];
  u16t* Ws0 = &Ws[tid * 8];

  for (int kt = 0; kt < K; kt += 32) {
    __syncthreads();
    GLDS16(Ap + kt, As0);
    GLDS16(Wp + kt, Ws0);
    asm volatile("s_waitcnt vmcnt(0)" ::: "memory");
    __syncthreads();
    bf16x8 af[2], bfv[2];
#pragma unroll
    for (int mi = 0; mi < 2; mi++)
      af[mi] = *(const bf16x8*)&As[(wr * 32 + mi * 16 + r15) * 32 + rhi * 8];
#pragma unroll
    for (int ni = 0; ni < 2; ni++)
      bfv[ni] = *(const bf16x8*)&Ws[(wc * 32 + ni * 16 + r15) * 32 + rhi * 8];
#pragma unroll
    for (int mi = 0; mi < 2; mi++)
#pragma unroll
      for (int ni = 0; ni < 2; ni++)
        acc[mi][ni] = mfma16(af[mi], bfv[ni], acc[mi][ni]);
  }

#pragma unroll
  for (int mi = 0; mi < 2; mi++)
#pragma unroll
    for (int ni = 0; ni < 2; ni++) {
      const int col = n0 + wc * 32 + ni * 16 + r15;
      const float bv = bias[col];
#pragma unroll
      for (int r = 0; r < 4; r++) {
        const int row = m0 + wr * 32 + mi * 16 + rhi * 4 + r;
        float v = acc[mi][ni][r] + bv;
        if (ACT == 1) v = v >= 0.f ? v : 0.01f * v;
        Cp[(size_t)row * ldc + col] = f2bf(v);
      }
    }
}

// ---------------- sparse MoE + shared expert in ONE dispatch ----------------
// e in [0,8): compacted expert-token tiles -> out_slots[slot]
// e == 8:    shared expert over all tokens (weight 1) -> shrd[token]
__global__ __launch_bounds__(256) void moe_shared(
    const u16t* __restrict__ x1b, const u16t* __restrict__ expwb,
    const float* __restrict__ expb,
    const u16t* __restrict__ shwb, const float* __restrict__ shb,
    const int* __restrict__ counts,
    const int* __restrict__ list, const float* __restrict__ wlist,
    u16t* __restrict__ out_slots, u16t* __restrict__ shrd)
{
  const int e = blockIdx.x >> 7, mt = blockIdx.x & 127;
  const bool sh = (e == 8);
  const int cnt = sh ? TT : counts[e];
  const int m0 = mt * 64;
  if (m0 >= cnt) return;
  const int n0 = blockIdx.y * 64;
  __shared__ alignas(16) u16t As[64 * 32];
  __shared__ alignas(16) u16t Ws[64 * 32];
  __shared__ int tks[64];
  __shared__ float wws[64];
  const int tid  = threadIdx.x;
  const int lane = tid & 63, wave = tid >> 6;
  const int r15  = lane & 15, rhi = lane >> 4;
  const int wr   = wave >> 1, wc  = wave & 1;
  const int arow = tid >> 2, acol = (tid & 3) * 8;

  if (tid < 64) {
    if (sh) { tks[tid] = m0 + tid; wws[tid] = 1.f; }
    else {
      int idx = m0 + tid; if (idx >= cnt) idx = cnt - 1;
      tks[tid] = list[e * 8192 + idx];
      wws[tid] = wlist[e * 8192 + idx];
    }
  }
  __syncthreads();
  const int tokA = sh ? tks[arow] : (tks[arow] >> 1);

  const f32x4 fz = {0.f, 0.f, 0.f, 0.f};
  f32x4 acc[2][2] = {{fz, fz}, {fz, fz}};

  const u16t* Ap = x1b + (size_t)tokA * 512 + acol;
  const u16t* W  = (sh ? shwb : expwb + (size_t)e * 262144);
  const float* bias = sh ? shb : expb + e * 512;
  u16t* outp = sh ? shrd : out_slots;
  const u16t* Wp = W + (size_t)(n0 + arow) * 512 + acol;
  u16t* As0 = &As[tid * 8];
  u16t* Ws0 = &Ws[tid * 8];

  for (int kt = 0; kt < 512; kt += 32) {
    __syncthreads();
    GLDS16(Ap + kt, As0);
    GLDS16(Wp + kt, Ws0);
    asm volatile("s_waitcnt vmcnt(0)" ::: "memory");
    __syncthreads();
    bf16x8 af[2], bfv[2];
#pragma unroll
    for (int mi = 0; mi < 2; mi++)
      af[mi] = *(const bf16x8*)&As[(wr * 32 + mi * 16 + r15) * 32 + rhi * 8];
#pragma unroll
    for (int ni = 0; ni < 2; ni++)
      bfv[ni] = *(const bf16x8*)&Ws[(wc * 32 + ni * 16 + r15) * 32 + rhi * 8];
#pragma unroll
    for (int mi = 0; mi < 2; mi++)
#pragma unroll
      for (int ni = 0; ni < 2; ni++)
        acc[mi][ni] = mfma16(af[mi], bfv[ni], acc[mi][ni]);
  }

#pragma unroll
  for (int mi = 0; mi < 2; mi++)
#pragma unroll
    for (int ni = 0; ni < 2; ni++) {
      const int col = n0 + wc * 32 + ni * 16 + r15;
      const float bv = bias[col];
#pragma unroll
      for (int r = 0; r < 4; r++) {
        const int rl = wr * 32 + mi * 16 + rhi * 4 + r;
        if (m0 + rl < cnt) {
          float z = acc[mi][ni][r] + bv;
          z = z >= 0.f ? z : 0.01f * z;
          outp[(size_t)tks[rl] * 512 + col] = f2bf(wws[rl] * z);
        }
      }
    }
}

// ---------------- flash attention v2 (Q pre-scaled by LAM upstream) ----------------
__global__ __launch_bounds__(256) void attn_kernel(
    const u16t* __restrict__ qkv, u16t* __restrict__ ao)
{
  const int bh = blockIdx.x;
  const int b = bh >> 3, h = bh & 7;
  const int qt = blockIdx.y;
  const int tid  = threadIdx.x;
  const int lane = tid & 63, wave = tid >> 6;
  const int r15  = lane & 15, rhi = lane >> 4;

  __shared__ alignas(16) u16t Ks[128 * 72];
  __shared__ alignas(16) u16t Vt[64 * 136];

  const int qrow = qt * 64 + wave * 16 + r15;
  const size_t qoff = ((size_t)qrow * BB + b) * 1536 + h * HDD;
  const bf16x8 qf0 = *(const bf16x8*)&qkv[qoff + rhi * 8];
  const bf16x8 qf1 = *(const bf16x8*)&qkv[qoff + 32 + rhi * 8];

  const f32x4 fz = {0.f, 0.f, 0.f, 0.f};
  f32x4 oa[4] = {fz, fz, fz, fz};
  float psum = 0.f;

  const int krow = tid >> 1, khalf = tid & 1;
  const int vd0 = wave * 16;

  u16x8 kA0, kA1, kA2, kA3, vA0, vA1, vA2, vA3;
  {
    const size_t kb = ((size_t)krow * BB + b) * 1536 + h * HDD + 512 + khalf * 32;
    kA0 = *(const u16x8*)&qkv[kb];      kA1 = *(const u16x8*)&qkv[kb + 8];
    kA2 = *(const u16x8*)&qkv[kb + 16]; kA3 = *(const u16x8*)&qkv[kb + 24];
    const size_t v0 = ((size_t)(2 * lane) * BB + b) * 1536 + h * HDD + 1024 + vd0;
    const size_t v1 = v0 + (size_t)BB * 1536;
    vA0 = *(const u16x8*)&qkv[v0]; vA1 = *(const u16x8*)&qkv[v0 + 8];
    vA2 = *(const u16x8*)&qkv[v1]; vA3 = *(const u16x8*)&qkv[v1 + 8];
  }

  for (int t = 0; t < 8; t++) {
    __syncthreads();
    {
      u16t* kd = &Ks[krow * 72 + khalf * 32];
      *(u16x8*)&kd[0]  = kA0; *(u16x8*)&kd[8]  = kA1;
      *(u16x8*)&kd[16] = kA2; *(u16x8*)&kd[24] = kA3;
    }
#pragma unroll
    for (int j = 0; j < 8; j++) {
      unsigned int w = (unsigned int)vA0[j] | ((unsigned int)vA2[j] << 16);
      *(unsigned int*)&Vt[(vd0 + j) * 136 + 2 * lane] = w;
    }
#pragma unroll
    for (int j = 0; j < 8; j++) {
      unsigned int w = (unsigned int)vA1[j] | ((unsigned int)vA3[j] << 16);
      *(unsigned int*)&Vt[(vd0 + 8 + j) * 136 + 2 * lane] = w;
    }
    if (t < 7) {
      const int kv0n = (t + 1) * 128;
      const size_t kb = ((size_t)(kv0n + krow) * BB + b) * 1536 + h * HDD + 512 + khalf * 32;
      kA0 = *(const u16x8*)&qkv[kb];      kA1 = *(const u16x8*)&qkv[kb + 8];
      kA2 = *(const u16x8*)&qkv[kb + 16]; kA3 = *(const u16x8*)&qkv[kb + 24];
      const size_t v0 = ((size_t)(kv0n + 2 * lane) * BB + b) * 1536 + h * HDD + 1024 + vd0;
      const size_t v1 = v0 + (size_t)BB * 1536;
      vA0 = *(const u16x8*)&qkv[v0]; vA1 = *(const u16x8*)&qkv[v0 + 8];
      vA2 = *(const u16x8*)&qkv[v1]; vA3 = *(const u16x8*)&qkv[v1 + 8];
    }
    __syncthreads();

    f32x4 s[8];
    __builtin_amdgcn_s_setprio(1);
#pragma unroll
    for (int nt = 0; nt < 8; nt++) {
      const u16t* kr = &Ks[(nt * 16 + r15) * 72];
      bf16x8 k0 = *(const bf16x8*)&kr[rhi * 8];
      bf16x8 k1 = *(const bf16x8*)&kr[32 + rhi * 8];
      f32x4 acc = fz;
      acc = mfma16(k0, qf0, acc);
      acc = mfma16(k1, qf1, acc);
      s[nt] = acc;
    }
    __builtin_amdgcn_s_setprio(0);

    unsigned int P2[8][2];
#pragma unroll
    for (int nt = 0; nt < 8; nt++) {
#pragma unroll
      for (int r = 0; r < 4; r++) {
        s[nt][r] = exp2f(s[nt][r]);   // Q pre-scaled by log2e/8
        psum += s[nt][r];
      }
      asm("v_cvt_pk_bf16_f32 %0, %1, %2" : "=v"(P2[nt][0]) : "v"(s[nt][0]), "v"(s[nt][1]));
      asm("v_cvt_pk_bf16_f32 %0, %1, %2" : "=v"(P2[nt][1]) : "v"(s[nt][2]), "v"(s[nt][3]));
    }

    __builtin_amdgcn_s_setprio(1);
#pragma unroll
    for (int c = 0; c < 4; c++) {
      union { unsigned int w[4]; bf16x8 v; } pf;
      pf.w[0] = P2[2 * c][0];     pf.w[1] = P2[2 * c][1];
      pf.w[2] = P2[2 * c + 1][0]; pf.w[3] = P2[2 * c + 1][1];
#pragma unroll
      for (int dd = 0; dd < 4; dd++) {
        const u16t* vr = &Vt[(dd * 16 + r15) * 136 + c * 32 + rhi * 4];
        union { u16x4 h[2]; bf16x8 v; } vb;
        vb.h[0] = *(const u16x4*)&vr[0];
        vb.h[1] = *(const u16x4*)&vr[16];
        oa[dd] = mfma16(vb.v, pf.v, oa[dd]);
      }
    }
    __builtin_amdgcn_s_setprio(0);
  }

  float ls = psum;
  ls += __shfl_xor(ls, 16);
  ls += __shfl_xor(ls, 32);
  const float inv = 1.f / ls;
  const size_t obase = ((size_t)qrow * BB + b) * EE + h * HDD;
#pragma unroll
  for (int dd = 0; dd < 4; dd++) {
    u16x4 o = { f2bf(oa[dd][0] * inv), f2bf(oa[dd][1] * inv),
                f2bf(oa[dd][2] * inv), f2bf(oa[dd][3] * inv) };
    *(u16x4*)&ao[obase + dd * 16 + rhi * 4] = o;
  }
}

// ---------------- fused LN1 + gate (wave per token) ----------------
__device__ __forceinline__ float wave_sum(float v) {
#pragma unroll
  for (int off = 1; off < 64; off <<= 1) v += __shfl_xor(v, off);
  return v;
}

__global__ __launch_bounds__(256) void ln1_gate(
    const float* __restrict__ x, const u16t* __restrict__ aopb,
    const float* __restrict__ g, const float* __restrict__ be,
    const float* __restrict__ gw, const float* __restrict__ gb,
    u16t* __restrict__ x1b,
    int* __restrict__ tok_pack, float2* __restrict__ tok_w,
    float* __restrict__ partials)
{
  const int wave = threadIdx.x >> 6, lane = threadIdx.x & 63;
  const int t = blockIdx.x * 4 + wave;
  const size_t base = (size_t)t * EE + lane * 8;
  float4 a0 = *(const float4*)&x[base], a1 = *(const float4*)&x[base + 4];
  u16x8 ap = *(const u16x8*)&aopb[base];
  float v[8] = { a0.x + bf2f(ap[0]), a0.y + bf2f(ap[1]), a0.z + bf2f(ap[2]), a0.w + bf2f(ap[3]),
                 a1.x + bf2f(ap[4]), a1.y + bf2f(ap[5]), a1.z + bf2f(ap[6]), a1.w + bf2f(ap[7]) };
  float s = 0.f;
#pragma unroll
  for (int i = 0; i < 8; i++) s += v[i];
  const float mean = wave_sum(s) * (1.f / EE);
  float vs = 0.f;
#pragma unroll
  for (int i = 0; i < 8; i++) { v[i] -= mean; vs += v[i] * v[i]; }
  const float inv = rsqrtf(wave_sum(vs) * (1.f / EE) + 1e-5f);
  float4 g0 = *(const float4*)&g[lane * 8],  g1 = *(const float4*)&g[lane * 8 + 4];
  float4 b0 = *(const float4*)&be[lane * 8], b1 = *(const float4*)&be[lane * 8 + 4];
  float o[8] = { v[0]*inv*g0.x + b0.x, v[1]*inv*g0.y + b0.y, v[2]*inv*g0.z + b0.z, v[3]*inv*g0.w + b0.w,
                 v[4]*inv*g1.x + b1.x, v[5]*inv*g1.y + b1.y, v[6]*inv*g1.z + b1.z, v[7]*inv*g1.w + b1.w };
  u16x8 ob = { f2bf(o[0]), f2bf(o[1]), f2bf(o[2]), f2bf(o[3]),
               f2bf(o[4]), f2bf(o[5]), f2bf(o[6]), f2bf(o[7]) };
  *(u16x8*)&x1b[base] = ob;

  float pe[8];
  float mx = -1e30f;
#pragma unroll
  for (int e = 0; e < 8; e++) {
    float4 ga = *(const float4*)&gw[e * EE + lane * 8];
    float4 gB = *(const float4*)&gw[e * EE + lane * 8 + 4];
    float d = o[0]*ga.x + o[1]*ga.y + o[2]*ga.z + o[3]*ga.w
            + o[4]*gB.x + o[5]*gB.y + o[6]*gB.z + o[7]*gB.w;
#pragma unroll
    for (int off = 1; off < 64; off <<= 1) d += __shfl_xor(d, off);
    pe[e] = d + gb[e];
    mx = fmaxf(mx, pe[e]);
  }
  float se = 0.f;
#pragma unroll
  for (int e = 0; e < 8; e++) { pe[e] = __expf(pe[e] - mx); se += pe[e]; }
  const float invs = 1.f / se;
#pragma unroll
  for (int e = 0; e < 8; e++) pe[e] *= invs;
  float v1 = -1.f; int i1 = 0;
#pragma unroll
  for (int e = 0; e < 8; e++) if (pe[e] > v1) { v1 = pe[e]; i1 = e; }
  float v2 = -1.f; int i2 = -1;
#pragma unroll
  for (int e = 0; e < 8; e++) if (e != i1 && pe[e] > v2) { v2 = pe[e]; i2 = e; }
  const float denom = 1.f / (v1 + v2);
  if (lane == 0) {
    tok_pack[t] = i1 | (i2 << 8);
    float2 w; w.x = v1 * denom; w.y = v2 * denom;
    tok_w[t] = w;
  }
  __shared__ float fb[4][8], pb[4][8];
  if (lane < 8) {
    fb[wave][lane] = (lane == i1 || lane == i2) ? 1.f : 0.f;
    pb[wave][lane] = pe[lane];
  }
  __syncthreads();
  if (threadIdx.x < 8) {
    const int e = threadIdx.x;
    partials[(size_t)blockIdx.x * 16 + e]     = fb[0][e] + fb[1][e] + fb[2][e] + fb[3][e];
    partials[(size_t)blockIdx.x * 16 + 8 + e] = pb[0][e] + pb[1][e] + pb[2][e] + pb[3][e];
  }
}

// ---------------- LN2 (bf16 inputs) ----------------
__global__ __launch_bounds__(256) void ln2_kernel(
    const u16t* __restrict__ x1b, const u16t* __restrict__ slots,
    const u16t* __restrict__ sh,
    const float* __restrict__ g, const float* __restrict__ be,
    float* __restrict__ out)
{
  const int wave = threadIdx.x >> 6, lane = threadIdx.x & 63;
  const int t = blockIdx.x * 4 + wave;
  const size_t base = (size_t)t * EE + lane * 8;
  u16x8 xv = *(const u16x8*)&x1b[base];
  u16x8 m0 = *(const u16x8*)&slots[(size_t)(2 * t) * EE + lane * 8];
  u16x8 m1 = *(const u16x8*)&slots[(size_t)(2 * t + 1) * EE + lane * 8];
  u16x8 sv = *(const u16x8*)&sh[base];
  float v[8];
#pragma unroll
  for (int i = 0; i < 8; i++)
    v[i] = bf2f(xv[i]) + bf2f(m0[i]) + bf2f(m1[i]) + bf2f(sv[i]);
  float s = 0.f;
#pragma unroll
  for (int i = 0; i < 8; i++) s += v[i];
  const float mean = wave_sum(s) * (1.f / EE);
  float vs = 0.f;
#pragma unroll
  for (int i = 0; i < 8; i++) { v[i] -= mean; vs += v[i] * v[i]; }
  const float inv = rsqrtf(wave_sum(vs) * (1.f / EE) + 1e-5f);
  float4 g0 = *(const float4*)&g[lane * 8],  g1 = *(const float4*)&g[lane * 8 + 4];
  float4 b0 = *(const float4*)&be[lane * 8], b1 = *(const float4*)&be[lane * 8 + 4];
  *(float4*)&out[base] = make_float4(v[0]*inv*g0.x + b0.x, v[1]*inv*g0.y + b0.y,
                                     v[2]*inv*g0.z + b0.z, v[3]*inv*g0.w + b0.w);
  *(float4*)&out[base + 4] = make_float4(v[4]*inv*g1.x + b1.x, v[5]*inv*g1.y + b1.y,
                                         v[6]*inv*g1.z + b1.z, v[7]*inv*g1.w + b1.w);
}

// ---------------- deterministic list build + loss reduce (grid 9) ----------------
__global__ __launch_bounds__(256) void build_lists(
    const int* __restrict__ tok_pack, const float2* __restrict__ tok_w,
    int* __restrict__ counts, int* __restrict__ list, float* __restrict__ wlist,
    const float* __restrict__ partials, float* __restrict__ loss_out)
{
  if (blockIdx.x == 8) {
    // gating-loss reduction
    __shared__ float acc2[16][16];
    __shared__ float fin[16];
    const int c = threadIdx.x & 15, grp = threadIdx.x >> 4;
    float s = 0.f;
    for (int i = grp; i < 2048; i += 16) s += partials[(size_t)i * 16 + c];
    acc2[grp][c] = s;
    __syncthreads();
    if (threadIdx.x < 16) {
      float t2 = 0.f;
      for (int g2 = 0; g2 < 16; g2++) t2 += acc2[g2][threadIdx.x];
      fin[threadIdx.x] = t2;
    }
    __syncthreads();
    if (threadIdx.x == 0) {
      float loss = 0.f;
      for (int e = 0; e < 8; e++)
        loss += (fin[e] * (1.f / TT)) * (fin[8 + e] * (1.f / TT));
      loss_out[0] = loss * 8.f;
    }
    return;
  }
  const int e = blockIdx.x;
  const int tid = threadIdx.x;
  const int lane = tid & 63, wave = tid >> 6;
  __shared__ int wtot[4];
  __shared__ int runb;
  if (tid == 0) runb = 0;
  __syncthreads();
  for (int c = 0; c < 32; c++) {
    const int t = c * 256 + tid;
    const int pk = tok_pack[t];
    const int i1 = pk & 255, i2 = (pk >> 8) & 255;
    const bool s1 = (i1 == e);
    const bool flag = s1 || (i2 == e);
    const unsigned long long mask = __ballot(flag);
    if (lane == 63) wtot[wave] = __popcll(mask);
    __syncthreads();
    int wbase = 0;
#pragma unroll
    for (int w2 = 0; w2 < 4; w2++) if (w2 < wave) wbase += wtot[w2];
    const int btot = wtot[0] + wtot[1] + wtot[2] + wtot[3];
    if (flag) {
      const int pre = __popcll(mask & ((1ull << lane) - 1ull));
      const int pos = runb + wbase + pre;
      list[e * 8192 + pos] = 2 * t + (s1 ? 0 : 1);
      float2 w = tok_w[t];
      wlist[e * 8192 + pos] = s1 ? w.x : w.y;
    }
    __syncthreads();
    if (tid == 0) runb += btot;
    __syncthreads();
  }
  if (tid == 0) counts[e] = runb;
}

// ---------------- host-side launcher ----------------
extern "C" void kernel_launch(void* const* d_in, const int* in_sizes, int n_in,
                              void* d_out, int out_size, void* d_ws, size_t ws_size,
                              hipStream_t stream) {
  const float* x    = (const float*)d_in[0];
  const float* wq   = (const float*)d_in[1];
  const float* bq   = (const float*)d_in[2];
  const float* wk   = (const float*)d_in[3];
  const float* bk   = (const float*)d_in[4];
  const float* wv   = (const float*)d_in[5];
  const float* bv   = (const float*)d_in[6];
  const float* in_w = (const float*)d_in[7];
  const float* in_b = (const float*)d_in[8];
  const float* out_w= (const float*)d_in[9];
  const float* out_b= (const float*)d_in[10];
  const float* ln1g = (const float*)d_in[11];
  const float* ln1b = (const float*)d_in[12];
  const float* ln2g = (const float*)d_in[13];
  const float* ln2b = (const float*)d_in[14];
  const float* shw  = (const float*)d_in[15];
  const float* shb  = (const float*)d_in[16];
  const float* gw   = (const float*)d_in[17];
  const float* gb   = (const float*)d_in[18];
  const float* expw = (const float*)d_in[19];
  const float* expb = (const float*)d_in[20];

  char* ws = (char*)d_ws;
  // --- static region ---
  u16t* xb     = (u16t*)(ws + 0);          // 8 MB
  u16t* inwb   = (u16t*)(ws + 8388608);    // 1.5 MB
  u16t* w3t    = (u16t*)(ws + 9961472);    // 1.5 MB
  u16t* w2big  = (u16t*)(ws + 11534336);   // 1.5 MB
  u16t* outwb  = (u16t*)(ws + 13107200);   // 0.5 MB
  u16t* shwb   = (u16t*)(ws + 13631488);   // 0.5 MB
  u16t* expwb  = (u16t*)(ws + 14155776);   // 4 MB
  float* b2    = (float*)(ws + 18350080);  // 6 KB
  int*  tok_pack = (int*)(ws + 18356224);  // 32 KB
  float2* tok_w  = (float2*)(ws + 18388992); // 64 KB
  int*  counts = (int*)(ws + 18454528);
  int*  list   = (int*)(ws + 18454656);    // 256 KB
  float* wlist = (float*)(ws + 18716800);  // 256 KB
  float* parts = (float*)(ws + 18978944);  // 128 KB
  // --- overlay pool ---
  const size_t S = 19110016;
  u16t* qkvb   = (u16t*)(ws + S);                 // 24 MB: stage1 -> attn
  u16t* aopb   = (u16t*)(ws + S);                 // 8 MB: outproj -> ln1 (qkvb dead)
  u16t* x1b    = (u16t*)(ws + S + 16777216);      // 8 MB: ln1 -> moe/shared/ln2
  u16t* oslots = (u16t*)(ws + S);                 // 16 MB: moe -> ln2 (aopb dead)
  u16t* aob    = (u16t*)(ws + 0);                 // 8 MB: attn -> outproj (xb dead)
  u16t* shrd   = (u16t*)(ws + 0);                 // 8 MB: moe_shared -> ln2 (aob dead)
  float* outp  = (float*)d_out;

  dim3 blk(256);
  // all converts in one dispatch
  cvt_all<<<7424, blk, 0, stream>>>(x, in_w, out_w, shw, expw,
                                    xb, inwb, outwb, shwb, expwb);
  cvt_t<<<dim3(8, 8, 3), blk, 0, stream>>>(wq, wk, wv, w3t);
  // weight/bias composition (Q segment pre-scaled by log2e/8)
  compose_k<<<dim3(8, 8, 3), blk, 0, stream>>>(inwb, w3t, w2big);
  bias_mv<<<24, blk, 0, stream>>>(in_w, in_b, bq, bk, bv, b2);
  // fused QKV projection -> q|k|v packed (ldc 1536)
  gemm_bt<0,1><<<dim3(64, 12), blk, 0, stream>>>(xb, EE, w2big, b2, qkvb, 1536, EE);
  // attention
  attn_kernel<<<dim3(64, 16), blk, 0, stream>>>(qkvb, aob);
  // out projection (bf16 out, 64x64 tiles)
  gemm64<0><<<dim3(128, 8), blk, 0, stream>>>(aob, EE, outwb, out_b, aopb, EE, EE);
  // fused LN1 + gate
  ln1_gate<<<2048, blk, 0, stream>>>(x, aopb, ln1g, ln1b, gw, gb, x1b, tok_pack, tok_w, parts);
  // list build + loss reduce (grid 9)
  build_lists<<<9, blk, 0, stream>>>(tok_pack, tok_w, counts, list, wlist,
                                     parts, outp + (size_t)TT * EE);
  // sparse MoE + shared expert in one dispatch
  moe_shared<<<dim3(1152, 8), blk, 0, stream>>>(x1b, expwb, expb, shwb, shb,
                                                counts, list, wlist, oslots, shrd);
  // LN2 -> output (f32)
  ln2_kernel<<<2048, blk, 0, stream>>>(x1b, oslots, shrd, ln2g, ln2b, outp);
}

// Round 9
// 176.456 us; speedup vs baseline: 2.0599x; 1.1364x over previous
//
#include <hip/hip_runtime.h>
#include <stdint.h>

// Problem dims (fixed)
#define LL   1024
#define BB   8
#define EE   512
#define HH   8
#define HDD  64
#define NEXP 8
#define TT   8192   // L*B tokens

typedef unsigned short u16t;
typedef __bf16 bf16x8 __attribute__((ext_vector_type(8)));
typedef u16t   u16x8  __attribute__((ext_vector_type(8)));
typedef u16t   u16x4  __attribute__((ext_vector_type(4)));
typedef float  f32x4  __attribute__((ext_vector_type(4)));

#define LAM 0.18033688011112042f   // log2(e)/8 : folded into Q projection

__device__ __forceinline__ u16t f2bf(float f) {
  union { float f; unsigned int u; } a; a.f = f;
  unsigned int r = a.u + 0x7fffu + ((a.u >> 16) & 1u);
  return (u16t)(r >> 16);
}
__device__ __forceinline__ float bf2f(u16t s) {
  union { unsigned int u; float f; } a; a.u = ((unsigned int)s) << 16; return a.f;
}

__device__ __forceinline__ f32x4 mfma16(bf16x8 a, bf16x8 b, f32x4 c) {
  return __builtin_amdgcn_mfma_f32_16x16x32_bf16(a, b, c, 0, 0, 0);
}

#define GLDS16(gp, lp) \
  __builtin_amdgcn_global_load_lds( \
      (const __attribute__((address_space(1))) unsigned int*)(const void*)(gp), \
      (__attribute__((address_space(3))) unsigned int*)(void*)(lp), 16, 0, 0)

// ---------------- all f32->bf16 converts in ONE dispatch (block-range) ----------------
__global__ __launch_bounds__(256) void cvt_all(
    const float* __restrict__ x, const float* __restrict__ in_w,
    const float* __restrict__ out_w, const float* __restrict__ shw,
    const float* __restrict__ expw,
    u16t* __restrict__ xb, u16t* __restrict__ inwb, u16t* __restrict__ outwb,
    u16t* __restrict__ shwb, u16t* __restrict__ expwb) {
  const int bid = blockIdx.x;
  const float* s; u16t* d; int i;
  if (bid < 4096)      { s = x;     d = xb;    i = bid; }
  else if (bid < 4864) { s = in_w;  d = inwb;  i = bid - 4096; }
  else if (bid < 5120) { s = out_w; d = outwb; i = bid - 4864; }
  else if (bid < 5376) { s = shw;   d = shwb;  i = bid - 5120; }
  else                 { s = expw;  d = expwb; i = bid - 5376; }
  const int idx = (i * 256 + threadIdx.x) * 4;
  float4 v = *(const float4*)&s[idx];
  u16x4 o = { f2bf(v.x), f2bf(v.y), f2bf(v.z), f2bf(v.w) };
  *(u16x4*)&d[idx] = o;
}

// ---------------- transpose-convert: out[n][j] = bf16(in[j][n]), 512x512, z=3 ----------------
__global__ __launch_bounds__(256) void cvt_t(const float* __restrict__ w0,
                                             const float* __restrict__ w1,
                                             const float* __restrict__ w2,
                                             u16t* __restrict__ out) {
  const float* src = blockIdx.z == 0 ? w0 : blockIdx.z == 1 ? w1 : w2;
  u16t* dst = out + (size_t)blockIdx.z * 262144;
  __shared__ float tile[64][65];
  const int r = threadIdx.x >> 4;
  const int c = (threadIdx.x & 15) * 4;
  const int r0 = blockIdx.y * 64, c0 = blockIdx.x * 64;
#pragma unroll
  for (int i = 0; i < 4; i++) {
    float4 v = *(const float4*)&src[(size_t)(r0 + r + i * 16) * 512 + c0 + c];
    tile[r + i * 16][c] = v.x; tile[r + i * 16][c + 1] = v.y;
    tile[r + i * 16][c + 2] = v.z; tile[r + i * 16][c + 3] = v.w;
  }
  __syncthreads();
#pragma unroll
  for (int i = 0; i < 4; i++) {
    const int orow = c0 + r + i * 16;
    u16x4 o = { f2bf(tile[c][r + i * 16]), f2bf(tile[c + 1][r + i * 16]),
                f2bf(tile[c + 2][r + i * 16]), f2bf(tile[c + 3][r + i * 16]) };
    *(u16x4*)&dst[(size_t)orow * 512 + r0 + c] = o;
  }
}

// ---------------- composed-weight GEMM (64x64 tiles); z==0 (Q) scaled by LAM ----------------
__global__ __launch_bounds__(256) void compose_k(const u16t* __restrict__ Aall,
                                                 const u16t* __restrict__ Wall,
                                                 u16t* __restrict__ Call) {
  const u16t* A = Aall + (size_t)blockIdx.z * 262144;
  const u16t* W = Wall + (size_t)blockIdx.z * 262144;
  u16t* C = Call + (size_t)blockIdx.z * 262144;
  const float scale = blockIdx.z == 0 ? LAM : 1.0f;
  __shared__ alignas(16) u16t As[64 * 32];
  __shared__ alignas(16) u16t Ws[64 * 32];
  const int tid = threadIdx.x;
  const int lane = tid & 63, wave = tid >> 6;
  const int r15 = lane & 15, rhi = lane >> 4;
  const int wr = wave >> 1, wc = wave & 1;
  const int m0 = blockIdx.x * 64, n0 = blockIdx.y * 64;
  const int arow = tid >> 2, acol = (tid & 3) * 8;
  const f32x4 fz = {0.f, 0.f, 0.f, 0.f};
  f32x4 acc[2][2] = {{fz, fz}, {fz, fz}};
  const u16t* Ap = A + (size_t)(m0 + arow) * 512 + acol;
  const u16t* Wp = W + (size_t)(n0 + arow) * 512 + acol;
  u16t* As0 = &As[tid * 8];
  u16t* Ws0 = &Ws[tid * 8];
  for (int kt = 0; kt < 512; kt += 32) {
    __syncthreads();
    GLDS16(Ap + kt, As0);
    GLDS16(Wp + kt, Ws0);
    asm volatile("s_waitcnt vmcnt(0)" ::: "memory");
    __syncthreads();
    bf16x8 af[2], bfv[2];
#pragma unroll
    for (int mi = 0; mi < 2; mi++)
      af[mi] = *(const bf16x8*)&As[(wr * 32 + mi * 16 + r15) * 32 + rhi * 8];
#pragma unroll
    for (int ni = 0; ni < 2; ni++)
      bfv[ni] = *(const bf16x8*)&Ws[(wc * 32 + ni * 16 + r15) * 32 + rhi * 8];
#pragma unroll
    for (int mi = 0; mi < 2; mi++)
#pragma unroll
      for (int ni = 0; ni < 2; ni++)
        acc[mi][ni] = mfma16(af[mi], bfv[ni], acc[mi][ni]);
  }
#pragma unroll
  for (int mi = 0; mi < 2; mi++)
#pragma unroll
    for (int ni = 0; ni < 2; ni++) {
      const int col = n0 + wc * 32 + ni * 16 + r15;
#pragma unroll
      for (int r = 0; r < 4; r++) {
        const int row = m0 + wr * 32 + mi * 16 + rhi * 4 + r;
        C[(size_t)row * 512 + col] = f2bf(acc[mi][ni][r] * scale);
      }
    }
}

// ---------------- composed bias (seg 0 scaled by LAM) ----------------
__global__ __launch_bounds__(256) void bias_mv(const float* __restrict__ in_w,
                                               const float* __restrict__ in_b,
                                               const float* __restrict__ b0,
                                               const float* __restrict__ b1,
                                               const float* __restrict__ b2v,
                                               float* __restrict__ out) {
  const int bi = blockIdx.x;                 // 24 blocks
  const int seg = bi >> 3, m0 = (bi & 7) * 64;
  const float* bvec = seg == 0 ? b0 : seg == 1 ? b1 : b2v;
  const int m = m0 + (threadIdx.x >> 2), q = threadIdx.x & 3;
  const float* row = in_w + (size_t)(seg * 512 + m) * 512 + q * 128;
  const float* bv = bvec + q * 128;
  float s = 0.f;
  for (int j = 0; j < 128; j++) s += row[j] * bv[j];
  s += __shfl_xor(s, 1); s += __shfl_xor(s, 2);
  if (q == 0) {
    float r2 = s + in_b[seg * 512 + m];
    out[seg * 512 + m] = seg == 0 ? r2 * LAM : r2;
  }
}

// ---------------- 128x128-tile GEMM (stage-1 QKV): C = A @ W^T + bias ----------------
template<int ACT, int OUTBF>
__global__ __launch_bounds__(256) void gemm_bt(
    const u16t* __restrict__ A, int lda,
    const u16t* __restrict__ W,
    const float* __restrict__ bias,
    void* __restrict__ Cp, int ldc, int K)
{
  __shared__ alignas(16) u16t As[128 * 32];
  __shared__ alignas(16) u16t Ws[128 * 32];
  const int tid  = threadIdx.x;
  const int lane = tid & 63, wave = tid >> 6;
  const int r15  = lane & 15, rhi = lane >> 4;
  const int wr   = wave >> 1, wc  = wave & 1;
  const int m0 = blockIdx.x * 128, n0 = blockIdx.y * 128;
  const int arow = tid >> 2, acol = (tid & 3) * 8;

  const f32x4 fz = {0.f, 0.f, 0.f, 0.f};
  f32x4 acc[4][4];
#pragma unroll
  for (int i = 0; i < 4; i++)
#pragma unroll
    for (int j = 0; j < 4; j++) acc[i][j] = fz;

  const u16t* Ap0 = A + (size_t)(m0 + arow) * lda + acol;
  const u16t* Ap1 = A + (size_t)(m0 + arow + 64) * lda + acol;
  const u16t* Wp0 = W + (size_t)(n0 + arow) * K + acol;
  const u16t* Wp1 = W + (size_t)(n0 + arow + 64) * K + acol;
  u16t* As0 = &As[tid * 8];       u16t* As1 = &As[(tid + 256) * 8];
  u16t* Ws0 = &Ws[tid * 8];       u16t* Ws1 = &Ws[(tid + 256) * 8];

  for (int kt = 0; kt < K; kt += 32) {
    __syncthreads();
    GLDS16(Ap0 + kt, As0);
    GLDS16(Ap1 + kt, As1);
    GLDS16(Wp0 + kt, Ws0);
    GLDS16(Wp1 + kt, Ws1);
    asm volatile("s_waitcnt vmcnt(0)" ::: "memory");
    __syncthreads();
    bf16x8 af[4], bfv[4];
#pragma unroll
    for (int mi = 0; mi < 4; mi++)
      af[mi] = *(const bf16x8*)&As[(wr * 64 + mi * 16 + r15) * 32 + rhi * 8];
#pragma unroll
    for (int ni = 0; ni < 4; ni++)
      bfv[ni] = *(const bf16x8*)&Ws[(wc * 64 + ni * 16 + r15) * 32 + rhi * 8];
#pragma unroll
    for (int mi = 0; mi < 4; mi++)
#pragma unroll
      for (int ni = 0; ni < 4; ni++)
        acc[mi][ni] = mfma16(af[mi], bfv[ni], acc[mi][ni]);
  }

#pragma unroll
  for (int mi = 0; mi < 4; mi++) {
#pragma unroll
    for (int ni = 0; ni < 4; ni++) {
      const int col = n0 + wc * 64 + ni * 16 + r15;
      const float bv = bias[col];
#pragma unroll
      for (int r = 0; r < 4; r++) {
        const int row = m0 + wr * 64 + mi * 16 + rhi * 4 + r;
        float v = acc[mi][ni][r] + bv;
        if (ACT == 1) v = v >= 0.f ? v : 0.01f * v;
        if (OUTBF) ((u16t*)Cp)[(size_t)row * ldc + col] = f2bf(v);
        else       ((float*)Cp)[(size_t)row * ldc + col] = v;
      }
    }
  }
}

// ---------------- 64x64-tile GEMM (out-proj) ----------------
template<int ACT>
__global__ __launch_bounds__(256) void gemm64(
    const u16t* __restrict__ A, int lda,
    const u16t* __restrict__ W,
    const float* __restrict__ bias,
    u16t* __restrict__ Cp, int ldc, int K)
{
  __shared__ alignas(16) u16t As[64 * 32];
  __shared__ alignas(16) u16t Ws[64 * 32];
  const int tid  = threadIdx.x;
  const int lane = tid & 63, wave = tid >> 6;
  const int r15  = lane & 15, rhi = lane >> 4;
  const int wr   = wave >> 1, wc  = wave & 1;
  const int m0 = blockIdx.x * 64, n0 = blockIdx.y * 64;
  const int arow = tid >> 2, acol = (tid & 3) * 8;

  const f32x4 fz = {0.f, 0.f, 0.f, 0.f};
  f32x4 acc[2][2] = {{fz, fz}, {fz, fz}};

  const u16t* Ap = A + (size_t)(m0 + arow) * lda + acol;
  const u16t* Wp = W + (size_t)(n0 + arow) * K + acol;
  u16t* As0 = &As[tid * 8];
  u16t* Ws0 = &Ws[tid * 8];

  for (int kt = 0; kt < K; kt += 32) {
    __syncthreads();
    GLDS16(Ap + kt, As0);
    GLDS16(Wp + kt, Ws0);
    asm volatile("s_waitcnt vmcnt(0)" ::: "memory");
    __syncthreads();
    bf16x8 af[2], bfv[2];
#pragma unroll
    for (int mi = 0; mi < 2; mi++)
      af[mi] = *(const bf16x8*)&As[(wr * 32 + mi * 16 + r15) * 32 + rhi * 8];
#pragma unroll
    for (int ni = 0; ni < 2; ni++)
      bfv[ni] = *(const bf16x8*)&Ws[(wc * 32 + ni * 16 + r15) * 32 + rhi * 8];
#pragma unroll
    for (int mi = 0; mi < 2; mi++)
#pragma unroll
      for (int ni = 0; ni < 2; ni++)
        acc[mi][ni] = mfma16(af[mi], bfv[ni], acc[mi][ni]);
  }

#pragma unroll
  for (int mi = 0; mi < 2; mi++)
#pragma unroll
    for (int ni = 0; ni < 2; ni++) {
      const int col = n0 + wc * 32 + ni * 16 + r15;
      const float bv = bias[col];
#pragma unroll
      for (int r = 0; r < 4; r++) {
        const int row = m0 + wr * 32 + mi * 16 + rhi * 4 + r;
        float v = acc[mi][ni][r] + bv;
        if (ACT == 1) v = v >= 0.f ? v : 0.01f * v;
        Cp[(size_t)row * ldc + col] = f2bf(v);
      }
    }
}

// ---------------- sparse MoE + shared expert in ONE dispatch ----------------
__global__ __launch_bounds__(256) void moe_shared(
    const u16t* __restrict__ x1b, const u16t* __restrict__ expwb,
    const float* __restrict__ expb,
    const u16t* __restrict__ shwb, const float* __restrict__ shb,
    const int* __restrict__ counts,
    const int* __restrict__ list, const float* __restrict__ wlist,
    u16t* __restrict__ out_slots, u16t* __restrict__ shrd)
{
  const int e = blockIdx.x >> 7, mt = blockIdx.x & 127;
  const bool sh = (e == 8);
  const int cnt = sh ? TT : counts[e];
  const int m0 = mt * 64;
  if (m0 >= cnt) return;
  const int n0 = blockIdx.y * 64;
  __shared__ alignas(16) u16t As[64 * 32];
  __shared__ alignas(16) u16t Ws[64 * 32];
  __shared__ int tks[64];
  __shared__ float wws[64];
  const int tid  = threadIdx.x;
  const int lane = tid & 63, wave = tid >> 6;
  const int r15  = lane & 15, rhi = lane >> 4;
  const int wr   = wave >> 1, wc  = wave & 1;
  const int arow = tid >> 2, acol = (tid & 3) * 8;

  if (tid < 64) {
    if (sh) { tks[tid] = m0 + tid; wws[tid] = 1.f; }
    else {
      int idx = m0 + tid; if (idx >= cnt) idx = cnt - 1;
      tks[tid] = list[e * 8192 + idx];
      wws[tid] = wlist[e * 8192 + idx];
    }
  }
  __syncthreads();
  const int tokA = sh ? tks[arow] : (tks[arow] >> 1);

  const f32x4 fz = {0.f, 0.f, 0.f, 0.f};
  f32x4 acc[2][2] = {{fz, fz}, {fz, fz}};

  const u16t* Ap = x1b + (size_t)tokA * 512 + acol;
  const u16t* W  = (sh ? shwb : expwb + (size_t)e * 262144);
  const float* bias = sh ? shb : expb + e * 512;
  u16t* outp = sh ? shrd : out_slots;
  const u16t* Wp = W + (size_t)(n0 + arow) * 512 + acol;
  u16t* As0 = &As[tid * 8];
  u16t* Ws0 = &Ws[tid * 8];

  for (int kt = 0; kt < 512; kt += 32) {
    __syncthreads();
    GLDS16(Ap + kt, As0);
    GLDS16(Wp + kt, Ws0);
    asm volatile("s_waitcnt vmcnt(0)" ::: "memory");
    __syncthreads();
    bf16x8 af[2], bfv[2];
#pragma unroll
    for (int mi = 0; mi < 2; mi++)
      af[mi] = *(const bf16x8*)&As[(wr * 32 + mi * 16 + r15) * 32 + rhi * 8];
#pragma unroll
    for (int ni = 0; ni < 2; ni++)
      bfv[ni] = *(const bf16x8*)&Ws[(wc * 32 + ni * 16 + r15) * 32 + rhi * 8];
#pragma unroll
    for (int mi = 0; mi < 2; mi++)
#pragma unroll
      for (int ni = 0; ni < 2; ni++)
        acc[mi][ni] = mfma16(af[mi], bfv[ni], acc[mi][ni]);
  }

#pragma unroll
  for (int mi = 0; mi < 2; mi++)
#pragma unroll
    for (int ni = 0; ni < 2; ni++) {
      const int col = n0 + wc * 32 + ni * 16 + r15;
      const float bv = bias[col];
#pragma unroll
      for (int r = 0; r < 4; r++) {
        const int rl = wr * 32 + mi * 16 + rhi * 4 + r;
        if (m0 + rl < cnt) {
          float z = acc[mi][ni][r] + bv;
          z = z >= 0.f ? z : 0.01f * z;
          outp[(size_t)tks[rl] * 512 + col] = f2bf(wws[rl] * z);
        }
      }
    }
}

// ---------------- flash attention v3: 8 waves / 128 q-rows per block ----------------
// grid (B*H, L/128), block 512. Wave w: q-tile (w>>2), q-subrow (w&3)*16 + r15.
// K/V staged once per 128 q-rows (2x compute per staged byte vs v2).
__global__ __launch_bounds__(512) void attn_kernel(
    const u16t* __restrict__ qkv, u16t* __restrict__ ao)
{
  const int bh = blockIdx.x;
  const int b = bh >> 3, h = bh & 7;
  const int qg = blockIdx.y;
  const int tid  = threadIdx.x;
  const int lane = tid & 63, wave = tid >> 6;
  const int r15  = lane & 15, rhi = lane >> 4;

  __shared__ alignas(16) u16t Ks[128 * 72];
  __shared__ alignas(16) u16t Vt[64 * 136];

  const int qrow = qg * 128 + (wave >> 2) * 64 + (wave & 3) * 16 + r15;
  const size_t qoff = ((size_t)qrow * BB + b) * 1536 + h * HDD;
  const bf16x8 qf0 = *(const bf16x8*)&qkv[qoff + rhi * 8];
  const bf16x8 qf1 = *(const bf16x8*)&qkv[qoff + 32 + rhi * 8];

  const f32x4 fz = {0.f, 0.f, 0.f, 0.f};
  f32x4 oa[4] = {fz, fz, fz, fz};
  float psum = 0.f;

  // staging roles (512 threads)
  const int krow = tid >> 2, kchunk = (tid & 3) * 16;       // K: 16 elems/thread
  const int vd0 = (wave & 3) * 16 + (lane >> 5) * 8;        // V: 8 d-cols
  const int vkv = (wave >> 2) * 64 + (lane & 31) * 2;       // V: kv pair

  u16x8 kA0, kA1, vA0, vA1;
  {
    const size_t kb = ((size_t)krow * BB + b) * 1536 + h * HDD + 512 + kchunk;
    kA0 = *(const u16x8*)&qkv[kb];
    kA1 = *(const u16x8*)&qkv[kb + 8];
    const size_t v0 = ((size_t)vkv * BB + b) * 1536 + h * HDD + 1024 + vd0;
    vA0 = *(const u16x8*)&qkv[v0];
    vA1 = *(const u16x8*)&qkv[v0 + (size_t)BB * 1536];
  }

  for (int t = 0; t < 8; t++) {
    __syncthreads();   // prev tile's readers done
    {
      u16t* kd = &Ks[krow * 72 + kchunk];
      *(u16x8*)&kd[0] = kA0;
      *(u16x8*)&kd[8] = kA1;
    }
#pragma unroll
    for (int j = 0; j < 8; j++) {
      unsigned int w = (unsigned int)vA0[j] | ((unsigned int)vA1[j] << 16);
      *(unsigned int*)&Vt[(vd0 + j) * 136 + vkv] = w;
    }
    if (t < 7) {  // prefetch next tile under compute
      const int kv0n = (t + 1) * 128;
      const size_t kb = ((size_t)(kv0n + krow) * BB + b) * 1536 + h * HDD + 512 + kchunk;
      kA0 = *(const u16x8*)&qkv[kb];
      kA1 = *(const u16x8*)&qkv[kb + 8];
      const size_t v0 = ((size_t)(kv0n + vkv) * BB + b) * 1536 + h * HDD + 1024 + vd0;
      vA0 = *(const u16x8*)&qkv[v0];
      vA1 = *(const u16x8*)&qkv[v0 + (size_t)BB * 1536];
    }
    __syncthreads();   // LDS tile ready

    // S^T = K · Q^T : lane holds S[q = r15][kv = nt*16 + rhi*4 + r]
    f32x4 s[8];
    __builtin_amdgcn_s_setprio(1);
#pragma unroll
    for (int nt = 0; nt < 8; nt++) {
      const u16t* kr = &Ks[(nt * 16 + r15) * 72];
      bf16x8 k0 = *(const bf16x8*)&kr[rhi * 8];
      bf16x8 k1 = *(const bf16x8*)&kr[32 + rhi * 8];
      f32x4 acc = fz;
      acc = mfma16(k0, qf0, acc);
      acc = mfma16(k1, qf1, acc);
      s[nt] = acc;
    }
    __builtin_amdgcn_s_setprio(0);

    unsigned int P2[8][2];
#pragma unroll
    for (int nt = 0; nt < 8; nt++) {
#pragma unroll
      for (int r = 0; r < 4; r++) {
        s[nt][r] = exp2f(s[nt][r]);   // Q pre-scaled by log2e/8
        psum += s[nt][r];
      }
      asm("v_cvt_pk_bf16_f32 %0, %1, %2" : "=v"(P2[nt][0]) : "v"(s[nt][0]), "v"(s[nt][1]));
      asm("v_cvt_pk_bf16_f32 %0, %1, %2" : "=v"(P2[nt][1]) : "v"(s[nt][2]), "v"(s[nt][3]));
    }

    __builtin_amdgcn_s_setprio(1);
#pragma unroll
    for (int c = 0; c < 4; c++) {
      union { unsigned int w[4]; bf16x8 v; } pf;
      pf.w[0] = P2[2 * c][0];     pf.w[1] = P2[2 * c][1];
      pf.w[2] = P2[2 * c + 1][0]; pf.w[3] = P2[2 * c + 1][1];
#pragma unroll
      for (int dd = 0; dd < 4; dd++) {
        const u16t* vr = &Vt[(dd * 16 + r15) * 136 + c * 32 + rhi * 4];
        union { u16x4 h[2]; bf16x8 v; } vb;
        vb.h[0] = *(const u16x4*)&vr[0];
        vb.h[1] = *(const u16x4*)&vr[16];
        oa[dd] = mfma16(vb.v, pf.v, oa[dd]);
      }
    }
    __builtin_amdgcn_s_setprio(0);
  }

  float ls = psum;
  ls += __shfl_xor(ls, 16);
  ls += __shfl_xor(ls, 32);
  const float inv = 1.f / ls;
  const size_t obase = ((size_t)qrow * BB + b) * EE + h * HDD;
#pragma unroll
  for (int dd = 0; dd < 4; dd++) {
    u16x4 o = { f2bf(oa[dd][0] * inv), f2bf(oa[dd][1] * inv),
                f2bf(oa[dd][2] * inv), f2bf(oa[dd][3] * inv) };
    *(u16x4*)&ao[obase + dd * 16 + rhi * 4] = o;
  }
}

// ---------------- fused LN1 + gate (wave per token) ----------------
__device__ __forceinline__ float wave_sum(float v) {
#pragma unroll
  for (int off = 1; off < 64; off <<= 1) v += __shfl_xor(v, off);
  return v;
}

__global__ __launch_bounds__(256) void ln1_gate(
    const float* __restrict__ x, const u16t* __restrict__ aopb,
    const float* __restrict__ g, const float* __restrict__ be,
    const float* __restrict__ gw, const float* __restrict__ gb,
    u16t* __restrict__ x1b,
    int* __restrict__ tok_pack, float2* __restrict__ tok_w,
    float* __restrict__ partials)
{
  const int wave = threadIdx.x >> 6, lane = threadIdx.x & 63;
  const int t = blockIdx.x * 4 + wave;
  const size_t base = (size_t)t * EE + lane * 8;
  float4 a0 = *(const float4*)&x[base], a1 = *(const float4*)&x[base + 4];
  u16x8 ap = *(const u16x8*)&aopb[base];
  float v[8] = { a0.x + bf2f(ap[0]), a0.y + bf2f(ap[1]), a0.z + bf2f(ap[2]), a0.w + bf2f(ap[3]),
                 a1.x + bf2f(ap[4]), a1.y + bf2f(ap[5]), a1.z + bf2f(ap[6]), a1.w + bf2f(ap[7]) };
  float s = 0.f;
#pragma unroll
  for (int i = 0; i < 8; i++) s += v[i];
  const float mean = wave_sum(s) * (1.f / EE);
  float vs = 0.f;
#pragma unroll
  for (int i = 0; i < 8; i++) { v[i] -= mean; vs += v[i] * v[i]; }
  const float inv = rsqrtf(wave_sum(vs) * (1.f / EE) + 1e-5f);
  float4 g0 = *(const float4*)&g[lane * 8],  g1 = *(const float4*)&g[lane * 8 + 4];
  float4 b0 = *(const float4*)&be[lane * 8], b1 = *(const float4*)&be[lane * 8 + 4];
  float o[8] = { v[0]*inv*g0.x + b0.x, v[1]*inv*g0.y + b0.y, v[2]*inv*g0.z + b0.z, v[3]*inv*g0.w + b0.w,
                 v[4]*inv*g1.x + b1.x, v[5]*inv*g1.y + b1.y, v[6]*inv*g1.z + b1.z, v[7]*inv*g1.w + b1.w };
  u16x8 ob = { f2bf(o[0]), f2bf(o[1]), f2bf(o[2]), f2bf(o[3]),
               f2bf(o[4]), f2bf(o[5]), f2bf(o[6]), f2bf(o[7]) };
  *(u16x8*)&x1b[base] = ob;

  float pe[8];
  float mx = -1e30f;
#pragma unroll
  for (int e = 0; e < 8; e++) {
    float4 ga = *(const float4*)&gw[e * EE + lane * 8];
    float4 gB = *(const float4*)&gw[e * EE + lane * 8 + 4];
    float d = o[0]*ga.x + o[1]*ga.y + o[2]*ga.z + o[3]*ga.w
            + o[4]*gB.x + o[5]*gB.y + o[6]*gB.z + o[7]*gB.w;
#pragma unroll
    for (int off = 1; off < 64; off <<= 1) d += __shfl_xor(d, off);
    pe[e] = d + gb[e];
    mx = fmaxf(mx, pe[e]);
  }
  float se = 0.f;
#pragma unroll
  for (int e = 0; e < 8; e++) { pe[e] = __expf(pe[e] - mx); se += pe[e]; }
  const float invs = 1.f / se;
#pragma unroll
  for (int e = 0; e < 8; e++) pe[e] *= invs;
  float v1 = -1.f; int i1 = 0;
#pragma unroll
  for (int e = 0; e < 8; e++) if (pe[e] > v1) { v1 = pe[e]; i1 = e; }
  float v2 = -1.f; int i2 = -1;
#pragma unroll
  for (int e = 0; e < 8; e++) if (e != i1 && pe[e] > v2) { v2 = pe[e]; i2 = e; }
  const float denom = 1.f / (v1 + v2);
  if (lane == 0) {
    tok_pack[t] = i1 | (i2 << 8);
    float2 w; w.x = v1 * denom; w.y = v2 * denom;
    tok_w[t] = w;
  }
  __shared__ float fb[4][8], pb[4][8];
  if (lane < 8) {
    fb[wave][lane] = (lane == i1 || lane == i2) ? 1.f : 0.f;
    pb[wave][lane] = pe[lane];
  }
  __syncthreads();
  if (threadIdx.x < 8) {
    const int e = threadIdx.x;
    partials[(size_t)blockIdx.x * 16 + e]     = fb[0][e] + fb[1][e] + fb[2][e] + fb[3][e];
    partials[(size_t)blockIdx.x * 16 + 8 + e] = pb[0][e] + pb[1][e] + pb[2][e] + pb[3][e];
  }
}

// ---------------- LN2 (bf16 inputs) ----------------
__global__ __launch_bounds__(256) void ln2_kernel(
    const u16t* __restrict__ x1b, const u16t* __restrict__ slots,
    const u16t* __restrict__ sh,
    const float* __restrict__ g, const float* __restrict__ be,
    float* __restrict__ out)
{
  const int wave = threadIdx.x >> 6, lane = threadIdx.x & 63;
  const int t = blockIdx.x * 4 + wave;
  const size_t base = (size_t)t * EE + lane * 8;
  u16x8 xv = *(const u16x8*)&x1b[base];
  u16x8 m0 = *(const u16x8*)&slots[(size_t)(2 * t) * EE + lane * 8];
  u16x8 m1 = *(const u16x8*)&slots[(size_t)(2 * t + 1) * EE + lane * 8];
  u16x8 sv = *(const u16x8*)&sh[base];
  float v[8];
#pragma unroll
  for (int i = 0; i < 8; i++)
    v[i] = bf2f(xv[i]) + bf2f(m0[i]) + bf2f(m1[i]) + bf2f(sv[i]);
  float s = 0.f;
#pragma unroll
  for (int i = 0; i < 8; i++) s += v[i];
  const float mean = wave_sum(s) * (1.f / EE);
  float vs = 0.f;
#pragma unroll
  for (int i = 0; i < 8; i++) { v[i] -= mean; vs += v[i] * v[i]; }
  const float inv = rsqrtf(wave_sum(vs) * (1.f / EE) + 1e-5f);
  float4 g0 = *(const float4*)&g[lane * 8],  g1 = *(const float4*)&g[lane * 8 + 4];
  float4 b0 = *(const float4*)&be[lane * 8], b1 = *(const float4*)&be[lane * 8 + 4];
  *(float4*)&out[base] = make_float4(v[0]*inv*g0.x + b0.x, v[1]*inv*g0.y + b0.y,
                                     v[2]*inv*g0.z + b0.z, v[3]*inv*g0.w + b0.w);
  *(float4*)&out[base + 4] = make_float4(v[4]*inv*g1.x + b1.x, v[5]*inv*g1.y + b1.y,
                                         v[6]*inv*g1.z + b1.z, v[7]*inv*g1.w + b1.w);
}

// ---------------- deterministic list build + loss reduce (grid 9, block 512) ----------------
__global__ __launch_bounds__(512) void build_lists(
    const int* __restrict__ tok_pack, const float2* __restrict__ tok_w,
    int* __restrict__ counts, int* __restrict__ list, float* __restrict__ wlist,
    const float* __restrict__ partials, float* __restrict__ loss_out)
{
  if (blockIdx.x == 8) {
    __shared__ float acc2[32][16];
    __shared__ float fin[16];
    const int c = threadIdx.x & 15, grp = threadIdx.x >> 4;   // 0..31
    float s = 0.f;
    for (int i = grp; i < 2048; i += 32) s += partials[(size_t)i * 16 + c];
    acc2[grp][c] = s;
    __syncthreads();
    if (threadIdx.x < 16) {
      float t2 = 0.f;
      for (int g2 = 0; g2 < 32; g2++) t2 += acc2[g2][threadIdx.x];
      fin[threadIdx.x] = t2;
    }
    __syncthreads();
    if (threadIdx.x == 0) {
      float loss = 0.f;
      for (int e = 0; e < 8; e++)
        loss += (fin[e] * (1.f / TT)) * (fin[8 + e] * (1.f / TT));
      loss_out[0] = loss * 8.f;
    }
    return;
  }
  const int e = blockIdx.x;
  const int tid = threadIdx.x;
  const int lane = tid & 63, wave = tid >> 6;   // 8 waves
  __shared__ int wtot[8];
  __shared__ int runb;
  if (tid == 0) runb = 0;
  __syncthreads();
  for (int c = 0; c < 16; c++) {
    const int t = c * 512 + tid;
    const int pk = tok_pack[t];
    const int i1 = pk & 255, i2 = (pk >> 8) & 255;
    const bool s1 = (i1 == e);
    const bool flag = s1 || (i2 == e);
    const unsigned long long mask = __ballot(flag);
    if (lane == 63) wtot[wave] = __popcll(mask);
    __syncthreads();
    int wbase = 0;
#pragma unroll
    for (int w2 = 0; w2 < 8; w2++) if (w2 < wave) wbase += wtot[w2];
    int btot = 0;
#pragma unroll
    for (int w2 = 0; w2 < 8; w2++) btot += wtot[w2];
    if (flag) {
      const int pre = __popcll(mask & ((1ull << lane) - 1ull));
      const int pos = runb + wbase + pre;
      list[e * 8192 + pos] = 2 * t + (s1 ? 0 : 1);
      float2 w = tok_w[t];
      wlist[e * 8192 + pos] = s1 ? w.x : w.y;
    }
    __syncthreads();
    if (tid == 0) runb += btot;
    __syncthreads();
  }
  if (tid == 0) counts[e] = runb;
}

// ---------------- host-side launcher ----------------
extern "C" void kernel_launch(void* const* d_in, const int* in_sizes, int n_in,
                              void* d_out, int out_size, void* d_ws, size_t ws_size,
                              hipStream_t stream) {
  const float* x    = (const float*)d_in[0];
  const float* wq   = (const float*)d_in[1];
  const float* bq   = (const float*)d_in[2];
  const float* wk   = (const float*)d_in[3];
  const float* bk   = (const float*)d_in[4];
  const float* wv   = (const float*)d_in[5];
  const float* bv   = (const float*)d_in[6];
  const float* in_w = (const float*)d_in[7];
  const float* in_b = (const float*)d_in[8];
  const float* out_w= (const float*)d_in[9];
  const float* out_b= (const float*)d_in[10];
  const float* ln1g = (const float*)d_in[11];
  const float* ln1b = (const float*)d_in[12];
  const float* ln2g = (const float*)d_in[13];
  const float* ln2b = (const float*)d_in[14];
  const float* shw  = (const float*)d_in[15];
  const float* shb  = (const float*)d_in[16];
  const float* gw   = (const float*)d_in[17];
  const float* gb   = (const float*)d_in[18];
  const float* expw = (const float*)d_in[19];
  const float* expb = (const float*)d_in[20];

  char* ws = (char*)d_ws;
  // --- static region ---
  u16t* xb     = (u16t*)(ws + 0);          // 8 MB
  u16t* inwb   = (u16t*)(ws + 8388608);    // 1.5 MB
  u16t* w3t    = (u16t*)(ws + 9961472);    // 1.5 MB
  u16t* w2big  = (u16t*)(ws + 11534336);   // 1.5 MB
  u16t* outwb  = (u16t*)(ws + 13107200);   // 0.5 MB
  u16t* shwb   = (u16t*)(ws + 13631488);   // 0.5 MB
  u16t* expwb  = (u16t*)(ws + 14155776);   // 4 MB
  float* b2    = (float*)(ws + 18350080);  // 6 KB
  int*  tok_pack = (int*)(ws + 18356224);  // 32 KB
  float2* tok_w  = (float2*)(ws + 18388992); // 64 KB
  int*  counts = (int*)(ws + 18454528);
  int*  list   = (int*)(ws + 18454656);    // 256 KB
  float* wlist = (float*)(ws + 18716800);  // 256 KB
  float* parts = (float*)(ws + 18978944);  // 128 KB
  // --- overlay pool ---
  const size_t S = 19110016;
  u16t* qkvb   = (u16t*)(ws + S);                 // 24 MB: stage1 -> attn
  u16t* aopb   = (u16t*)(ws + S);                 // 8 MB: outproj -> ln1 (qkvb dead)
  u16t* x1b    = (u16t*)(ws + S + 16777216);      // 8 MB: ln1 -> moe/shared/ln2
  u16t* oslots = (u16t*)(ws + S);                 // 16 MB: moe -> ln2 (aopb dead)
  u16t* aob    = (u16t*)(ws + 0);                 // 8 MB: attn -> outproj (xb dead)
  u16t* shrd   = (u16t*)(ws + 0);                 // 8 MB: moe_shared -> ln2 (aob dead)
  float* outp  = (float*)d_out;

  dim3 blk(256);
  // all converts in one dispatch
  cvt_all<<<7424, blk, 0, stream>>>(x, in_w, out_w, shw, expw,
                                    xb, inwb, outwb, shwb, expwb);
  cvt_t<<<dim3(8, 8, 3), blk, 0, stream>>>(wq, wk, wv, w3t);
  // weight/bias composition (Q segment pre-scaled by log2e/8)
  compose_k<<<dim3(8, 8, 3), blk, 0, stream>>>(inwb, w3t, w2big);
  bias_mv<<<24, blk, 0, stream>>>(in_w, in_b, bq, bk, bv, b2);
  // fused QKV projection -> q|k|v packed (ldc 1536)
  gemm_bt<0,1><<<dim3(64, 12), blk, 0, stream>>>(xb, EE, w2big, b2, qkvb, 1536, EE);
  // attention (512-thread blocks, 128 q-rows each)
  attn_kernel<<<dim3(64, 8), dim3(512), 0, stream>>>(qkvb, aob);
  // out projection (bf16 out, 64x64 tiles)
  gemm64<0><<<dim3(128, 8), blk, 0, stream>>>(aob, EE, outwb, out_b, aopb, EE, EE);
  // fused LN1 + gate
  ln1_gate<<<2048, blk, 0, stream>>>(x, aopb, ln1g, ln1b, gw, gb, x1b, tok_pack, tok_w, parts);
  // list build + loss reduce (grid 9, block 512)
  build_lists<<<9, dim3(512), 0, stream>>>(tok_pack, tok_w, counts, list, wlist,
                                           parts, outp + (size_t)TT * EE);
  // sparse MoE + shared expert in one dispatch
  moe_shared<<<dim3(1152, 8), blk, 0, stream>>>(x1b, expwb, expb, shwb, shb,
                                                counts, list, wlist, oslots, shrd);
  // LN2 -> output (f32)
  ln2_kernel<<<2048, blk, 0, stream>>>(x1b, oslots, shrd, ln2g, ln2b, outp);
}